// Round 4
// baseline (320.021 us; speedup 1.0000x reference)
//
#include <hip/hip_runtime.h>

// GCN edge-predictor encoder, R4: MFMA (split-bf16) GEMMs.
//   deg/dinv -> CSR -> xp=dinv*x -> t1=gather(xp) [bf16 hi/lo]
//   -> h'=dinv*(t1@Wb+bb) [f32] -> t2=gather(h') [bf16 hi/lo]
//   -> m=relu(t2@Wmu+bmu), s=relu(t2@Wls+bls)
// GEMM: A@W ~= Ah@Wh + Ah@Wl + Al@Wh (bf16 splits, f32 accum) via
// v_mfma_f32_32x32x16_bf16. A,W staged in LDS with 16B-slot XOR swizzle.

#define CH 128
#define SCAN_CHUNK 1024

typedef __attribute__((ext_vector_type(8))) short short8v;

__device__ inline ushort f2bf(float f) {
  uint u = __builtin_bit_cast(uint, f);
  uint r = (u + 0x7FFFu + ((u >> 16) & 1u)) >> 16;
  return (ushort)r;
}
__device__ inline float bf2f(ushort h) {
  uint u = ((uint)h) << 16;
  return __builtin_bit_cast(float, u);
}

__global__ void count_kernel(const int* __restrict__ ei, int E, int* __restrict__ cnt) {
  int e = blockIdx.x * blockDim.x + threadIdx.x;
  if (e < E) atomicAdd(&cnt[ei[E + e]], 1);
}

__global__ __launch_bounds__(256) void scan_sum_kernel(const int* __restrict__ cnt,
    int n, int* __restrict__ bsum) {
  __shared__ int sdata[256];
  int base = blockIdx.x * SCAN_CHUNK;
  int tid = threadIdx.x;
  int s = 0;
  #pragma unroll
  for (int j = 0; j < 4; ++j) {
    int i = base + tid * 4 + j;
    if (i < n) s += cnt[i];
  }
  sdata[tid] = s;
  __syncthreads();
  for (int off = 128; off > 0; off >>= 1) {
    if (tid < off) sdata[tid] += sdata[tid + off];
    __syncthreads();
  }
  if (tid == 0) bsum[blockIdx.x] = sdata[0];
}

__global__ __launch_bounds__(256) void scan_bsum_kernel(int* __restrict__ bsum,
    int nb, int* __restrict__ total_out) {
  __shared__ int sdata[1024];
  int tid = threadIdx.x;
  #pragma unroll
  for (int j = 0; j < 4; ++j) {
    int i = tid * 4 + j;
    sdata[i] = (i < nb) ? bsum[i] : 0;
  }
  __syncthreads();
  if (tid == 0) {
    int run = 0;
    for (int i = 0; i < nb; ++i) { int v = sdata[i]; sdata[i] = run; run += v; }
    *total_out = run;
  }
  __syncthreads();
  #pragma unroll
  for (int j = 0; j < 4; ++j) {
    int i = tid * 4 + j;
    if (i < nb) bsum[i] = sdata[i];
  }
}

__global__ __launch_bounds__(256) void scan_fin_kernel(const int* __restrict__ cnt,
    int n, const int* __restrict__ bsum, const int* __restrict__ total,
    int* __restrict__ rowptr, int* __restrict__ cursor, float* __restrict__ dinv) {
  __shared__ int sthr[256];
  int base = blockIdx.x * SCAN_CHUNK;
  int tid = threadIdx.x;
  int v[4];
  int ts = 0;
  #pragma unroll
  for (int j = 0; j < 4; ++j) {
    int i = base + tid * 4 + j;
    v[j] = (i < n) ? cnt[i] : 0;
    ts += v[j];
  }
  sthr[tid] = ts;
  __syncthreads();
  for (int off = 1; off < 256; off <<= 1) {
    int t = (tid >= off) ? sthr[tid - off] : 0;
    __syncthreads();
    sthr[tid] += t;
    __syncthreads();
  }
  int excl = sthr[tid] - ts + bsum[blockIdx.x];
  #pragma unroll
  for (int j = 0; j < 4; ++j) {
    int i = base + tid * 4 + j;
    if (i < n) {
      rowptr[i] = excl;
      cursor[i] = excl;
      dinv[i]   = rsqrtf((float)(v[j] + 1));
      excl += v[j];
    }
  }
  if (blockIdx.x == 0 && tid == 0) rowptr[n] = *total;
}

__global__ void fill_kernel(const int* __restrict__ ei, int E,
                            int* __restrict__ cursor, int* __restrict__ col) {
  int e = blockIdx.x * blockDim.x + threadIdx.x;
  if (e < E) {
    int d = ei[E + e];
    int pos = atomicAdd(&cursor[d], 1);
    col[pos] = ei[e];
  }
}

// xp[i] = dinv[i] * x[i], float4-vectorized.
__global__ __launch_bounds__(256) void prescale_kernel(const float* __restrict__ x,
    const float* __restrict__ dinv, float* __restrict__ xp, int n) {
  int t = blockIdx.x * 256 + threadIdx.x;
  if (t < n * (CH / 4)) {
    float d = dinv[t >> 5];
    float4 v = ((const float4*)x)[t];
    ((float4*)xp)[t] = make_float4(v.x * d, v.y * d, v.z * d, v.w * d);
  }
}

// Transpose + split W (f32 [128][128]) -> Wt_hi/lo bf16 [c][k]. 3 matrices,
// one block each (blockIdx.x selects).
__global__ __launch_bounds__(256) void wsplit_kernel(
    const float* __restrict__ W0, ushort* __restrict__ W0h, ushort* __restrict__ W0l,
    const float* __restrict__ W1, ushort* __restrict__ W1h, ushort* __restrict__ W1l,
    const float* __restrict__ W2, ushort* __restrict__ W2h, ushort* __restrict__ W2l) {
  __shared__ float Wf[128][132];
  const float* W; ushort* Wh; ushort* Wl;
  if (blockIdx.x == 0)      { W = W0; Wh = W0h; Wl = W0l; }
  else if (blockIdx.x == 1) { W = W1; Wh = W1h; Wl = W1l; }
  else                      { W = W2; Wh = W2h; Wl = W2l; }
  int tid = threadIdx.x;
  const float4* W4 = (const float4*)W;
  #pragma unroll
  for (int i = 0; i < 16; ++i) {
    int j = tid + i * 256;          // f4 idx, 4096 total
    int row = j >> 5, c4 = j & 31;
    float4 v = W4[j];
    Wf[row][c4 * 4 + 0] = v.x; Wf[row][c4 * 4 + 1] = v.y;
    Wf[row][c4 * 4 + 2] = v.z; Wf[row][c4 * 4 + 3] = v.w;
  }
  __syncthreads();
  #pragma unroll
  for (int i = 0; i < 64; ++i) {
    int o = tid + i * 256;          // 16384 outputs
    int c = o >> 7, k = o & 127;
    float v = Wf[k][c];
    ushort h = f2bf(v);
    ushort l = f2bf(v - bf2f(h));
    Wh[o] = h;
    Wl[o] = l;
  }
}

// One wave per node; gather-sum of pre-scaled features; output split bf16.
__global__ __launch_bounds__(256) void agg_kernel(const float* __restrict__ feat,
    const int* __restrict__ rowptr, const int* __restrict__ col,
    const float* __restrict__ dinv, ushort* __restrict__ out_hi,
    ushort* __restrict__ out_lo, int n) {
  int w = (blockIdx.x * 256 + threadIdx.x) >> 6;
  if (w >= n) return;
  int lane = threadIdx.x & 63;
  int g  = lane >> 5;
  int cl = lane & 31;
  const float4* f4 = (const float4*)feat;
  float4 acc = make_float4(0.f, 0.f, 0.f, 0.f);
  if (g == 0) acc = f4[(size_t)w * 32 + cl];   // self-loop term
  int s = rowptr[w], e = rowptr[w + 1];
  int j = s;
  for (; j + 4 <= e; j += 4) {
    int c0 = col[j + g];
    int c1 = col[j + 2 + g];
    float4 v0 = f4[(size_t)c0 * 32 + cl];
    float4 v1 = f4[(size_t)c1 * 32 + cl];
    acc.x += v0.x + v1.x;
    acc.y += v0.y + v1.y;
    acc.z += v0.z + v1.z;
    acc.w += v0.w + v1.w;
  }
  for (; j < e; j += 2) {
    int jj = j + g;
    if (jj < e) {
      int c = col[jj];
      float4 v = f4[(size_t)c * 32 + cl];
      acc.x += v.x; acc.y += v.y; acc.z += v.z; acc.w += v.w;
    }
  }
  acc.x += __shfl_xor(acc.x, 32);
  acc.y += __shfl_xor(acc.y, 32);
  acc.z += __shfl_xor(acc.z, 32);
  acc.w += __shfl_xor(acc.w, 32);
  if (g == 0) {
    float di = dinv[w];
    float v0 = acc.x * di, v1 = acc.y * di, v2 = acc.z * di, v3 = acc.w * di;
    ushort h0 = f2bf(v0), h1 = f2bf(v1), h2 = f2bf(v2), h3 = f2bf(v3);
    ushort l0 = f2bf(v0 - bf2f(h0)), l1 = f2bf(v1 - bf2f(h1));
    ushort l2 = f2bf(v2 - bf2f(h2)), l3 = f2bf(v3 - bf2f(h3));
    ((ushort4*)out_hi)[(size_t)w * 32 + cl] = make_ushort4(h0, h1, h2, h3);
    ((ushort4*)out_lo)[(size_t)w * 32 + cl] = make_ushort4(l0, l1, l2, l3);
  }
}

// MFMA GEMM: out = post(A@W + b). A given as bf16 hi/lo [M][128] row-major;
// W as bf16 hi/lo transposed [c][k]. 64 rows/block, 2 waves; wave = 32 rows x
// 128 cols = 4 accum tiles of 32x32. nmat=2 reuses the staged A tile.
// post: dinv != nullptr -> v = dinv[row]*(v); else v = relu(v).
__global__ __launch_bounds__(128) void gemm_mfma_kernel(
    const ushort* __restrict__ Ahi, const ushort* __restrict__ Alo,
    const ushort* __restrict__ W0h, const ushort* __restrict__ W0l,
    const float* __restrict__ b0,
    const ushort* __restrict__ W1h, const ushort* __restrict__ W1l,
    const float* __restrict__ b1,
    const float* __restrict__ dinv,
    float* __restrict__ out0, float* __restrict__ out1,
    int M, int nmat) {
  typedef __attribute__((ext_vector_type(16))) float floatx16;
  __shared__ ushort Ah[64 * 128];
  __shared__ ushort Al[64 * 128];
  __shared__ ushort Wh[128 * 128];
  __shared__ ushort Wl[128 * 128];

  const int tid = threadIdx.x;
  const int m0 = blockIdx.x * 64;
  const int lane = tid & 63;
  const int wv = tid >> 6;          // wave 0/1 -> rows 0-31 / 32-63 of tile
  const int rA = lane & 31;         // A-row-in-32 / W-col-in-32
  const int swz = lane & 15;
  const int kh = lane >> 5;         // k half (0/1)

  // stage A hi/lo (16B slots, phys = slot ^ (row&15))
  {
    const uint4* GH = (const uint4*)Ahi;
    const uint4* GL = (const uint4*)Alo;
    uint4* LH = (uint4*)Ah;
    uint4* LL = (uint4*)Al;
    #pragma unroll
    for (int t = 0; t < 8; ++t) {
      int q = tid + t * 128;        // 0..1023
      int row = q >> 4, ls = q & 15;
      int phys = ls ^ (row & 15);
      uint4 vh = make_uint4(0, 0, 0, 0), vl = make_uint4(0, 0, 0, 0);
      if (m0 + row < M) {
        size_t gidx = (size_t)(m0 + row) * 16 + ls;
        vh = GH[gidx];
        vl = GL[gidx];
      }
      LH[row * 16 + phys] = vh;
      LL[row * 16 + phys] = vl;
    }
  }

  for (int mat = 0; mat < nmat; ++mat) {
    const ushort* gwh = mat ? W1h : W0h;
    const ushort* gwl = mat ? W1l : W0l;
    const float*  bb  = mat ? b1 : b0;
    float* outp       = mat ? out1 : out0;

    if (mat) __syncthreads();       // prev compute done before restage
    {
      const uint4* GH = (const uint4*)gwh;
      const uint4* GL = (const uint4*)gwl;
      uint4* LH = (uint4*)Wh;
      uint4* LL = (uint4*)Wl;
      #pragma unroll
      for (int t = 0; t < 16; ++t) {
        int q = tid + t * 128;      // 0..2047
        int row = q >> 4, ls = q & 15;
        int phys = ls ^ (row & 15);
        LH[row * 16 + phys] = GH[q];
        LL[row * 16 + phys] = GL[q];
      }
    }
    __syncthreads();

    floatx16 acc[4];
    #pragma unroll
    for (int t = 0; t < 4; ++t)
      #pragma unroll
      for (int j = 0; j < 16; ++j) acc[t][j] = 0.f;

    const short8v* AHv = (const short8v*)Ah;
    const short8v* ALv = (const short8v*)Al;
    const short8v* WHv = (const short8v*)Wh;
    const short8v* WLv = (const short8v*)Wl;
    const int arow = wv * 32 + rA;

    #pragma unroll
    for (int kc = 0; kc < 8; ++kc) {
      int ls = kc * 2 + kh;
      int ph = ls ^ swz;
      short8v ah = AHv[arow * 16 + ph];
      short8v al = ALv[arow * 16 + ph];
      short8v wh[4], wl[4];
      #pragma unroll
      for (int t = 0; t < 4; ++t) {
        wh[t] = WHv[(t * 32 + rA) * 16 + ph];
        wl[t] = WLv[(t * 32 + rA) * 16 + ph];
      }
      #pragma unroll
      for (int t = 0; t < 4; ++t)
        acc[t] = __builtin_amdgcn_mfma_f32_32x32x16_bf16(ah, wh[t], acc[t], 0, 0, 0);
      #pragma unroll
      for (int t = 0; t < 4; ++t)
        acc[t] = __builtin_amdgcn_mfma_f32_32x32x16_bf16(ah, wl[t], acc[t], 0, 0, 0);
      #pragma unroll
      for (int t = 0; t < 4; ++t)
        acc[t] = __builtin_amdgcn_mfma_f32_32x32x16_bf16(al, wh[t], acc[t], 0, 0, 0);
    }

    float bcol[4];
    #pragma unroll
    for (int t = 0; t < 4; ++t) bcol[t] = bb[t * 32 + rA];
    #pragma unroll
    for (int t = 0; t < 4; ++t) {
      #pragma unroll
      for (int r = 0; r < 16; ++r) {
        int r32 = (r & 3) + 8 * (r >> 2) + 4 * kh;
        int row = m0 + wv * 32 + r32;
        if (row < M) {
          float v = acc[t][r] + bcol[t];
          if (dinv) v *= dinv[row];
          else      v = fmaxf(v, 0.f);
          outp[(size_t)row * CH + t * 32 + rA] = v;
        }
      }
    }
  }
}

extern "C" void kernel_launch(void* const* d_in, const int* in_sizes, int n_in,
                              void* d_out, int out_size, void* d_ws, size_t ws_size,
                              hipStream_t stream) {
  const float* x      = (const float*)d_in[0];
  const int*   ei     = (const int*)d_in[1];
  const float* W_base = (const float*)d_in[2];
  const float* b_base = (const float*)d_in[3];
  const float* W_mu   = (const float*)d_in[4];
  const float* b_mu   = (const float*)d_in[5];
  const float* W_ls   = (const float*)d_in[6];
  const float* b_ls   = (const float*)d_in[7];
  float* out = (float*)d_out;

  const int N = in_sizes[0] / CH;
  const int E = in_sizes[1] / 2;

  char* ws = (char*)d_ws;
  size_t off = 0;
  auto carve = [&](size_t bytes) -> void* {
    void* p = ws + off;
    off += (bytes + 511) & ~(size_t)511;
    return p;
  };
  int*    cnt    = (int*)carve((size_t)N * 4);
  int*    rowptr = (int*)carve((size_t)(N + 1) * 4);
  int*    cursor = (int*)carve((size_t)N * 4);
  int*    col    = (int*)carve((size_t)E * 4);
  float*  dinv   = (float*)carve((size_t)N * 4);
  int*    bsum   = (int*)carve((size_t)2048 * 4);
  int*    total  = (int*)carve((size_t)4);
  ushort* Wbh = (ushort*)carve((size_t)CH * CH * 2);
  ushort* Wbl = (ushort*)carve((size_t)CH * CH * 2);
  ushort* Wmh = (ushort*)carve((size_t)CH * CH * 2);
  ushort* Wml = (ushort*)carve((size_t)CH * CH * 2);
  ushort* Wsh = (ushort*)carve((size_t)CH * CH * 2);
  ushort* Wsl = (ushort*)carve((size_t)CH * CH * 2);
  float*  bufA = (float*)carve((size_t)N * CH * 4);   // xp, then h'
  ushort* thi  = (ushort*)carve((size_t)N * CH * 2);  // t1/t2 hi
  ushort* tlo  = (ushort*)carve((size_t)N * CH * 2);  // t1/t2 lo

  hipMemsetAsync(cnt, 0, (size_t)N * 4, stream);

  int eb = (E + 255) / 256;
  int nb = (N + SCAN_CHUNK - 1) / SCAN_CHUNK;
  count_kernel<<<eb, 256, 0, stream>>>(ei, E, cnt);
  scan_sum_kernel<<<nb, 256, 0, stream>>>(cnt, N, bsum);
  scan_bsum_kernel<<<1, 256, 0, stream>>>(bsum, nb, total);
  scan_fin_kernel<<<nb, 256, 0, stream>>>(cnt, N, bsum, total, rowptr, cursor, dinv);
  fill_kernel<<<eb, 256, 0, stream>>>(ei, E, cursor, col);

  wsplit_kernel<<<3, 256, 0, stream>>>(W_base, Wbh, Wbl, W_mu, Wmh, Wml,
                                       W_ls, Wsh, Wsl);

  int pb = (N * (CH / 4) + 255) / 256;
  int ab = (N * 64 + 255) / 256;
  int gb = (N + 63) / 64;

  prescale_kernel<<<pb, 256, 0, stream>>>(x, dinv, bufA, N);
  agg_kernel<<<ab, 256, 0, stream>>>(bufA, rowptr, col, dinv, thi, tlo, N);  // t1
  gemm_mfma_kernel<<<gb, 128, 0, stream>>>(thi, tlo, Wbh, Wbl, b_base,
                                           nullptr, nullptr, nullptr,
                                           dinv, bufA, nullptr, N, 1);       // h'
  agg_kernel<<<ab, 256, 0, stream>>>(bufA, rowptr, col, dinv, thi, tlo, N);  // t2
  gemm_mfma_kernel<<<gb, 128, 0, stream>>>(thi, tlo, Wmh, Wml, b_mu,
                                           Wsh, Wsl, b_ls,
                                           nullptr, out, out + (size_t)N * CH,
                                           N, 2);                            // m, s
}

// Round 5
// 284.984 us; speedup vs baseline: 1.1229x; 1.1229x over previous
//
#include <hip/hip_runtime.h>

// GCN edge-predictor encoder, R5: LDS-free MFMA GEMMs (split-bf16).
//   deg/dinv -> CSR -> xp=dinv*x -> t1=gather(xp) [bf16 hi/lo]
//   -> h'=dinv*(t1@Wb+bb) [f32] -> t2=gather(h') [bf16 hi/lo]
//   -> m=relu(t2@Wmu+bmu), s=relu(t2@Wls+bls)
// GEMM: A@W ~= Ah@Wh + Ah@Wl + Al@Wh (bf16 splits, f32 accum) via
// v_mfma_f32_32x32x16_bf16. Fragments loaded global->VGPR directly
// (A row-major, W pre-transposed [c][k]): 16B/lane contiguous, no LDS,
// no barriers. R4's 96KB-LDS staging gave 1 block/CU @ 2 waves -> 76us.

#define CH 128
#define SCAN_CHUNK 1024

typedef __attribute__((ext_vector_type(8))) short short8v;
typedef __attribute__((ext_vector_type(16))) float floatx16;

__device__ inline ushort f2bf(float f) {
  uint u = __builtin_bit_cast(uint, f);
  uint r = (u + 0x7FFFu + ((u >> 16) & 1u)) >> 16;
  return (ushort)r;
}
__device__ inline float bf2f(ushort h) {
  uint u = ((uint)h) << 16;
  return __builtin_bit_cast(float, u);
}

__global__ void count_kernel(const int* __restrict__ ei, int E, int* __restrict__ cnt) {
  int e = blockIdx.x * blockDim.x + threadIdx.x;
  if (e < E) atomicAdd(&cnt[ei[E + e]], 1);
}

__global__ __launch_bounds__(256) void scan_sum_kernel(const int* __restrict__ cnt,
    int n, int* __restrict__ bsum) {
  __shared__ int sdata[256];
  int base = blockIdx.x * SCAN_CHUNK;
  int tid = threadIdx.x;
  int s = 0;
  #pragma unroll
  for (int j = 0; j < 4; ++j) {
    int i = base + tid * 4 + j;
    if (i < n) s += cnt[i];
  }
  sdata[tid] = s;
  __syncthreads();
  for (int off = 128; off > 0; off >>= 1) {
    if (tid < off) sdata[tid] += sdata[tid + off];
    __syncthreads();
  }
  if (tid == 0) bsum[blockIdx.x] = sdata[0];
}

__global__ __launch_bounds__(256) void scan_bsum_kernel(int* __restrict__ bsum,
    int nb, int* __restrict__ total_out) {
  __shared__ int sdata[1024];
  int tid = threadIdx.x;
  #pragma unroll
  for (int j = 0; j < 4; ++j) {
    int i = tid * 4 + j;
    sdata[i] = (i < nb) ? bsum[i] : 0;
  }
  __syncthreads();
  if (tid == 0) {
    int run = 0;
    for (int i = 0; i < nb; ++i) { int v = sdata[i]; sdata[i] = run; run += v; }
    *total_out = run;
  }
  __syncthreads();
  #pragma unroll
  for (int j = 0; j < 4; ++j) {
    int i = tid * 4 + j;
    if (i < nb) bsum[i] = sdata[i];
  }
}

__global__ __launch_bounds__(256) void scan_fin_kernel(const int* __restrict__ cnt,
    int n, const int* __restrict__ bsum, const int* __restrict__ total,
    int* __restrict__ rowptr, int* __restrict__ cursor, float* __restrict__ dinv) {
  __shared__ int sthr[256];
  int base = blockIdx.x * SCAN_CHUNK;
  int tid = threadIdx.x;
  int v[4];
  int ts = 0;
  #pragma unroll
  for (int j = 0; j < 4; ++j) {
    int i = base + tid * 4 + j;
    v[j] = (i < n) ? cnt[i] : 0;
    ts += v[j];
  }
  sthr[tid] = ts;
  __syncthreads();
  for (int off = 1; off < 256; off <<= 1) {
    int t = (tid >= off) ? sthr[tid - off] : 0;
    __syncthreads();
    sthr[tid] += t;
    __syncthreads();
  }
  int excl = sthr[tid] - ts + bsum[blockIdx.x];
  #pragma unroll
  for (int j = 0; j < 4; ++j) {
    int i = base + tid * 4 + j;
    if (i < n) {
      rowptr[i] = excl;
      cursor[i] = excl;
      dinv[i]   = rsqrtf((float)(v[j] + 1));
      excl += v[j];
    }
  }
  if (blockIdx.x == 0 && tid == 0) rowptr[n] = *total;
}

__global__ void fill_kernel(const int* __restrict__ ei, int E,
                            int* __restrict__ cursor, int* __restrict__ col) {
  int e = blockIdx.x * blockDim.x + threadIdx.x;
  if (e < E) {
    int d = ei[E + e];
    int pos = atomicAdd(&cursor[d], 1);
    col[pos] = ei[e];
  }
}

// xp[i] = dinv[i] * x[i], float4-vectorized.
__global__ __launch_bounds__(256) void prescale_kernel(const float* __restrict__ x,
    const float* __restrict__ dinv, float* __restrict__ xp, int n) {
  int t = blockIdx.x * 256 + threadIdx.x;
  if (t < n * (CH / 4)) {
    float d = dinv[t >> 5];
    float4 v = ((const float4*)x)[t];
    ((float4*)xp)[t] = make_float4(v.x * d, v.y * d, v.z * d, v.w * d);
  }
}

// Transpose + split W (f32 [128][128], 3 matrices) -> Wt hi/lo bf16 [c][k].
// 48 blocks: blockIdx/16 = matrix, blockIdx%16 = 8-col slice. Coalesced
// writes, strided (L2-resident) reads.
__global__ __launch_bounds__(256) void wsplit_kernel(
    const float* __restrict__ W0, ushort* __restrict__ W0h, ushort* __restrict__ W0l,
    const float* __restrict__ W1, ushort* __restrict__ W1h, ushort* __restrict__ W1l,
    const float* __restrict__ W2, ushort* __restrict__ W2h, ushort* __restrict__ W2l) {
  int m = blockIdx.x >> 4, sl = blockIdx.x & 15;
  const float* W; ushort* Wh; ushort* Wl;
  if (m == 0)      { W = W0; Wh = W0h; Wl = W0l; }
  else if (m == 1) { W = W1; Wh = W1h; Wl = W1l; }
  else             { W = W2; Wh = W2h; Wl = W2l; }
  int o = sl * 1024 + threadIdx.x * 4;   // output idx (c*128+k), 4 per thread
  int c = o >> 7, k = o & 127;
  #pragma unroll
  for (int j = 0; j < 4; ++j) {
    float v = W[(k + j) * 128 + c];
    ushort h = f2bf(v);
    Wh[o + j] = h;
    Wl[o + j] = f2bf(v - bf2f(h));
  }
}

// One wave per node; gather-sum of pre-scaled features; output split bf16.
__global__ __launch_bounds__(256) void agg_kernel(const float* __restrict__ feat,
    const int* __restrict__ rowptr, const int* __restrict__ col,
    const float* __restrict__ dinv, ushort* __restrict__ out_hi,
    ushort* __restrict__ out_lo, int n) {
  int w = (blockIdx.x * 256 + threadIdx.x) >> 6;
  if (w >= n) return;
  int lane = threadIdx.x & 63;
  int g  = lane >> 5;
  int cl = lane & 31;
  const float4* f4 = (const float4*)feat;
  float4 acc = make_float4(0.f, 0.f, 0.f, 0.f);
  if (g == 0) acc = f4[(size_t)w * 32 + cl];   // self-loop term
  int s = rowptr[w], e = rowptr[w + 1];
  int j = s;
  for (; j + 4 <= e; j += 4) {
    int c0 = col[j + g];
    int c1 = col[j + 2 + g];
    float4 v0 = f4[(size_t)c0 * 32 + cl];
    float4 v1 = f4[(size_t)c1 * 32 + cl];
    acc.x += v0.x + v1.x;
    acc.y += v0.y + v1.y;
    acc.z += v0.z + v1.z;
    acc.w += v0.w + v1.w;
  }
  for (; j < e; j += 2) {
    int jj = j + g;
    if (jj < e) {
      int c = col[jj];
      float4 v = f4[(size_t)c * 32 + cl];
      acc.x += v.x; acc.y += v.y; acc.z += v.z; acc.w += v.w;
    }
  }
  acc.x += __shfl_xor(acc.x, 32);
  acc.y += __shfl_xor(acc.y, 32);
  acc.z += __shfl_xor(acc.z, 32);
  acc.w += __shfl_xor(acc.w, 32);
  if (g == 0) {
    float di = dinv[w];
    float v0 = acc.x * di, v1 = acc.y * di, v2 = acc.z * di, v3 = acc.w * di;
    ushort h0 = f2bf(v0), h1 = f2bf(v1), h2 = f2bf(v2), h3 = f2bf(v3);
    ushort l0 = f2bf(v0 - bf2f(h0)), l1 = f2bf(v1 - bf2f(h1));
    ushort l2 = f2bf(v2 - bf2f(h2)), l3 = f2bf(v3 - bf2f(h3));
    ((ushort4*)out_hi)[(size_t)w * 32 + cl] = make_ushort4(h0, h1, h2, h3);
    ((ushort4*)out_lo)[(size_t)w * 32 + cl] = make_ushort4(l0, l1, l2, l3);
  }
}

// LDS-free MFMA GEMM: out = post(A@W + b). A = bf16 hi/lo [M][128] row-major,
// W = bf16 hi/lo transposed [c][k]. 256 thr = 4 waves x 32 rows = 128 rows/blk.
// Fragments loaded straight from global (16B/lane); no LDS, no barriers.
// post: dinv != nullptr -> v *= dinv[row]; else v = relu(v).
__global__ __launch_bounds__(256) void gemm_mfma_kernel(
    const ushort* __restrict__ Ahi, const ushort* __restrict__ Alo,
    const ushort* __restrict__ W0h, const ushort* __restrict__ W0l,
    const float* __restrict__ b0,
    const ushort* __restrict__ W1h, const ushort* __restrict__ W1l,
    const float* __restrict__ b1,
    const float* __restrict__ dinv,
    float* __restrict__ out0, float* __restrict__ out1,
    int M, int nmat) {
  const int tid  = threadIdx.x;
  const int lane = tid & 63;
  const int wv   = tid >> 6;         // wave id 0..3
  const int rA   = lane & 31;        // A row-in-tile / W col-in-tile
  const int kh   = lane >> 5;        // k half
  const int row  = blockIdx.x * 128 + wv * 32 + rA;
  const bool rowok = row < M;

  const short8v* AH = (const short8v*)Ahi;
  const short8v* AL = (const short8v*)Alo;
  const short8v zero8 = {0, 0, 0, 0, 0, 0, 0, 0};

  // A fragments for all 8 k-chunks (16B each, reused across matrices).
  short8v ah[8], al[8];
  #pragma unroll
  for (int kc = 0; kc < 8; ++kc) {
    int fi = row * 16 + kc * 2 + kh;
    ah[kc] = rowok ? AH[fi] : zero8;
    al[kc] = rowok ? AL[fi] : zero8;
  }

  for (int mat = 0; mat < nmat; ++mat) {
    const short8v* WH = (const short8v*)(mat ? W1h : W0h);
    const short8v* WL = (const short8v*)(mat ? W1l : W0l);
    const float*   bb = mat ? b1 : b0;
    float*       outp = mat ? out1 : out0;

    floatx16 acc[4];
    #pragma unroll
    for (int t = 0; t < 4; ++t)
      #pragma unroll
      for (int j = 0; j < 16; ++j) acc[t][j] = 0.f;

    #pragma unroll
    for (int kc = 0; kc < 8; ++kc) {
      int fk = kc * 2 + kh;
      short8v wh[4], wl[4];
      #pragma unroll
      for (int t = 0; t < 4; ++t) {
        wh[t] = WH[(t * 32 + rA) * 16 + fk];
        wl[t] = WL[(t * 32 + rA) * 16 + fk];
      }
      #pragma unroll
      for (int t = 0; t < 4; ++t)
        acc[t] = __builtin_amdgcn_mfma_f32_32x32x16_bf16(ah[kc], wh[t], acc[t], 0, 0, 0);
      #pragma unroll
      for (int t = 0; t < 4; ++t)
        acc[t] = __builtin_amdgcn_mfma_f32_32x32x16_bf16(ah[kc], wl[t], acc[t], 0, 0, 0);
      #pragma unroll
      for (int t = 0; t < 4; ++t)
        acc[t] = __builtin_amdgcn_mfma_f32_32x32x16_bf16(al[kc], wh[t], acc[t], 0, 0, 0);
    }

    float bcol[4];
    #pragma unroll
    for (int t = 0; t < 4; ++t) bcol[t] = bb[t * 32 + rA];
    #pragma unroll
    for (int t = 0; t < 4; ++t) {
      #pragma unroll
      for (int r = 0; r < 16; ++r) {
        int r32 = (r & 3) + 8 * (r >> 2) + 4 * kh;
        int orow = blockIdx.x * 128 + wv * 32 + r32;
        if (orow < M) {
          float v = acc[t][r] + bcol[t];
          if (dinv) v *= dinv[orow];
          else      v = fmaxf(v, 0.f);
          outp[(size_t)orow * CH + t * 32 + rA] = v;
        }
      }
    }
  }
}

extern "C" void kernel_launch(void* const* d_in, const int* in_sizes, int n_in,
                              void* d_out, int out_size, void* d_ws, size_t ws_size,
                              hipStream_t stream) {
  const float* x      = (const float*)d_in[0];
  const int*   ei     = (const int*)d_in[1];
  const float* W_base = (const float*)d_in[2];
  const float* b_base = (const float*)d_in[3];
  const float* W_mu   = (const float*)d_in[4];
  const float* b_mu   = (const float*)d_in[5];
  const float* W_ls   = (const float*)d_in[6];
  const float* b_ls   = (const float*)d_in[7];
  float* out = (float*)d_out;

  const int N = in_sizes[0] / CH;
  const int E = in_sizes[1] / 2;

  char* ws = (char*)d_ws;
  size_t off = 0;
  auto carve = [&](size_t bytes) -> void* {
    void* p = ws + off;
    off += (bytes + 511) & ~(size_t)511;
    return p;
  };
  int*    cnt    = (int*)carve((size_t)N * 4);
  int*    rowptr = (int*)carve((size_t)(N + 1) * 4);
  int*    cursor = (int*)carve((size_t)N * 4);
  int*    col    = (int*)carve((size_t)E * 4);
  float*  dinv   = (float*)carve((size_t)N * 4);
  int*    bsum   = (int*)carve((size_t)2048 * 4);
  int*    total  = (int*)carve((size_t)4);
  ushort* Wbh = (ushort*)carve((size_t)CH * CH * 2);
  ushort* Wbl = (ushort*)carve((size_t)CH * CH * 2);
  ushort* Wmh = (ushort*)carve((size_t)CH * CH * 2);
  ushort* Wml = (ushort*)carve((size_t)CH * CH * 2);
  ushort* Wsh = (ushort*)carve((size_t)CH * CH * 2);
  ushort* Wsl = (ushort*)carve((size_t)CH * CH * 2);
  float*  bufA = (float*)carve((size_t)N * CH * 4);   // xp, then h'
  ushort* thi  = (ushort*)carve((size_t)N * CH * 2);  // t1/t2 hi
  ushort* tlo  = (ushort*)carve((size_t)N * CH * 2);  // t1/t2 lo

  hipMemsetAsync(cnt, 0, (size_t)N * 4, stream);

  int eb = (E + 255) / 256;
  int nb = (N + SCAN_CHUNK - 1) / SCAN_CHUNK;
  count_kernel<<<eb, 256, 0, stream>>>(ei, E, cnt);
  scan_sum_kernel<<<nb, 256, 0, stream>>>(cnt, N, bsum);
  scan_bsum_kernel<<<1, 256, 0, stream>>>(bsum, nb, total);
  scan_fin_kernel<<<nb, 256, 0, stream>>>(cnt, N, bsum, total, rowptr, cursor, dinv);
  fill_kernel<<<eb, 256, 0, stream>>>(ei, E, cursor, col);

  wsplit_kernel<<<48, 256, 0, stream>>>(W_base, Wbh, Wbl, W_mu, Wmh, Wml,
                                        W_ls, Wsh, Wsl);

  int pb = (N * (CH / 4) + 255) / 256;
  int ab = (N * 64 + 255) / 256;
  int gb = (N + 127) / 128;

  prescale_kernel<<<pb, 256, 0, stream>>>(x, dinv, bufA, N);
  agg_kernel<<<ab, 256, 0, stream>>>(bufA, rowptr, col, dinv, thi, tlo, N);  // t1
  gemm_mfma_kernel<<<gb, 256, 0, stream>>>(thi, tlo, Wbh, Wbl, b_base,
                                           nullptr, nullptr, nullptr,
                                           dinv, bufA, nullptr, N, 1);       // h'
  agg_kernel<<<ab, 256, 0, stream>>>(bufA, rowptr, col, dinv, thi, tlo, N);  // t2
  gemm_mfma_kernel<<<gb, 256, 0, stream>>>(thi, tlo, Wmh, Wml, b_mu,
                                           Wsh, Wsl, b_ls,
                                           nullptr, out, out + (size_t)N * CH,
                                           N, 2);                            // m, s
}

// Round 6
// 271.400 us; speedup vs baseline: 1.1791x; 1.0501x over previous
//
#include <hip/hip_runtime.h>

// GCN edge-predictor encoder, R6: MFMA GEMM with W-in-LDS (swizzled), A-in-reg.
//   deg/dinv -> CSR -> xp=dinv*x -> t1=gather(xp) [bf16 hi/lo]
//   -> h'=dinv*(t1@Wb+bb) [f32] -> t2=gather(h') [bf16 hi/lo]
//   -> m=relu(t2@Wmu+bmu), s=relu(t2@Wls+bls)
// GEMM: A@W ~= Ah@Wh + Ah@Wl + Al@Wh (bf16 splits, f32 accum) via
// v_mfma_f32_32x32x16_bf16. R5 (no LDS) was latency-bound: 8x16B W loads
// from L2 per kc, ~90% idle. Now W hi/lo staged once per matrix in 64KB LDS
// (16B-slot XOR swizzle -> conflict-free ds_read_b128), 2 blocks/CU.

#define CH 128
#define SCAN_CHUNK 1024

typedef __attribute__((ext_vector_type(8))) short short8v;
typedef __attribute__((ext_vector_type(16))) float floatx16;

__device__ inline ushort f2bf(float f) {
  uint u = __builtin_bit_cast(uint, f);
  uint r = (u + 0x7FFFu + ((u >> 16) & 1u)) >> 16;
  return (ushort)r;
}
__device__ inline float bf2f(ushort h) {
  uint u = ((uint)h) << 16;
  return __builtin_bit_cast(float, u);
}

__global__ void count_kernel(const int* __restrict__ ei, int E, int* __restrict__ cnt) {
  int e = blockIdx.x * blockDim.x + threadIdx.x;
  if (e < E) atomicAdd(&cnt[ei[E + e]], 1);
}

__global__ __launch_bounds__(256) void scan_sum_kernel(const int* __restrict__ cnt,
    int n, int* __restrict__ bsum) {
  __shared__ int sdata[256];
  int base = blockIdx.x * SCAN_CHUNK;
  int tid = threadIdx.x;
  int s = 0;
  #pragma unroll
  for (int j = 0; j < 4; ++j) {
    int i = base + tid * 4 + j;
    if (i < n) s += cnt[i];
  }
  sdata[tid] = s;
  __syncthreads();
  for (int off = 128; off > 0; off >>= 1) {
    if (tid < off) sdata[tid] += sdata[tid + off];
    __syncthreads();
  }
  if (tid == 0) bsum[blockIdx.x] = sdata[0];
}

__global__ __launch_bounds__(256) void scan_bsum_kernel(int* __restrict__ bsum,
    int nb, int* __restrict__ total_out) {
  __shared__ int sdata[1024];
  int tid = threadIdx.x;
  #pragma unroll
  for (int j = 0; j < 4; ++j) {
    int i = tid * 4 + j;
    sdata[i] = (i < nb) ? bsum[i] : 0;
  }
  __syncthreads();
  if (tid == 0) {
    int run = 0;
    for (int i = 0; i < nb; ++i) { int v = sdata[i]; sdata[i] = run; run += v; }
    *total_out = run;
  }
  __syncthreads();
  #pragma unroll
  for (int j = 0; j < 4; ++j) {
    int i = tid * 4 + j;
    if (i < nb) bsum[i] = sdata[i];
  }
}

__global__ __launch_bounds__(256) void scan_fin_kernel(const int* __restrict__ cnt,
    int n, const int* __restrict__ bsum, const int* __restrict__ total,
    int* __restrict__ rowptr, int* __restrict__ cursor, float* __restrict__ dinv) {
  __shared__ int sthr[256];
  int base = blockIdx.x * SCAN_CHUNK;
  int tid = threadIdx.x;
  int v[4];
  int ts = 0;
  #pragma unroll
  for (int j = 0; j < 4; ++j) {
    int i = base + tid * 4 + j;
    v[j] = (i < n) ? cnt[i] : 0;
    ts += v[j];
  }
  sthr[tid] = ts;
  __syncthreads();
  for (int off = 1; off < 256; off <<= 1) {
    int t = (tid >= off) ? sthr[tid - off] : 0;
    __syncthreads();
    sthr[tid] += t;
    __syncthreads();
  }
  int excl = sthr[tid] - ts + bsum[blockIdx.x];
  #pragma unroll
  for (int j = 0; j < 4; ++j) {
    int i = base + tid * 4 + j;
    if (i < n) {
      rowptr[i] = excl;
      cursor[i] = excl;
      dinv[i]   = rsqrtf((float)(v[j] + 1));
      excl += v[j];
    }
  }
  if (blockIdx.x == 0 && tid == 0) rowptr[n] = *total;
}

__global__ void fill_kernel(const int* __restrict__ ei, int E,
                            int* __restrict__ cursor, int* __restrict__ col) {
  int e = blockIdx.x * blockDim.x + threadIdx.x;
  if (e < E) {
    int d = ei[E + e];
    int pos = atomicAdd(&cursor[d], 1);
    col[pos] = ei[e];
  }
}

// xp[i] = dinv[i] * x[i], float4-vectorized.
__global__ __launch_bounds__(256) void prescale_kernel(const float* __restrict__ x,
    const float* __restrict__ dinv, float* __restrict__ xp, int n) {
  int t = blockIdx.x * 256 + threadIdx.x;
  if (t < n * (CH / 4)) {
    float d = dinv[t >> 5];
    float4 v = ((const float4*)x)[t];
    ((float4*)xp)[t] = make_float4(v.x * d, v.y * d, v.z * d, v.w * d);
  }
}

// Transpose + split W (f32 [128][128], 3 matrices) -> Wt hi/lo bf16 [c][k].
__global__ __launch_bounds__(256) void wsplit_kernel(
    const float* __restrict__ W0, ushort* __restrict__ W0h, ushort* __restrict__ W0l,
    const float* __restrict__ W1, ushort* __restrict__ W1h, ushort* __restrict__ W1l,
    const float* __restrict__ W2, ushort* __restrict__ W2h, ushort* __restrict__ W2l) {
  int m = blockIdx.x >> 4, sl = blockIdx.x & 15;
  const float* W; ushort* Wh; ushort* Wl;
  if (m == 0)      { W = W0; Wh = W0h; Wl = W0l; }
  else if (m == 1) { W = W1; Wh = W1h; Wl = W1l; }
  else             { W = W2; Wh = W2h; Wl = W2l; }
  int o = sl * 1024 + threadIdx.x * 4;   // output idx (c*128+k), 4 per thread
  int c = o >> 7, k = o & 127;
  #pragma unroll
  for (int j = 0; j < 4; ++j) {
    float v = W[(k + j) * 128 + c];
    ushort h = f2bf(v);
    Wh[o + j] = h;
    Wl[o + j] = f2bf(v - bf2f(h));
  }
}

// One wave per node; gather-sum of pre-scaled features; output split bf16.
__global__ __launch_bounds__(256) void agg_kernel(const float* __restrict__ feat,
    const int* __restrict__ rowptr, const int* __restrict__ col,
    const float* __restrict__ dinv, ushort* __restrict__ out_hi,
    ushort* __restrict__ out_lo, int n) {
  int w = (blockIdx.x * 256 + threadIdx.x) >> 6;
  if (w >= n) return;
  int lane = threadIdx.x & 63;
  int g  = lane >> 5;
  int cl = lane & 31;
  const float4* f4 = (const float4*)feat;
  float4 acc = make_float4(0.f, 0.f, 0.f, 0.f);
  if (g == 0) acc = f4[(size_t)w * 32 + cl];   // self-loop term
  int s = rowptr[w], e = rowptr[w + 1];
  int j = s;
  for (; j + 4 <= e; j += 4) {
    int c0 = col[j + g];
    int c1 = col[j + 2 + g];
    float4 v0 = f4[(size_t)c0 * 32 + cl];
    float4 v1 = f4[(size_t)c1 * 32 + cl];
    acc.x += v0.x + v1.x;
    acc.y += v0.y + v1.y;
    acc.z += v0.z + v1.z;
    acc.w += v0.w + v1.w;
  }
  for (; j < e; j += 2) {
    int jj = j + g;
    if (jj < e) {
      int c = col[jj];
      float4 v = f4[(size_t)c * 32 + cl];
      acc.x += v.x; acc.y += v.y; acc.z += v.z; acc.w += v.w;
    }
  }
  acc.x += __shfl_xor(acc.x, 32);
  acc.y += __shfl_xor(acc.y, 32);
  acc.z += __shfl_xor(acc.z, 32);
  acc.w += __shfl_xor(acc.w, 32);
  if (g == 0) {
    float di = dinv[w];
    float v0 = acc.x * di, v1 = acc.y * di, v2 = acc.z * di, v3 = acc.w * di;
    ushort h0 = f2bf(v0), h1 = f2bf(v1), h2 = f2bf(v2), h3 = f2bf(v3);
    ushort l0 = f2bf(v0 - bf2f(h0)), l1 = f2bf(v1 - bf2f(h1));
    ushort l2 = f2bf(v2 - bf2f(h2)), l3 = f2bf(v3 - bf2f(h3));
    ((ushort4*)out_hi)[(size_t)w * 32 + cl] = make_ushort4(h0, h1, h2, h3);
    ((ushort4*)out_lo)[(size_t)w * 32 + cl] = make_ushort4(l0, l1, l2, l3);
  }
}

// MFMA GEMM: out = post(A@W + b). A = bf16 hi/lo [M][128] row-major (regs),
// W = bf16 hi/lo transposed [c][k] staged in 64KB LDS with 16B-slot XOR
// swizzle (phys = slot ^ (row&15)) -> conflict-free ds_read_b128.
// 256 thr = 4 waves x 32 rows = 128 rows/block; 2 blocks/CU.
// post: dinv != nullptr -> v *= dinv[row]; else v = relu(v).
__global__ __launch_bounds__(256) void gemm_mfma_kernel(
    const ushort* __restrict__ Ahi, const ushort* __restrict__ Alo,
    const ushort* __restrict__ W0h, const ushort* __restrict__ W0l,
    const float* __restrict__ b0,
    const ushort* __restrict__ W1h, const ushort* __restrict__ W1l,
    const float* __restrict__ b1,
    const float* __restrict__ dinv,
    float* __restrict__ out0, float* __restrict__ out1,
    int M, int nmat) {
  __shared__ ushort Wh[128 * 128];   // 32KB, swizzled 16B slots
  __shared__ ushort Wl[128 * 128];   // 32KB

  const int tid  = threadIdx.x;
  const int lane = tid & 63;
  const int wv   = tid >> 6;         // wave id 0..3
  const int rA   = lane & 31;        // A row-in-tile / W col-in-tile
  const int kh   = lane >> 5;        // k half
  const int row  = blockIdx.x * 128 + wv * 32 + rA;
  const bool rowok = row < M;

  const short8v* AH = (const short8v*)Ahi;
  const short8v* AL = (const short8v*)Alo;
  const short8v zero8 = {0, 0, 0, 0, 0, 0, 0, 0};

  // A fragments for all 8 k-chunks (16B each, reused across matrices).
  short8v ah[8], al[8];
  #pragma unroll
  for (int kc = 0; kc < 8; ++kc) {
    int fi = row * 16 + kc * 2 + kh;
    ah[kc] = rowok ? AH[fi] : zero8;
    al[kc] = rowok ? AL[fi] : zero8;
  }

  for (int mat = 0; mat < nmat; ++mat) {
    const uint4*  GH = (const uint4*)(mat ? W1h : W0h);
    const uint4*  GL = (const uint4*)(mat ? W1l : W0l);
    const float*  bb = mat ? b1 : b0;
    float*      outp = mat ? out1 : out0;

    if (mat) __syncthreads();        // drain reads of prev W before overwrite
    {
      uint4* LH = (uint4*)Wh;
      uint4* LL = (uint4*)Wl;
      #pragma unroll
      for (int t = 0; t < 8; ++t) {
        int q = tid + t * 256;       // 0..2047 16B slots
        int wr = q >> 4, ls = q & 15;
        int phys = ls ^ (wr & 15);
        LH[wr * 16 + phys] = GH[q];
        LL[wr * 16 + phys] = GL[q];
      }
    }
    __syncthreads();

    floatx16 acc[4];
    #pragma unroll
    for (int t = 0; t < 4; ++t)
      #pragma unroll
      for (int j = 0; j < 16; ++j) acc[t][j] = 0.f;

    const short8v* WHv = (const short8v*)Wh;
    const short8v* WLv = (const short8v*)Wl;

    #pragma unroll
    for (int kc = 0; kc < 8; ++kc) {
      int fk = kc * 2 + kh;
      int ph = fk ^ (rA & 15);       // swizzled slot (wrow&15 == rA&15)
      short8v wh[4], wl[4];
      #pragma unroll
      for (int t = 0; t < 4; ++t) {
        wh[t] = WHv[(t * 32 + rA) * 16 + ph];
        wl[t] = WLv[(t * 32 + rA) * 16 + ph];
      }
      #pragma unroll
      for (int t = 0; t < 4; ++t)
        acc[t] = __builtin_amdgcn_mfma_f32_32x32x16_bf16(ah[kc], wh[t], acc[t], 0, 0, 0);
      #pragma unroll
      for (int t = 0; t < 4; ++t)
        acc[t] = __builtin_amdgcn_mfma_f32_32x32x16_bf16(ah[kc], wl[t], acc[t], 0, 0, 0);
      #pragma unroll
      for (int t = 0; t < 4; ++t)
        acc[t] = __builtin_amdgcn_mfma_f32_32x32x16_bf16(al[kc], wh[t], acc[t], 0, 0, 0);
    }

    float bcol[4];
    #pragma unroll
    for (int t = 0; t < 4; ++t) bcol[t] = bb[t * 32 + rA];
    #pragma unroll
    for (int t = 0; t < 4; ++t) {
      #pragma unroll
      for (int r = 0; r < 16; ++r) {
        int r32 = (r & 3) + 8 * (r >> 2) + 4 * kh;
        int orow = blockIdx.x * 128 + wv * 32 + r32;
        if (orow < M) {
          float v = acc[t][r] + bcol[t];
          if (dinv) v *= dinv[orow];
          else      v = fmaxf(v, 0.f);
          outp[(size_t)orow * CH + t * 32 + rA] = v;
        }
      }
    }
  }
}

extern "C" void kernel_launch(void* const* d_in, const int* in_sizes, int n_in,
                              void* d_out, int out_size, void* d_ws, size_t ws_size,
                              hipStream_t stream) {
  const float* x      = (const float*)d_in[0];
  const int*   ei     = (const int*)d_in[1];
  const float* W_base = (const float*)d_in[2];
  const float* b_base = (const float*)d_in[3];
  const float* W_mu   = (const float*)d_in[4];
  const float* b_mu   = (const float*)d_in[5];
  const float* W_ls   = (const float*)d_in[6];
  const float* b_ls   = (const float*)d_in[7];
  float* out = (float*)d_out;

  const int N = in_sizes[0] / CH;
  const int E = in_sizes[1] / 2;

  char* ws = (char*)d_ws;
  size_t off = 0;
  auto carve = [&](size_t bytes) -> void* {
    void* p = ws + off;
    off += (bytes + 511) & ~(size_t)511;
    return p;
  };
  int*    cnt    = (int*)carve((size_t)N * 4);
  int*    rowptr = (int*)carve((size_t)(N + 1) * 4);
  int*    cursor = (int*)carve((size_t)N * 4);
  int*    col    = (int*)carve((size_t)E * 4);
  float*  dinv   = (float*)carve((size_t)N * 4);
  int*    bsum   = (int*)carve((size_t)2048 * 4);
  int*    total  = (int*)carve((size_t)4);
  ushort* Wbh = (ushort*)carve((size_t)CH * CH * 2);
  ushort* Wbl = (ushort*)carve((size_t)CH * CH * 2);
  ushort* Wmh = (ushort*)carve((size_t)CH * CH * 2);
  ushort* Wml = (ushort*)carve((size_t)CH * CH * 2);
  ushort* Wsh = (ushort*)carve((size_t)CH * CH * 2);
  ushort* Wsl = (ushort*)carve((size_t)CH * CH * 2);
  float*  bufA = (float*)carve((size_t)N * CH * 4);   // xp, then h'
  ushort* thi  = (ushort*)carve((size_t)N * CH * 2);  // t1/t2 hi
  ushort* tlo  = (ushort*)carve((size_t)N * CH * 2);  // t1/t2 lo

  hipMemsetAsync(cnt, 0, (size_t)N * 4, stream);

  int eb = (E + 255) / 256;
  int nb = (N + SCAN_CHUNK - 1) / SCAN_CHUNK;
  count_kernel<<<eb, 256, 0, stream>>>(ei, E, cnt);
  scan_sum_kernel<<<nb, 256, 0, stream>>>(cnt, N, bsum);
  scan_bsum_kernel<<<1, 256, 0, stream>>>(bsum, nb, total);
  scan_fin_kernel<<<nb, 256, 0, stream>>>(cnt, N, bsum, total, rowptr, cursor, dinv);
  fill_kernel<<<eb, 256, 0, stream>>>(ei, E, cursor, col);

  wsplit_kernel<<<48, 256, 0, stream>>>(W_base, Wbh, Wbl, W_mu, Wmh, Wml,
                                        W_ls, Wsh, Wsl);

  int pb = (N * (CH / 4) + 255) / 256;
  int ab = (N * 64 + 255) / 256;
  int gb = (N + 127) / 128;

  prescale_kernel<<<pb, 256, 0, stream>>>(x, dinv, bufA, N);
  agg_kernel<<<ab, 256, 0, stream>>>(bufA, rowptr, col, dinv, thi, tlo, N);  // t1
  gemm_mfma_kernel<<<gb, 256, 0, stream>>>(thi, tlo, Wbh, Wbl, b_base,
                                           nullptr, nullptr, nullptr,
                                           dinv, bufA, nullptr, N, 1);       // h'
  agg_kernel<<<ab, 256, 0, stream>>>(bufA, rowptr, col, dinv, thi, tlo, N);  // t2
  gemm_mfma_kernel<<<gb, 256, 0, stream>>>(thi, tlo, Wmh, Wml, b_mu,
                                           Wsh, Wsl, b_ls,
                                           nullptr, out, out + (size_t)N * CH,
                                           N, 2);                            // m, s
}

// Round 7
// 241.058 us; speedup vs baseline: 1.3276x; 1.1259x over previous
//
#include <hip/hip_runtime.h>

// GCN edge-predictor encoder, R7: occupancy-fixed MFMA GEMM.
//   deg/dinv -> CSR -> xp=dinv*x -> t1=gather(xp) [bf16 hi/lo]
//   -> h'=dinv*(t1@Wb+bb) [f32] -> t2=gather(h') [bf16 hi/lo]
//   -> m=relu(t2@Wmu+bmu), s=relu(t2@Wls+bls)
// GEMM: A@W ~= Ah@Wh + Ah@Wl + Al@Wh (split bf16, f32 accum),
// v_mfma_f32_32x32x16_bf16. R6 was occupancy-bound (2.4 waves/CU, grid 391).
// Now: block = 128 rows x 64 cols, W-LDS 32KB, gridDim.y = mat*2+colhalf
// -> 4x blocks, ~5x waves/CU.

#define CH 128
#define SCAN_CHUNK 1024

typedef __attribute__((ext_vector_type(8))) short short8v;
typedef __attribute__((ext_vector_type(16))) float floatx16;

__device__ inline ushort f2bf(float f) {
  uint u = __builtin_bit_cast(uint, f);
  uint r = (u + 0x7FFFu + ((u >> 16) & 1u)) >> 16;
  return (ushort)r;
}
__device__ inline float bf2f(ushort h) {
  uint u = ((uint)h) << 16;
  return __builtin_bit_cast(float, u);
}

__global__ void count_kernel(const int* __restrict__ ei, int E, int* __restrict__ cnt) {
  int e = blockIdx.x * blockDim.x + threadIdx.x;
  if (e < E) atomicAdd(&cnt[ei[E + e]], 1);
}

__global__ __launch_bounds__(256) void scan_sum_kernel(const int* __restrict__ cnt,
    int n, int* __restrict__ bsum) {
  __shared__ int sdata[256];
  int base = blockIdx.x * SCAN_CHUNK;
  int tid = threadIdx.x;
  int s = 0;
  #pragma unroll
  for (int j = 0; j < 4; ++j) {
    int i = base + tid * 4 + j;
    if (i < n) s += cnt[i];
  }
  sdata[tid] = s;
  __syncthreads();
  for (int off = 128; off > 0; off >>= 1) {
    if (tid < off) sdata[tid] += sdata[tid + off];
    __syncthreads();
  }
  if (tid == 0) bsum[blockIdx.x] = sdata[0];
}

__global__ __launch_bounds__(256) void scan_bsum_kernel(int* __restrict__ bsum,
    int nb, int* __restrict__ total_out) {
  __shared__ int sdata[1024];
  int tid = threadIdx.x;
  #pragma unroll
  for (int j = 0; j < 4; ++j) {
    int i = tid * 4 + j;
    sdata[i] = (i < nb) ? bsum[i] : 0;
  }
  __syncthreads();
  if (tid == 0) {
    int run = 0;
    for (int i = 0; i < nb; ++i) { int v = sdata[i]; sdata[i] = run; run += v; }
    *total_out = run;
  }
  __syncthreads();
  #pragma unroll
  for (int j = 0; j < 4; ++j) {
    int i = tid * 4 + j;
    if (i < nb) bsum[i] = sdata[i];
  }
}

__global__ __launch_bounds__(256) void scan_fin_kernel(const int* __restrict__ cnt,
    int n, const int* __restrict__ bsum, const int* __restrict__ total,
    int* __restrict__ rowptr, int* __restrict__ cursor, float* __restrict__ dinv) {
  __shared__ int sthr[256];
  int base = blockIdx.x * SCAN_CHUNK;
  int tid = threadIdx.x;
  int v[4];
  int ts = 0;
  #pragma unroll
  for (int j = 0; j < 4; ++j) {
    int i = base + tid * 4 + j;
    v[j] = (i < n) ? cnt[i] : 0;
    ts += v[j];
  }
  sthr[tid] = ts;
  __syncthreads();
  for (int off = 1; off < 256; off <<= 1) {
    int t = (tid >= off) ? sthr[tid - off] : 0;
    __syncthreads();
    sthr[tid] += t;
    __syncthreads();
  }
  int excl = sthr[tid] - ts + bsum[blockIdx.x];
  #pragma unroll
  for (int j = 0; j < 4; ++j) {
    int i = base + tid * 4 + j;
    if (i < n) {
      rowptr[i] = excl;
      cursor[i] = excl;
      dinv[i]   = rsqrtf((float)(v[j] + 1));
      excl += v[j];
    }
  }
  if (blockIdx.x == 0 && tid == 0) rowptr[n] = *total;
}

__global__ void fill_kernel(const int* __restrict__ ei, int E,
                            int* __restrict__ cursor, int* __restrict__ col) {
  int e = blockIdx.x * blockDim.x + threadIdx.x;
  if (e < E) {
    int d = ei[E + e];
    int pos = atomicAdd(&cursor[d], 1);
    col[pos] = ei[e];
  }
}

// xp[i] = dinv[i] * x[i], float4-vectorized.
__global__ __launch_bounds__(256) void prescale_kernel(const float* __restrict__ x,
    const float* __restrict__ dinv, float* __restrict__ xp, int n) {
  int t = blockIdx.x * 256 + threadIdx.x;
  if (t < n * (CH / 4)) {
    float d = dinv[t >> 5];
    float4 v = ((const float4*)x)[t];
    ((float4*)xp)[t] = make_float4(v.x * d, v.y * d, v.z * d, v.w * d);
  }
}

// Transpose + split W (f32 [128][128], 3 matrices) -> Wt hi/lo bf16 [c][k].
__global__ __launch_bounds__(256) void wsplit_kernel(
    const float* __restrict__ W0, ushort* __restrict__ W0h, ushort* __restrict__ W0l,
    const float* __restrict__ W1, ushort* __restrict__ W1h, ushort* __restrict__ W1l,
    const float* __restrict__ W2, ushort* __restrict__ W2h, ushort* __restrict__ W2l) {
  int m = blockIdx.x >> 4, sl = blockIdx.x & 15;
  const float* W; ushort* Wh; ushort* Wl;
  if (m == 0)      { W = W0; Wh = W0h; Wl = W0l; }
  else if (m == 1) { W = W1; Wh = W1h; Wl = W1l; }
  else             { W = W2; Wh = W2h; Wl = W2l; }
  int o = sl * 1024 + threadIdx.x * 4;   // output idx (c*128+k), 4 per thread
  int c = o >> 7, k = o & 127;
  #pragma unroll
  for (int j = 0; j < 4; ++j) {
    float v = W[(k + j) * 128 + c];
    ushort h = f2bf(v);
    Wh[o + j] = h;
    Wl[o + j] = f2bf(v - bf2f(h));
  }
}

// One wave per node; gather-sum of pre-scaled features; output split bf16.
__global__ __launch_bounds__(256) void agg_kernel(const float* __restrict__ feat,
    const int* __restrict__ rowptr, const int* __restrict__ col,
    const float* __restrict__ dinv, ushort* __restrict__ out_hi,
    ushort* __restrict__ out_lo, int n) {
  int w = (blockIdx.x * 256 + threadIdx.x) >> 6;
  if (w >= n) return;
  int lane = threadIdx.x & 63;
  int g  = lane >> 5;
  int cl = lane & 31;
  const float4* f4 = (const float4*)feat;
  float4 acc = make_float4(0.f, 0.f, 0.f, 0.f);
  if (g == 0) acc = f4[(size_t)w * 32 + cl];   // self-loop term
  int s = rowptr[w], e = rowptr[w + 1];
  int j = s;
  for (; j + 4 <= e; j += 4) {
    int c0 = col[j + g];
    int c1 = col[j + 2 + g];
    float4 v0 = f4[(size_t)c0 * 32 + cl];
    float4 v1 = f4[(size_t)c1 * 32 + cl];
    acc.x += v0.x + v1.x;
    acc.y += v0.y + v1.y;
    acc.z += v0.z + v1.z;
    acc.w += v0.w + v1.w;
  }
  for (; j < e; j += 2) {
    int jj = j + g;
    if (jj < e) {
      int c = col[jj];
      float4 v = f4[(size_t)c * 32 + cl];
      acc.x += v.x; acc.y += v.y; acc.z += v.z; acc.w += v.w;
    }
  }
  acc.x += __shfl_xor(acc.x, 32);
  acc.y += __shfl_xor(acc.y, 32);
  acc.z += __shfl_xor(acc.z, 32);
  acc.w += __shfl_xor(acc.w, 32);
  if (g == 0) {
    float di = dinv[w];
    float v0 = acc.x * di, v1 = acc.y * di, v2 = acc.z * di, v3 = acc.w * di;
    ushort h0 = f2bf(v0), h1 = f2bf(v1), h2 = f2bf(v2), h3 = f2bf(v3);
    ushort l0 = f2bf(v0 - bf2f(h0)), l1 = f2bf(v1 - bf2f(h1));
    ushort l2 = f2bf(v2 - bf2f(h2)), l3 = f2bf(v3 - bf2f(h3));
    ((ushort4*)out_hi)[(size_t)w * 32 + cl] = make_ushort4(h0, h1, h2, h3);
    ((ushort4*)out_lo)[(size_t)w * 32 + cl] = make_ushort4(l0, l1, l2, l3);
  }
}

// MFMA GEMM, col-split: out = post(A@W + b). A = bf16 hi/lo [M][128] (regs),
// W = bf16 hi/lo transposed [c][k], 64-col slice staged in 32KB LDS
// (16B-slot XOR swizzle). Block = 4 waves x 32 rows = 128 rows x 64 cols.
// blockIdx.y = mat*2 + colhalf (launch y=2 for single, y=4 for dual).
// post: dinv != nullptr -> v *= dinv[row]; else v = relu(v).
__global__ __launch_bounds__(256) void gemm_mfma_kernel(
    const ushort* __restrict__ Ahi, const ushort* __restrict__ Alo,
    const ushort* __restrict__ W0h, const ushort* __restrict__ W0l,
    const float* __restrict__ b0,
    const ushort* __restrict__ W1h, const ushort* __restrict__ W1l,
    const float* __restrict__ b1,
    const float* __restrict__ dinv,
    float* __restrict__ out0, float* __restrict__ out1,
    int M) {
  __shared__ ushort Wh[64 * 128];    // 16KB, swizzled 16B slots
  __shared__ ushort Wl[64 * 128];    // 16KB

  const int mat = blockIdx.y >> 1;
  const int c0  = (blockIdx.y & 1) * 64;
  const uint4* GH = (const uint4*)(mat ? W1h : W0h);
  const uint4* GL = (const uint4*)(mat ? W1l : W0l);
  const float* bb = mat ? b1 : b0;
  float*     outp = mat ? out1 : out0;

  const int tid  = threadIdx.x;
  const int lane = tid & 63;
  const int wv   = tid >> 6;         // wave id 0..3
  const int rA   = lane & 31;        // A row-in-tile / W col-in-tile
  const int kh   = lane >> 5;        // k half
  const int row  = blockIdx.x * 128 + wv * 32 + rA;
  const bool rowok = row < M;

  // stage W cols [c0, c0+64), hi/lo: 1024 16B slots each
  {
    uint4* LH = (uint4*)Wh;
    uint4* LL = (uint4*)Wl;
    #pragma unroll
    for (int t = 0; t < 4; ++t) {
      int q = tid + t * 256;         // 0..1023
      int wr = q >> 4, ls = q & 15;
      int phys = ls ^ (wr & 15);
      LH[wr * 16 + phys] = GH[(c0 + wr) * 16 + ls];
      LL[wr * 16 + phys] = GL[(c0 + wr) * 16 + ls];
    }
  }

  const short8v* AH = (const short8v*)Ahi;
  const short8v* AL = (const short8v*)Alo;
  const short8v zero8 = {0, 0, 0, 0, 0, 0, 0, 0};

  // A fragments for all 8 k-chunks (16B each).
  short8v ah[8], al[8];
  #pragma unroll
  for (int kc = 0; kc < 8; ++kc) {
    int fi = row * 16 + kc * 2 + kh;
    ah[kc] = rowok ? AH[fi] : zero8;
    al[kc] = rowok ? AL[fi] : zero8;
  }

  __syncthreads();

  floatx16 acc[2];
  #pragma unroll
  for (int t = 0; t < 2; ++t)
    #pragma unroll
    for (int j = 0; j < 16; ++j) acc[t][j] = 0.f;

  const short8v* WHv = (const short8v*)Wh;
  const short8v* WLv = (const short8v*)Wl;

  #pragma unroll
  for (int kc = 0; kc < 8; ++kc) {
    int fk = kc * 2 + kh;
    int ph = fk ^ (rA & 15);         // swizzled slot (wrow&15 == rA&15)
    short8v wh[2], wl[2];
    #pragma unroll
    for (int t = 0; t < 2; ++t) {
      wh[t] = WHv[(t * 32 + rA) * 16 + ph];
      wl[t] = WLv[(t * 32 + rA) * 16 + ph];
    }
    #pragma unroll
    for (int t = 0; t < 2; ++t)
      acc[t] = __builtin_amdgcn_mfma_f32_32x32x16_bf16(ah[kc], wh[t], acc[t], 0, 0, 0);
    #pragma unroll
    for (int t = 0; t < 2; ++t)
      acc[t] = __builtin_amdgcn_mfma_f32_32x32x16_bf16(ah[kc], wl[t], acc[t], 0, 0, 0);
    #pragma unroll
    for (int t = 0; t < 2; ++t)
      acc[t] = __builtin_amdgcn_mfma_f32_32x32x16_bf16(al[kc], wh[t], acc[t], 0, 0, 0);
  }

  float bcol[2];
  #pragma unroll
  for (int t = 0; t < 2; ++t) bcol[t] = bb[c0 + t * 32 + rA];
  #pragma unroll
  for (int t = 0; t < 2; ++t) {
    #pragma unroll
    for (int r = 0; r < 16; ++r) {
      int r32 = (r & 3) + 8 * (r >> 2) + 4 * kh;
      int orow = blockIdx.x * 128 + wv * 32 + r32;
      if (orow < M) {
        float v = acc[t][r] + bcol[t];
        if (dinv) v *= dinv[orow];
        else      v = fmaxf(v, 0.f);
        outp[(size_t)orow * CH + c0 + t * 32 + rA] = v;
      }
    }
  }
}

extern "C" void kernel_launch(void* const* d_in, const int* in_sizes, int n_in,
                              void* d_out, int out_size, void* d_ws, size_t ws_size,
                              hipStream_t stream) {
  const float* x      = (const float*)d_in[0];
  const int*   ei     = (const int*)d_in[1];
  const float* W_base = (const float*)d_in[2];
  const float* b_base = (const float*)d_in[3];
  const float* W_mu   = (const float*)d_in[4];
  const float* b_mu   = (const float*)d_in[5];
  const float* W_ls   = (const float*)d_in[6];
  const float* b_ls   = (const float*)d_in[7];
  float* out = (float*)d_out;

  const int N = in_sizes[0] / CH;
  const int E = in_sizes[1] / 2;

  char* ws = (char*)d_ws;
  size_t off = 0;
  auto carve = [&](size_t bytes) -> void* {
    void* p = ws + off;
    off += (bytes + 511) & ~(size_t)511;
    return p;
  };
  int*    cnt    = (int*)carve((size_t)N * 4);
  int*    rowptr = (int*)carve((size_t)(N + 1) * 4);
  int*    cursor = (int*)carve((size_t)N * 4);
  int*    col    = (int*)carve((size_t)E * 4);
  float*  dinv   = (float*)carve((size_t)N * 4);
  int*    bsum   = (int*)carve((size_t)2048 * 4);
  int*    total  = (int*)carve((size_t)4);
  ushort* Wbh = (ushort*)carve((size_t)CH * CH * 2);
  ushort* Wbl = (ushort*)carve((size_t)CH * CH * 2);
  ushort* Wmh = (ushort*)carve((size_t)CH * CH * 2);
  ushort* Wml = (ushort*)carve((size_t)CH * CH * 2);
  ushort* Wsh = (ushort*)carve((size_t)CH * CH * 2);
  ushort* Wsl = (ushort*)carve((size_t)CH * CH * 2);
  float*  bufA = (float*)carve((size_t)N * CH * 4);   // xp, then h'
  ushort* thi  = (ushort*)carve((size_t)N * CH * 2);  // t1/t2 hi
  ushort* tlo  = (ushort*)carve((size_t)N * CH * 2);  // t1/t2 lo

  hipMemsetAsync(cnt, 0, (size_t)N * 4, stream);

  int eb = (E + 255) / 256;
  int nb = (N + SCAN_CHUNK - 1) / SCAN_CHUNK;
  count_kernel<<<eb, 256, 0, stream>>>(ei, E, cnt);
  scan_sum_kernel<<<nb, 256, 0, stream>>>(cnt, N, bsum);
  scan_bsum_kernel<<<1, 256, 0, stream>>>(bsum, nb, total);
  scan_fin_kernel<<<nb, 256, 0, stream>>>(cnt, N, bsum, total, rowptr, cursor, dinv);
  fill_kernel<<<eb, 256, 0, stream>>>(ei, E, cursor, col);

  wsplit_kernel<<<48, 256, 0, stream>>>(W_base, Wbh, Wbl, W_mu, Wmh, Wml,
                                        W_ls, Wsh, Wsl);

  int pb = (N * (CH / 4) + 255) / 256;
  int ab = (N * 64 + 255) / 256;
  int gb = (N + 127) / 128;

  prescale_kernel<<<pb, 256, 0, stream>>>(x, dinv, bufA, N);
  agg_kernel<<<ab, 256, 0, stream>>>(bufA, rowptr, col, dinv, thi, tlo, N);  // t1
  gemm_mfma_kernel<<<dim3(gb, 2), 256, 0, stream>>>(thi, tlo, Wbh, Wbl, b_base,
                                           nullptr, nullptr, nullptr,
                                           dinv, bufA, nullptr, N);          // h'
  agg_kernel<<<ab, 256, 0, stream>>>(bufA, rowptr, col, dinv, thi, tlo, N);  // t2
  gemm_mfma_kernel<<<dim3(gb, 4), 256, 0, stream>>>(thi, tlo, Wmh, Wml, b_mu,
                                           Wsh, Wsl, b_ls,
                                           nullptr, out, out + (size_t)N * CH,
                                           N);                               // m, s
}

// Round 8
// 228.508 us; speedup vs baseline: 1.4005x; 1.0549x over previous
//
#include <hip/hip_runtime.h>

// GCN edge-predictor encoder, R8: high-MLP gather + fused prescale.
//   deg/dinv -> CSR -> t1=gather(dinv*x)*dinv [bf16 hi/lo]
//   -> h'=dinv*(t1@Wb+bb) [f32] -> t2=gather(h')*dinv [bf16 hi/lo]
//   -> m=relu(t2@Wmu+bmu), s=relu(t2@Wls+bls)
// agg: one wave/node, 4 edge-groups x 16 lanes x 32B (float8/row-half),
// unroll x2 -> 8 rows (4KB) in flight per wave-iter (R7 had 2). srcscale
// (dinv[src]) fused for layer 1 -> prescale kernel deleted.
// GEMM (R7): split-bf16 MFMA, W-slice in 32KB swizzled LDS, col+mat grid.y.

#define CH 128
#define SCAN_CHUNK 1024

typedef __attribute__((ext_vector_type(8))) short short8v;
typedef __attribute__((ext_vector_type(16))) float floatx16;

__device__ inline ushort f2bf(float f) {
  uint u = __builtin_bit_cast(uint, f);
  uint r = (u + 0x7FFFu + ((u >> 16) & 1u)) >> 16;
  return (ushort)r;
}
__device__ inline float bf2f(ushort h) {
  uint u = ((uint)h) << 16;
  return __builtin_bit_cast(float, u);
}

__global__ void count_kernel(const int* __restrict__ ei, int E, int* __restrict__ cnt) {
  int e = blockIdx.x * blockDim.x + threadIdx.x;
  if (e < E) atomicAdd(&cnt[ei[E + e]], 1);
}

__global__ __launch_bounds__(256) void scan_sum_kernel(const int* __restrict__ cnt,
    int n, int* __restrict__ bsum) {
  __shared__ int sdata[256];
  int base = blockIdx.x * SCAN_CHUNK;
  int tid = threadIdx.x;
  int s = 0;
  #pragma unroll
  for (int j = 0; j < 4; ++j) {
    int i = base + tid * 4 + j;
    if (i < n) s += cnt[i];
  }
  sdata[tid] = s;
  __syncthreads();
  for (int off = 128; off > 0; off >>= 1) {
    if (tid < off) sdata[tid] += sdata[tid + off];
    __syncthreads();
  }
  if (tid == 0) bsum[blockIdx.x] = sdata[0];
}

__global__ __launch_bounds__(256) void scan_bsum_kernel(int* __restrict__ bsum,
    int nb, int* __restrict__ total_out) {
  __shared__ int sdata[1024];
  int tid = threadIdx.x;
  #pragma unroll
  for (int j = 0; j < 4; ++j) {
    int i = tid * 4 + j;
    sdata[i] = (i < nb) ? bsum[i] : 0;
  }
  __syncthreads();
  if (tid == 0) {
    int run = 0;
    for (int i = 0; i < nb; ++i) { int v = sdata[i]; sdata[i] = run; run += v; }
    *total_out = run;
  }
  __syncthreads();
  #pragma unroll
  for (int j = 0; j < 4; ++j) {
    int i = tid * 4 + j;
    if (i < nb) bsum[i] = sdata[i];
  }
}

__global__ __launch_bounds__(256) void scan_fin_kernel(const int* __restrict__ cnt,
    int n, const int* __restrict__ bsum, const int* __restrict__ total,
    int* __restrict__ rowptr, int* __restrict__ cursor, float* __restrict__ dinv) {
  __shared__ int sthr[256];
  int base = blockIdx.x * SCAN_CHUNK;
  int tid = threadIdx.x;
  int v[4];
  int ts = 0;
  #pragma unroll
  for (int j = 0; j < 4; ++j) {
    int i = base + tid * 4 + j;
    v[j] = (i < n) ? cnt[i] : 0;
    ts += v[j];
  }
  sthr[tid] = ts;
  __syncthreads();
  for (int off = 1; off < 256; off <<= 1) {
    int t = (tid >= off) ? sthr[tid - off] : 0;
    __syncthreads();
    sthr[tid] += t;
    __syncthreads();
  }
  int excl = sthr[tid] - ts + bsum[blockIdx.x];
  #pragma unroll
  for (int j = 0; j < 4; ++j) {
    int i = base + tid * 4 + j;
    if (i < n) {
      rowptr[i] = excl;
      cursor[i] = excl;
      dinv[i]   = rsqrtf((float)(v[j] + 1));
      excl += v[j];
    }
  }
  if (blockIdx.x == 0 && tid == 0) rowptr[n] = *total;
}

__global__ void fill_kernel(const int* __restrict__ ei, int E,
                            int* __restrict__ cursor, int* __restrict__ col) {
  int e = blockIdx.x * blockDim.x + threadIdx.x;
  if (e < E) {
    int d = ei[E + e];
    int pos = atomicAdd(&cursor[d], 1);
    col[pos] = ei[e];
  }
}

// Transpose + split W (f32 [128][128], 3 matrices) -> Wt hi/lo bf16 [c][k].
__global__ __launch_bounds__(256) void wsplit_kernel(
    const float* __restrict__ W0, ushort* __restrict__ W0h, ushort* __restrict__ W0l,
    const float* __restrict__ W1, ushort* __restrict__ W1h, ushort* __restrict__ W1l,
    const float* __restrict__ W2, ushort* __restrict__ W2h, ushort* __restrict__ W2l) {
  int m = blockIdx.x >> 4, sl = blockIdx.x & 15;
  const float* W; ushort* Wh; ushort* Wl;
  if (m == 0)      { W = W0; Wh = W0h; Wl = W0l; }
  else if (m == 1) { W = W1; Wh = W1h; Wl = W1l; }
  else             { W = W2; Wh = W2h; Wl = W2l; }
  int o = sl * 1024 + threadIdx.x * 4;   // output idx (c*128+k), 4 per thread
  int c = o >> 7, k = o & 127;
  #pragma unroll
  for (int j = 0; j < 4; ++j) {
    float v = W[(k + j) * 128 + c];
    ushort h = f2bf(v);
    Wh[o + j] = h;
    Wl[o + j] = f2bf(v - bf2f(h));
  }
}

// One wave per node; 4 edge-groups of 16 lanes, 32B (2xfloat4) per lane.
// srcscale != null (layer 1): row src scaled by srcscale[src], self by di.
// out = di * acc, written as split bf16.
__global__ __launch_bounds__(256) void agg_kernel(const float* __restrict__ feat,
    const int* __restrict__ rowptr, const int* __restrict__ col,
    const float* __restrict__ dinv, const float* __restrict__ srcscale,
    ushort* __restrict__ out_hi, ushort* __restrict__ out_lo, int n) {
  int w = (blockIdx.x * 256 + threadIdx.x) >> 6;
  if (w >= n) return;
  int lane = threadIdx.x & 63;
  int g  = lane >> 4;        // edge group 0..3
  int cl = lane & 15;        // 32B chunk: float4 idx cl*2, cl*2+1
  const float4* f4 = (const float4*)feat;
  float di = dinv[w];
  float4 a0 = make_float4(0.f, 0.f, 0.f, 0.f);
  float4 a1 = make_float4(0.f, 0.f, 0.f, 0.f);
  if (g == 0) {              // self-loop term
    float ss = srcscale ? di : 1.f;
    float4 v0 = f4[(size_t)w * 32 + cl * 2];
    float4 v1 = f4[(size_t)w * 32 + cl * 2 + 1];
    a0 = make_float4(ss * v0.x, ss * v0.y, ss * v0.z, ss * v0.w);
    a1 = make_float4(ss * v1.x, ss * v1.y, ss * v1.z, ss * v1.w);
  }
  int s = rowptr[w], e = rowptr[w + 1];
  int j = s;
  for (; j + 8 <= e; j += 8) {
    int c0 = col[j + g];
    int c1 = col[j + 4 + g];
    float s0 = srcscale ? srcscale[c0] : 1.f;
    float s1 = srcscale ? srcscale[c1] : 1.f;
    float4 v00 = f4[(size_t)c0 * 32 + cl * 2];
    float4 v01 = f4[(size_t)c0 * 32 + cl * 2 + 1];
    float4 v10 = f4[(size_t)c1 * 32 + cl * 2];
    float4 v11 = f4[(size_t)c1 * 32 + cl * 2 + 1];
    a0.x = fmaf(s0, v00.x, fmaf(s1, v10.x, a0.x));
    a0.y = fmaf(s0, v00.y, fmaf(s1, v10.y, a0.y));
    a0.z = fmaf(s0, v00.z, fmaf(s1, v10.z, a0.z));
    a0.w = fmaf(s0, v00.w, fmaf(s1, v10.w, a0.w));
    a1.x = fmaf(s0, v01.x, fmaf(s1, v11.x, a1.x));
    a1.y = fmaf(s0, v01.y, fmaf(s1, v11.y, a1.y));
    a1.z = fmaf(s0, v01.z, fmaf(s1, v11.z, a1.z));
    a1.w = fmaf(s0, v01.w, fmaf(s1, v11.w, a1.w));
  }
  for (; j < e; j += 4) {
    int jj = j + g;
    if (jj < e) {
      int c = col[jj];
      float s0 = srcscale ? srcscale[c] : 1.f;
      float4 v0 = f4[(size_t)c * 32 + cl * 2];
      float4 v1 = f4[(size_t)c * 32 + cl * 2 + 1];
      a0.x = fmaf(s0, v0.x, a0.x); a0.y = fmaf(s0, v0.y, a0.y);
      a0.z = fmaf(s0, v0.z, a0.z); a0.w = fmaf(s0, v0.w, a0.w);
      a1.x = fmaf(s0, v1.x, a1.x); a1.y = fmaf(s0, v1.y, a1.y);
      a1.z = fmaf(s0, v1.z, a1.z); a1.w = fmaf(s0, v1.w, a1.w);
    }
  }
  // reduce across the 4 groups (xor 16, then 32)
  #pragma unroll
  for (int m = 16; m <= 32; m <<= 1) {
    a0.x += __shfl_xor(a0.x, m); a0.y += __shfl_xor(a0.y, m);
    a0.z += __shfl_xor(a0.z, m); a0.w += __shfl_xor(a0.w, m);
    a1.x += __shfl_xor(a1.x, m); a1.y += __shfl_xor(a1.y, m);
    a1.z += __shfl_xor(a1.z, m); a1.w += __shfl_xor(a1.w, m);
  }
  if (g == 0) {
    float r[8] = {a0.x * di, a0.y * di, a0.z * di, a0.w * di,
                  a1.x * di, a1.y * di, a1.z * di, a1.w * di};
    ushort h[8], l[8];
    #pragma unroll
    for (int i = 0; i < 8; ++i) {
      h[i] = f2bf(r[i]);
      l[i] = f2bf(r[i] - bf2f(h[i]));
    }
    size_t o = (size_t)w * 32 + cl * 2;
    ((ushort4*)out_hi)[o]     = make_ushort4(h[0], h[1], h[2], h[3]);
    ((ushort4*)out_hi)[o + 1] = make_ushort4(h[4], h[5], h[6], h[7]);
    ((ushort4*)out_lo)[o]     = make_ushort4(l[0], l[1], l[2], l[3]);
    ((ushort4*)out_lo)[o + 1] = make_ushort4(l[4], l[5], l[6], l[7]);
  }
}

// MFMA GEMM, col-split: out = post(A@W + b). A = bf16 hi/lo [M][128] (regs),
// W = bf16 hi/lo transposed [c][k], 64-col slice staged in 32KB LDS
// (16B-slot XOR swizzle). Block = 4 waves x 32 rows = 128 rows x 64 cols.
// blockIdx.y = mat*2 + colhalf (launch y=2 for single, y=4 for dual).
// post: dinv != nullptr -> v *= dinv[row]; else v = relu(v).
__global__ __launch_bounds__(256) void gemm_mfma_kernel(
    const ushort* __restrict__ Ahi, const ushort* __restrict__ Alo,
    const ushort* __restrict__ W0h, const ushort* __restrict__ W0l,
    const float* __restrict__ b0,
    const ushort* __restrict__ W1h, const ushort* __restrict__ W1l,
    const float* __restrict__ b1,
    const float* __restrict__ dinv,
    float* __restrict__ out0, float* __restrict__ out1,
    int M) {
  __shared__ ushort Wh[64 * 128];    // 16KB, swizzled 16B slots
  __shared__ ushort Wl[64 * 128];    // 16KB

  const int mat = blockIdx.y >> 1;
  const int c0  = (blockIdx.y & 1) * 64;
  const uint4* GH = (const uint4*)(mat ? W1h : W0h);
  const uint4* GL = (const uint4*)(mat ? W1l : W0l);
  const float* bb = mat ? b1 : b0;
  float*     outp = mat ? out1 : out0;

  const int tid  = threadIdx.x;
  const int lane = tid & 63;
  const int wv   = tid >> 6;         // wave id 0..3
  const int rA   = lane & 31;        // A row-in-tile / W col-in-tile
  const int kh   = lane >> 5;        // k half
  const int row  = blockIdx.x * 128 + wv * 32 + rA;
  const bool rowok = row < M;

  // stage W cols [c0, c0+64), hi/lo: 1024 16B slots each
  {
    uint4* LH = (uint4*)Wh;
    uint4* LL = (uint4*)Wl;
    #pragma unroll
    for (int t = 0; t < 4; ++t) {
      int q = tid + t * 256;         // 0..1023
      int wr = q >> 4, ls = q & 15;
      int phys = ls ^ (wr & 15);
      LH[wr * 16 + phys] = GH[(c0 + wr) * 16 + ls];
      LL[wr * 16 + phys] = GL[(c0 + wr) * 16 + ls];
    }
  }

  const short8v* AH = (const short8v*)Ahi;
  const short8v* AL = (const short8v*)Alo;
  const short8v zero8 = {0, 0, 0, 0, 0, 0, 0, 0};

  // A fragments for all 8 k-chunks (16B each).
  short8v ah[8], al[8];
  #pragma unroll
  for (int kc = 0; kc < 8; ++kc) {
    int fi = row * 16 + kc * 2 + kh;
    ah[kc] = rowok ? AH[fi] : zero8;
    al[kc] = rowok ? AL[fi] : zero8;
  }

  __syncthreads();

  floatx16 acc[2];
  #pragma unroll
  for (int t = 0; t < 2; ++t)
    #pragma unroll
    for (int j = 0; j < 16; ++j) acc[t][j] = 0.f;

  const short8v* WHv = (const short8v*)Wh;
  const short8v* WLv = (const short8v*)Wl;

  #pragma unroll
  for (int kc = 0; kc < 8; ++kc) {
    int fk = kc * 2 + kh;
    int ph = fk ^ (rA & 15);         // swizzled slot (wrow&15 == rA&15)
    short8v wh[2], wl[2];
    #pragma unroll
    for (int t = 0; t < 2; ++t) {
      wh[t] = WHv[(t * 32 + rA) * 16 + ph];
      wl[t] = WLv[(t * 32 + rA) * 16 + ph];
    }
    #pragma unroll
    for (int t = 0; t < 2; ++t)
      acc[t] = __builtin_amdgcn_mfma_f32_32x32x16_bf16(ah[kc], wh[t], acc[t], 0, 0, 0);
    #pragma unroll
    for (int t = 0; t < 2; ++t)
      acc[t] = __builtin_amdgcn_mfma_f32_32x32x16_bf16(ah[kc], wl[t], acc[t], 0, 0, 0);
    #pragma unroll
    for (int t = 0; t < 2; ++t)
      acc[t] = __builtin_amdgcn_mfma_f32_32x32x16_bf16(al[kc], wh[t], acc[t], 0, 0, 0);
  }

  float bcol[2];
  #pragma unroll
  for (int t = 0; t < 2; ++t) bcol[t] = bb[c0 + t * 32 + rA];
  #pragma unroll
  for (int t = 0; t < 2; ++t) {
    #pragma unroll
    for (int r = 0; r < 16; ++r) {
      int r32 = (r & 3) + 8 * (r >> 2) + 4 * kh;
      int orow = blockIdx.x * 128 + wv * 32 + r32;
      if (orow < M) {
        float v = acc[t][r] + bcol[t];
        if (dinv) v *= dinv[orow];
        else      v = fmaxf(v, 0.f);
        outp[(size_t)orow * CH + c0 + t * 32 + rA] = v;
      }
    }
  }
}

extern "C" void kernel_launch(void* const* d_in, const int* in_sizes, int n_in,
                              void* d_out, int out_size, void* d_ws, size_t ws_size,
                              hipStream_t stream) {
  const float* x      = (const float*)d_in[0];
  const int*   ei     = (const int*)d_in[1];
  const float* W_base = (const float*)d_in[2];
  const float* b_base = (const float*)d_in[3];
  const float* W_mu   = (const float*)d_in[4];
  const float* b_mu   = (const float*)d_in[5];
  const float* W_ls   = (const float*)d_in[6];
  const float* b_ls   = (const float*)d_in[7];
  float* out = (float*)d_out;

  const int N = in_sizes[0] / CH;
  const int E = in_sizes[1] / 2;

  char* ws = (char*)d_ws;
  size_t off = 0;
  auto carve = [&](size_t bytes) -> void* {
    void* p = ws + off;
    off += (bytes + 511) & ~(size_t)511;
    return p;
  };
  int*    cnt    = (int*)carve((size_t)N * 4);
  int*    rowptr = (int*)carve((size_t)(N + 1) * 4);
  int*    cursor = (int*)carve((size_t)N * 4);
  int*    col    = (int*)carve((size_t)E * 4);
  float*  dinv   = (float*)carve((size_t)N * 4);
  int*    bsum   = (int*)carve((size_t)2048 * 4);
  int*    total  = (int*)carve((size_t)4);
  ushort* Wbh = (ushort*)carve((size_t)CH * CH * 2);
  ushort* Wbl = (ushort*)carve((size_t)CH * CH * 2);
  ushort* Wmh = (ushort*)carve((size_t)CH * CH * 2);
  ushort* Wml = (ushort*)carve((size_t)CH * CH * 2);
  ushort* Wsh = (ushort*)carve((size_t)CH * CH * 2);
  ushort* Wsl = (ushort*)carve((size_t)CH * CH * 2);
  float*  bufA = (float*)carve((size_t)N * CH * 4);   // h'
  ushort* thi  = (ushort*)carve((size_t)N * CH * 2);  // t1/t2 hi
  ushort* tlo  = (ushort*)carve((size_t)N * CH * 2);  // t1/t2 lo

  hipMemsetAsync(cnt, 0, (size_t)N * 4, stream);

  int eb = (E + 255) / 256;
  int nb = (N + SCAN_CHUNK - 1) / SCAN_CHUNK;
  count_kernel<<<eb, 256, 0, stream>>>(ei, E, cnt);
  scan_sum_kernel<<<nb, 256, 0, stream>>>(cnt, N, bsum);
  scan_bsum_kernel<<<1, 256, 0, stream>>>(bsum, nb, total);
  scan_fin_kernel<<<nb, 256, 0, stream>>>(cnt, N, bsum, total, rowptr, cursor, dinv);
  fill_kernel<<<eb, 256, 0, stream>>>(ei, E, cursor, col);

  wsplit_kernel<<<48, 256, 0, stream>>>(W_base, Wbh, Wbl, W_mu, Wmh, Wml,
                                        W_ls, Wsh, Wsl);

  int ab = (N * 64 + 255) / 256;
  int gb = (N + 127) / 128;

  // t1 = gather(dinv*x) * dinv  (prescale fused via srcscale=dinv)
  agg_kernel<<<ab, 256, 0, stream>>>(x, rowptr, col, dinv, dinv, thi, tlo, N);
  gemm_mfma_kernel<<<dim3(gb, 2), 256, 0, stream>>>(thi, tlo, Wbh, Wbl, b_base,
                                           nullptr, nullptr, nullptr,
                                           dinv, bufA, nullptr, N);          // h'
  // t2 = gather(h') * dinv  (h' already carries its dinv factor)
  agg_kernel<<<ab, 256, 0, stream>>>(bufA, rowptr, col, dinv, nullptr, thi, tlo, N);
  gemm_mfma_kernel<<<dim3(gb, 4), 256, 0, stream>>>(thi, tlo, Wmh, Wml, b_mu,
                                           Wsh, Wsl, b_ls,
                                           nullptr, out, out + (size_t)N * CH,
                                           N);                               // m, s
}

// Round 9
// 212.374 us; speedup vs baseline: 1.5069x; 1.0760x over previous
//
#include <hip/hip_runtime.h>

// GCN edge-predictor encoder, R9: linearized network (layer 1 has NO relu!).
//   m = relu(A^2 x (Wb@Wmu) + (A1)(bb@Wmu) + bmu), s likewise with W_ls.
//   deg/dinv -> CSR -> t1 = A@x (f32) -> z = A@t1 (split bf16) + r = A@1
//   -> wcomb: Wcm=Wb@Wmu, Wcs=Wb@Wls, pm=bb@Wmu, ps=bb@Wls -> split
//   -> dual MFMA gemm: m,s = relu(z@Wc + r*p + b)
// Gather: one wave/node, 4 edge-groups x 16 lanes x 32B, srcscale=dinv.
// GEMM: split-bf16 (Ah@Wh+Ah@Wl+Al@Wh) 32x32x16 MFMA, W-slice in 32KB
// swizzled LDS, grid.y = mat*2+colhalf.

#define CH 128
#define SCAN_CHUNK 1024

typedef __attribute__((ext_vector_type(8))) short short8v;
typedef __attribute__((ext_vector_type(16))) float floatx16;

__device__ inline ushort f2bf(float f) {
  uint u = __builtin_bit_cast(uint, f);
  uint r = (u + 0x7FFFu + ((u >> 16) & 1u)) >> 16;
  return (ushort)r;
}
__device__ inline float bf2f(ushort h) {
  uint u = ((uint)h) << 16;
  return __builtin_bit_cast(float, u);
}

__global__ void count_kernel(const int* __restrict__ ei, int E, int* __restrict__ cnt) {
  int e = blockIdx.x * blockDim.x + threadIdx.x;
  if (e < E) atomicAdd(&cnt[ei[E + e]], 1);
}

__global__ __launch_bounds__(256) void scan_sum_kernel(const int* __restrict__ cnt,
    int n, int* __restrict__ bsum) {
  __shared__ int sdata[256];
  int base = blockIdx.x * SCAN_CHUNK;
  int tid = threadIdx.x;
  int s = 0;
  #pragma unroll
  for (int j = 0; j < 4; ++j) {
    int i = base + tid * 4 + j;
    if (i < n) s += cnt[i];
  }
  sdata[tid] = s;
  __syncthreads();
  for (int off = 128; off > 0; off >>= 1) {
    if (tid < off) sdata[tid] += sdata[tid + off];
    __syncthreads();
  }
  if (tid == 0) bsum[blockIdx.x] = sdata[0];
}

__global__ __launch_bounds__(256) void scan_bsum_kernel(int* __restrict__ bsum,
    int nb, int* __restrict__ total_out) {
  __shared__ int sdata[1024];
  int tid = threadIdx.x;
  #pragma unroll
  for (int j = 0; j < 4; ++j) {
    int i = tid * 4 + j;
    sdata[i] = (i < nb) ? bsum[i] : 0;
  }
  __syncthreads();
  if (tid == 0) {
    int run = 0;
    for (int i = 0; i < nb; ++i) { int v = sdata[i]; sdata[i] = run; run += v; }
    *total_out = run;
  }
  __syncthreads();
  #pragma unroll
  for (int j = 0; j < 4; ++j) {
    int i = tid * 4 + j;
    if (i < nb) bsum[i] = sdata[i];
  }
}

__global__ __launch_bounds__(256) void scan_fin_kernel(const int* __restrict__ cnt,
    int n, const int* __restrict__ bsum, const int* __restrict__ total,
    int* __restrict__ rowptr, int* __restrict__ cursor, float* __restrict__ dinv) {
  __shared__ int sthr[256];
  int base = blockIdx.x * SCAN_CHUNK;
  int tid = threadIdx.x;
  int v[4];
  int ts = 0;
  #pragma unroll
  for (int j = 0; j < 4; ++j) {
    int i = base + tid * 4 + j;
    v[j] = (i < n) ? cnt[i] : 0;
    ts += v[j];
  }
  sthr[tid] = ts;
  __syncthreads();
  for (int off = 1; off < 256; off <<= 1) {
    int t = (tid >= off) ? sthr[tid - off] : 0;
    __syncthreads();
    sthr[tid] += t;
    __syncthreads();
  }
  int excl = sthr[tid] - ts + bsum[blockIdx.x];
  #pragma unroll
  for (int j = 0; j < 4; ++j) {
    int i = base + tid * 4 + j;
    if (i < n) {
      rowptr[i] = excl;
      cursor[i] = excl;
      dinv[i]   = rsqrtf((float)(v[j] + 1));
      excl += v[j];
    }
  }
  if (blockIdx.x == 0 && tid == 0) rowptr[n] = *total;
}

__global__ void fill_kernel(const int* __restrict__ ei, int E,
                            int* __restrict__ cursor, int* __restrict__ col) {
  int e = blockIdx.x * blockDim.x + threadIdx.x;
  if (e < E) {
    int d = ei[E + e];
    int pos = atomicAdd(&cursor[d], 1);
    col[pos] = ei[e];
  }
}

// Wcm = Wb@Wmu, Wcs = Wb@Wls (f32 [k][c]); pm = bb@Wmu, ps = bb@Wls.
// Blocks 0-31: matrix products (16 per matrix). Block 32: bias products.
__global__ __launch_bounds__(256) void wcomb_kernel(
    const float* __restrict__ Wb, const float* __restrict__ bb,
    const float* __restrict__ Wmu, const float* __restrict__ Wls,
    float* __restrict__ Wcm, float* __restrict__ Wcs,
    float* __restrict__ pm, float* __restrict__ ps) {
  int gid = blockIdx.x;
  if (gid < 32) {
    int sel = gid >> 4;
    const float* W2 = sel ? Wls : Wmu;
    float* outp = sel ? Wcs : Wcm;
    int o = (gid & 15) * 1024 + threadIdx.x * 4;
    int k = o >> 7, c = o & 127;
    float acc0 = 0.f, acc1 = 0.f, acc2 = 0.f, acc3 = 0.f;
    for (int j = 0; j < 128; ++j) {
      float a = Wb[k * 128 + j];
      const float* wr = &W2[j * 128 + c];
      acc0 = fmaf(a, wr[0], acc0);
      acc1 = fmaf(a, wr[1], acc1);
      acc2 = fmaf(a, wr[2], acc2);
      acc3 = fmaf(a, wr[3], acc3);
    }
    *((float4*)&outp[o]) = make_float4(acc0, acc1, acc2, acc3);
  } else {
    int t = threadIdx.x;
    int sel = t >> 7, c = t & 127;
    const float* W2 = sel ? Wls : Wmu;
    float acc = 0.f;
    for (int j = 0; j < 128; ++j) acc = fmaf(bb[j], W2[j * 128 + c], acc);
    (sel ? ps : pm)[c] = acc;
  }
}

// Transpose + split W (f32 [k][c], 2 matrices) -> Wt hi/lo bf16 [c][k].
__global__ __launch_bounds__(256) void wsplit_kernel(
    const float* __restrict__ W0, ushort* __restrict__ W0h, ushort* __restrict__ W0l,
    const float* __restrict__ W1, ushort* __restrict__ W1h, ushort* __restrict__ W1l) {
  int m = blockIdx.x >> 4, sl = blockIdx.x & 15;
  const float* W = m ? W1 : W0;
  ushort* Wh = m ? W1h : W0h;
  ushort* Wl = m ? W1l : W0l;
  int o = sl * 1024 + threadIdx.x * 4;   // output idx (c*128+k), 4 per thread
  int c = o >> 7, k = o & 127;
  #pragma unroll
  for (int j = 0; j < 4; ++j) {
    float v = W[(k + j) * 128 + c];
    ushort h = f2bf(v);
    Wh[o + j] = h;
    Wl[o + j] = f2bf(v - bf2f(h));
  }
}

// One wave per node; 4 edge-groups of 16 lanes, 32B (2xfloat4) per lane.
// out[w] = dinv[w] * ( dinv[w]*feat[w] + sum_src dinv[src]*feat[src] ).
// Output: f32 (out_f32) or split bf16 (out_hi/lo).
// r_out (optional): r[w] = dinv[w]*(dinv[w] + sum_src dinv[src]) = (A@1)[w].
__global__ __launch_bounds__(256) void agg_kernel(const float* __restrict__ feat,
    const int* __restrict__ rowptr, const int* __restrict__ col,
    const float* __restrict__ dinv,
    float* __restrict__ out_f32, ushort* __restrict__ out_hi,
    ushort* __restrict__ out_lo, float* __restrict__ r_out, int n) {
  int w = (blockIdx.x * 256 + threadIdx.x) >> 6;
  if (w >= n) return;
  int lane = threadIdx.x & 63;
  int g  = lane >> 4;        // edge group 0..3
  int cl = lane & 15;        // 32B chunk: float4 idx cl*2, cl*2+1
  const float4* f4 = (const float4*)feat;
  float di = dinv[w];
  float4 a0 = make_float4(0.f, 0.f, 0.f, 0.f);
  float4 a1 = make_float4(0.f, 0.f, 0.f, 0.f);
  float rsum = 0.f;
  if (g == 0) {              // self-loop term, scaled by dinv[w]
    float4 v0 = f4[(size_t)w * 32 + cl * 2];
    float4 v1 = f4[(size_t)w * 32 + cl * 2 + 1];
    a0 = make_float4(di * v0.x, di * v0.y, di * v0.z, di * v0.w);
    a1 = make_float4(di * v1.x, di * v1.y, di * v1.z, di * v1.w);
  }
  int s = rowptr[w], e = rowptr[w + 1];
  int j = s;
  for (; j + 8 <= e; j += 8) {
    int c0 = col[j + g];
    int c1 = col[j + 4 + g];
    float s0 = dinv[c0];
    float s1 = dinv[c1];
    rsum += s0 + s1;
    float4 v00 = f4[(size_t)c0 * 32 + cl * 2];
    float4 v01 = f4[(size_t)c0 * 32 + cl * 2 + 1];
    float4 v10 = f4[(size_t)c1 * 32 + cl * 2];
    float4 v11 = f4[(size_t)c1 * 32 + cl * 2 + 1];
    a0.x = fmaf(s0, v00.x, fmaf(s1, v10.x, a0.x));
    a0.y = fmaf(s0, v00.y, fmaf(s1, v10.y, a0.y));
    a0.z = fmaf(s0, v00.z, fmaf(s1, v10.z, a0.z));
    a0.w = fmaf(s0, v00.w, fmaf(s1, v10.w, a0.w));
    a1.x = fmaf(s0, v01.x, fmaf(s1, v11.x, a1.x));
    a1.y = fmaf(s0, v01.y, fmaf(s1, v11.y, a1.y));
    a1.z = fmaf(s0, v01.z, fmaf(s1, v11.z, a1.z));
    a1.w = fmaf(s0, v01.w, fmaf(s1, v11.w, a1.w));
  }
  for (; j < e; j += 4) {
    int jj = j + g;
    if (jj < e) {
      int c = col[jj];
      float s0 = dinv[c];
      rsum += s0;
      float4 v0 = f4[(size_t)c * 32 + cl * 2];
      float4 v1 = f4[(size_t)c * 32 + cl * 2 + 1];
      a0.x = fmaf(s0, v0.x, a0.x); a0.y = fmaf(s0, v0.y, a0.y);
      a0.z = fmaf(s0, v0.z, a0.z); a0.w = fmaf(s0, v0.w, a0.w);
      a1.x = fmaf(s0, v1.x, a1.x); a1.y = fmaf(s0, v1.y, a1.y);
      a1.z = fmaf(s0, v1.z, a1.z); a1.w = fmaf(s0, v1.w, a1.w);
    }
  }
  // reduce across the 4 groups (xor 16, then 32)
  #pragma unroll
  for (int m = 16; m <= 32; m <<= 1) {
    a0.x += __shfl_xor(a0.x, m); a0.y += __shfl_xor(a0.y, m);
    a0.z += __shfl_xor(a0.z, m); a0.w += __shfl_xor(a0.w, m);
    a1.x += __shfl_xor(a1.x, m); a1.y += __shfl_xor(a1.y, m);
    a1.z += __shfl_xor(a1.z, m); a1.w += __shfl_xor(a1.w, m);
    rsum += __shfl_xor(rsum, m);
  }
  if (g == 0) {
    float r[8] = {a0.x * di, a0.y * di, a0.z * di, a0.w * di,
                  a1.x * di, a1.y * di, a1.z * di, a1.w * di};
    if (out_f32) {
      ((float4*)out_f32)[(size_t)w * 32 + cl * 2] =
          make_float4(r[0], r[1], r[2], r[3]);
      ((float4*)out_f32)[(size_t)w * 32 + cl * 2 + 1] =
          make_float4(r[4], r[5], r[6], r[7]);
    } else {
      ushort h[8], l[8];
      #pragma unroll
      for (int i = 0; i < 8; ++i) {
        h[i] = f2bf(r[i]);
        l[i] = f2bf(r[i] - bf2f(h[i]));
      }
      size_t o = (size_t)w * 32 + cl * 2;
      ((ushort4*)out_hi)[o]     = make_ushort4(h[0], h[1], h[2], h[3]);
      ((ushort4*)out_hi)[o + 1] = make_ushort4(h[4], h[5], h[6], h[7]);
      ((ushort4*)out_lo)[o]     = make_ushort4(l[0], l[1], l[2], l[3]);
      ((ushort4*)out_lo)[o + 1] = make_ushort4(l[4], l[5], l[6], l[7]);
    }
    if (r_out && cl == 0) r_out[w] = di * (di + rsum);
  }
}

// MFMA GEMM, col-split: out = relu(A@W + r*p + b). A = bf16 hi/lo [M][128]
// (regs), W = bf16 hi/lo transposed [c][k], 64-col slice in 32KB swizzled LDS.
// Block = 4 waves x 32 rows = 128 rows x 64 cols. blockIdx.y = mat*2+colhalf.
__global__ __launch_bounds__(256) void gemm_mfma_kernel(
    const ushort* __restrict__ Ahi, const ushort* __restrict__ Alo,
    const ushort* __restrict__ W0h, const ushort* __restrict__ W0l,
    const float* __restrict__ p0, const float* __restrict__ b0,
    const ushort* __restrict__ W1h, const ushort* __restrict__ W1l,
    const float* __restrict__ p1, const float* __restrict__ b1,
    const float* __restrict__ rbuf,
    float* __restrict__ out0, float* __restrict__ out1,
    int M) {
  __shared__ ushort Wh[64 * 128];    // 16KB, swizzled 16B slots
  __shared__ ushort Wl[64 * 128];    // 16KB

  const int mat = blockIdx.y >> 1;
  const int c0  = (blockIdx.y & 1) * 64;
  const uint4* GH = (const uint4*)(mat ? W1h : W0h);
  const uint4* GL = (const uint4*)(mat ? W1l : W0l);
  const float* pp = mat ? p1 : p0;
  const float* bb = mat ? b1 : b0;
  float*     outp = mat ? out1 : out0;

  const int tid  = threadIdx.x;
  const int lane = tid & 63;
  const int wv   = tid >> 6;         // wave id 0..3
  const int rA   = lane & 31;        // A row-in-tile / W col-in-tile
  const int kh   = lane >> 5;        // k half
  const int row  = blockIdx.x * 128 + wv * 32 + rA;
  const bool rowok = row < M;

  // stage W cols [c0, c0+64), hi/lo: 1024 16B slots each
  {
    uint4* LH = (uint4*)Wh;
    uint4* LL = (uint4*)Wl;
    #pragma unroll
    for (int t = 0; t < 4; ++t) {
      int q = tid + t * 256;         // 0..1023
      int wr = q >> 4, ls = q & 15;
      int phys = ls ^ (wr & 15);
      LH[wr * 16 + phys] = GH[(c0 + wr) * 16 + ls];
      LL[wr * 16 + phys] = GL[(c0 + wr) * 16 + ls];
    }
  }

  const short8v* AH = (const short8v*)Ahi;
  const short8v* AL = (const short8v*)Alo;
  const short8v zero8 = {0, 0, 0, 0, 0, 0, 0, 0};

  // A fragments for all 8 k-chunks (16B each).
  short8v ah[8], al[8];
  #pragma unroll
  for (int kc = 0; kc < 8; ++kc) {
    int fi = row * 16 + kc * 2 + kh;
    ah[kc] = rowok ? AH[fi] : zero8;
    al[kc] = rowok ? AL[fi] : zero8;
  }

  __syncthreads();

  floatx16 acc[2];
  #pragma unroll
  for (int t = 0; t < 2; ++t)
    #pragma unroll
    for (int j = 0; j < 16; ++j) acc[t][j] = 0.f;

  const short8v* WHv = (const short8v*)Wh;
  const short8v* WLv = (const short8v*)Wl;

  #pragma unroll
  for (int kc = 0; kc < 8; ++kc) {
    int fk = kc * 2 + kh;
    int ph = fk ^ (rA & 15);         // swizzled slot (wrow&15 == rA&15)
    short8v wh[2], wl[2];
    #pragma unroll
    for (int t = 0; t < 2; ++t) {
      wh[t] = WHv[(t * 32 + rA) * 16 + ph];
      wl[t] = WLv[(t * 32 + rA) * 16 + ph];
    }
    #pragma unroll
    for (int t = 0; t < 2; ++t)
      acc[t] = __builtin_amdgcn_mfma_f32_32x32x16_bf16(ah[kc], wh[t], acc[t], 0, 0, 0);
    #pragma unroll
    for (int t = 0; t < 2; ++t)
      acc[t] = __builtin_amdgcn_mfma_f32_32x32x16_bf16(ah[kc], wl[t], acc[t], 0, 0, 0);
    #pragma unroll
    for (int t = 0; t < 2; ++t)
      acc[t] = __builtin_amdgcn_mfma_f32_32x32x16_bf16(al[kc], wh[t], acc[t], 0, 0, 0);
  }

  float bcol[2], pcol[2];
  #pragma unroll
  for (int t = 0; t < 2; ++t) {
    bcol[t] = bb[c0 + t * 32 + rA];
    pcol[t] = pp[c0 + t * 32 + rA];
  }
  #pragma unroll
  for (int r = 0; r < 16; ++r) {
    int r32 = (r & 3) + 8 * (r >> 2) + 4 * kh;
    int orow = blockIdx.x * 128 + wv * 32 + r32;
    if (orow < M) {
      float rb = rbuf[orow];
      #pragma unroll
      for (int t = 0; t < 2; ++t) {
        float v = acc[t][r] + fmaf(rb, pcol[t], bcol[t]);
        v = fmaxf(v, 0.f);
        outp[(size_t)orow * CH + c0 + t * 32 + rA] = v;
      }
    }
  }
}

extern "C" void kernel_launch(void* const* d_in, const int* in_sizes, int n_in,
                              void* d_out, int out_size, void* d_ws, size_t ws_size,
                              hipStream_t stream) {
  const float* x      = (const float*)d_in[0];
  const int*   ei     = (const int*)d_in[1];
  const float* W_base = (const float*)d_in[2];
  const float* b_base = (const float*)d_in[3];
  const float* W_mu   = (const float*)d_in[4];
  const float* b_mu   = (const float*)d_in[5];
  const float* W_ls   = (const float*)d_in[6];
  const float* b_ls   = (const float*)d_in[7];
  float* out = (float*)d_out;

  const int N = in_sizes[0] / CH;
  const int E = in_sizes[1] / 2;

  char* ws = (char*)d_ws;
  size_t off = 0;
  auto carve = [&](size_t bytes) -> void* {
    void* p = ws + off;
    off += (bytes + 511) & ~(size_t)511;
    return p;
  };
  int*    cnt    = (int*)carve((size_t)N * 4);
  int*    rowptr = (int*)carve((size_t)(N + 1) * 4);
  int*    cursor = (int*)carve((size_t)N * 4);
  int*    col    = (int*)carve((size_t)E * 4);
  float*  dinv   = (float*)carve((size_t)N * 4);
  float*  rbuf   = (float*)carve((size_t)N * 4);
  int*    bsum   = (int*)carve((size_t)2048 * 4);
  int*    total  = (int*)carve((size_t)4);
  float*  Wcm  = (float*)carve((size_t)CH * CH * 4);
  float*  Wcs  = (float*)carve((size_t)CH * CH * 4);
  float*  pm   = (float*)carve((size_t)CH * 4);
  float*  ps   = (float*)carve((size_t)CH * 4);
  ushort* Wcmh = (ushort*)carve((size_t)CH * CH * 2);
  ushort* Wcml = (ushort*)carve((size_t)CH * CH * 2);
  ushort* Wcsh = (ushort*)carve((size_t)CH * CH * 2);
  ushort* Wcsl = (ushort*)carve((size_t)CH * CH * 2);
  float*  t1   = (float*)carve((size_t)N * CH * 4);   // A@x (f32)
  ushort* zhi  = (ushort*)carve((size_t)N * CH * 2);  // z = A^2@x hi
  ushort* zlo  = (ushort*)carve((size_t)N * CH * 2);  // z lo

  hipMemsetAsync(cnt, 0, (size_t)N * 4, stream);

  int eb = (E + 255) / 256;
  int nb = (N + SCAN_CHUNK - 1) / SCAN_CHUNK;
  count_kernel<<<eb, 256, 0, stream>>>(ei, E, cnt);
  scan_sum_kernel<<<nb, 256, 0, stream>>>(cnt, N, bsum);
  scan_bsum_kernel<<<1, 256, 0, stream>>>(bsum, nb, total);
  scan_fin_kernel<<<nb, 256, 0, stream>>>(cnt, N, bsum, total, rowptr, cursor, dinv);
  fill_kernel<<<eb, 256, 0, stream>>>(ei, E, cursor, col);

  wcomb_kernel<<<33, 256, 0, stream>>>(W_base, b_base, W_mu, W_ls,
                                       Wcm, Wcs, pm, ps);
  wsplit_kernel<<<32, 256, 0, stream>>>(Wcm, Wcmh, Wcml, Wcs, Wcsh, Wcsl);

  int ab = (N * 64 + 255) / 256;
  int gb = (N + 127) / 128;

  // t1 = A@x (f32)
  agg_kernel<<<ab, 256, 0, stream>>>(x, rowptr, col, dinv,
                                     t1, nullptr, nullptr, nullptr, N);
  // z = A@t1 (split bf16), r = A@1
  agg_kernel<<<ab, 256, 0, stream>>>(t1, rowptr, col, dinv,
                                     nullptr, zhi, zlo, rbuf, N);
  // m = relu(z@Wcm + r*pm + bmu), s = relu(z@Wcs + r*ps + bls)
  gemm_mfma_kernel<<<dim3(gb, 4), 256, 0, stream>>>(zhi, zlo,
                                           Wcmh, Wcml, pm, b_mu,
                                           Wcsh, Wcsl, ps, b_ls,
                                           rbuf, out, out + (size_t)N * CH, N);
}

// Round 10
// 210.886 us; speedup vs baseline: 1.5175x; 1.0071x over previous
//
#include <hip/hip_runtime.h>

// GCN edge-predictor encoder, R10: transaction-efficient gather.
//   m = relu(A^2 x (Wb@Wmu) + (A1)(bb@Wmu) + bmu), s likewise with W_ls.
//   deg/dinv -> CSR -> t1 = A@x (f32) -> z = A@t1 (split bf16) + r = A@1
//   -> wcombsplit: Wcm=Wb@Wmu, Wcs=Wb@Wls (split-bf16 transposed), pm, ps
//   -> dual MFMA gemm: m,s = relu(z@Wc + r*p + b)
// agg: one wave/node, 4 edge-groups x 16 lanes; CONTIGUOUS group loads
// (lane reads f4[row*32+cl] and f4[row*32+16+cl]: 256B/instr/group = 2 full
// cache lines; R9's cl*2 interleave touched 4 lines at half coverage).
// Edge ladder 16/8/4 with masked tail.
// GEMM: split-bf16 (Ah@Wh+Ah@Wl+Al@Wh) 32x32x16 MFMA, W-slice in 32KB
// swizzled LDS, grid.y = mat*2+colhalf.

#define CH 128
#define SCAN_CHUNK 1024

typedef __attribute__((ext_vector_type(8))) short short8v;
typedef __attribute__((ext_vector_type(16))) float floatx16;

__device__ inline ushort f2bf(float f) {
  uint u = __builtin_bit_cast(uint, f);
  uint r = (u + 0x7FFFu + ((u >> 16) & 1u)) >> 16;
  return (ushort)r;
}
__device__ inline float bf2f(ushort h) {
  uint u = ((uint)h) << 16;
  return __builtin_bit_cast(float, u);
}

__global__ void count_kernel(const int* __restrict__ ei, int E, int* __restrict__ cnt) {
  int e = blockIdx.x * blockDim.x + threadIdx.x;
  if (e < E) atomicAdd(&cnt[ei[E + e]], 1);
}

__global__ __launch_bounds__(256) void scan_sum_kernel(const int* __restrict__ cnt,
    int n, int* __restrict__ bsum) {
  __shared__ int sdata[256];
  int base = blockIdx.x * SCAN_CHUNK;
  int tid = threadIdx.x;
  int s = 0;
  #pragma unroll
  for (int j = 0; j < 4; ++j) {
    int i = base + tid * 4 + j;
    if (i < n) s += cnt[i];
  }
  sdata[tid] = s;
  __syncthreads();
  for (int off = 128; off > 0; off >>= 1) {
    if (tid < off) sdata[tid] += sdata[tid + off];
    __syncthreads();
  }
  if (tid == 0) bsum[blockIdx.x] = sdata[0];
}

__global__ __launch_bounds__(256) void scan_bsum_kernel(int* __restrict__ bsum,
    int nb, int* __restrict__ total_out) {
  __shared__ int sdata[1024];
  int tid = threadIdx.x;
  #pragma unroll
  for (int j = 0; j < 4; ++j) {
    int i = tid * 4 + j;
    sdata[i] = (i < nb) ? bsum[i] : 0;
  }
  __syncthreads();
  if (tid == 0) {
    int run = 0;
    for (int i = 0; i < nb; ++i) { int v = sdata[i]; sdata[i] = run; run += v; }
    *total_out = run;
  }
  __syncthreads();
  #pragma unroll
  for (int j = 0; j < 4; ++j) {
    int i = tid * 4 + j;
    if (i < nb) bsum[i] = sdata[i];
  }
}

__global__ __launch_bounds__(256) void scan_fin_kernel(const int* __restrict__ cnt,
    int n, const int* __restrict__ bsum, const int* __restrict__ total,
    int* __restrict__ rowptr, int* __restrict__ cursor, float* __restrict__ dinv) {
  __shared__ int sthr[256];
  int base = blockIdx.x * SCAN_CHUNK;
  int tid = threadIdx.x;
  int v[4];
  int ts = 0;
  #pragma unroll
  for (int j = 0; j < 4; ++j) {
    int i = base + tid * 4 + j;
    v[j] = (i < n) ? cnt[i] : 0;
    ts += v[j];
  }
  sthr[tid] = ts;
  __syncthreads();
  for (int off = 1; off < 256; off <<= 1) {
    int t = (tid >= off) ? sthr[tid - off] : 0;
    __syncthreads();
    sthr[tid] += t;
    __syncthreads();
  }
  int excl = sthr[tid] - ts + bsum[blockIdx.x];
  #pragma unroll
  for (int j = 0; j < 4; ++j) {
    int i = base + tid * 4 + j;
    if (i < n) {
      rowptr[i] = excl;
      cursor[i] = excl;
      dinv[i]   = rsqrtf((float)(v[j] + 1));
      excl += v[j];
    }
  }
  if (blockIdx.x == 0 && tid == 0) rowptr[n] = *total;
}

__global__ void fill_kernel(const int* __restrict__ ei, int E,
                            int* __restrict__ cursor, int* __restrict__ col) {
  int e = blockIdx.x * blockDim.x + threadIdx.x;
  if (e < E) {
    int d = ei[E + e];
    int pos = atomicAdd(&cursor[d], 1);
    col[pos] = ei[e];
  }
}

// Fused: Wc = Wb@W2 computed and written DIRECTLY as transposed split-bf16
// [c][k] hi/lo (no f32 intermediate). Blocks 0-31: 16 per matrix; block 32:
// pm = bb@Wmu, ps = bb@Wls.
__global__ __launch_bounds__(256) void wcombsplit_kernel(
    const float* __restrict__ Wb, const float* __restrict__ bb,
    const float* __restrict__ Wmu, const float* __restrict__ Wls,
    ushort* __restrict__ Wcmh, ushort* __restrict__ Wcml,
    ushort* __restrict__ Wcsh, ushort* __restrict__ Wcsl,
    float* __restrict__ pm, float* __restrict__ ps) {
  int gid = blockIdx.x;
  if (gid < 32) {
    int sel = gid >> 4;
    const float* W2 = sel ? Wls : Wmu;
    ushort* Wh = sel ? Wcsh : Wcmh;
    ushort* Wl = sel ? Wcsl : Wcml;
    int o = (gid & 15) * 1024 + threadIdx.x * 4;  // [k][c] linear, 4 consecutive c
    int k = o >> 7, c = o & 127;
    float acc[4] = {0.f, 0.f, 0.f, 0.f};
    for (int j = 0; j < 128; ++j) {
      float a = Wb[k * 128 + j];
      const float* wr = &W2[j * 128 + c];
      acc[0] = fmaf(a, wr[0], acc[0]);
      acc[1] = fmaf(a, wr[1], acc[1]);
      acc[2] = fmaf(a, wr[2], acc[2]);
      acc[3] = fmaf(a, wr[3], acc[3]);
    }
    #pragma unroll
    for (int j = 0; j < 4; ++j) {     // write transposed [c][k] split
      ushort h = f2bf(acc[j]);
      Wh[(c + j) * 128 + k] = h;
      Wl[(c + j) * 128 + k] = f2bf(acc[j] - bf2f(h));
    }
  } else {
    int t = threadIdx.x;
    int sel = t >> 7, c = t & 127;
    const float* W2 = sel ? Wls : Wmu;
    float acc = 0.f;
    for (int j = 0; j < 128; ++j) acc = fmaf(bb[j], W2[j * 128 + c], acc);
    (sel ? ps : pm)[c] = acc;
  }
}

// One wave per node; 4 edge-groups of 16 lanes. Lane handles f4 slots cl and
// 16+cl of each row (contiguous 256B per group instruction).
// out[w] = dinv[w] * ( dinv[w]*feat[w] + sum_src dinv[src]*feat[src] ).
// Output: f32 (out_f32) or split bf16 (out_hi/lo).
// r_out (optional): r[w] = dinv[w]*(dinv[w] + sum_src dinv[src]) = (A@1)[w].
__global__ __launch_bounds__(256) void agg_kernel(const float* __restrict__ feat,
    const int* __restrict__ rowptr, const int* __restrict__ col,
    const float* __restrict__ dinv,
    float* __restrict__ out_f32, ushort* __restrict__ out_hi,
    ushort* __restrict__ out_lo, float* __restrict__ r_out, int n) {
  int w = (blockIdx.x * 256 + threadIdx.x) >> 6;
  if (w >= n) return;
  int lane = threadIdx.x & 63;
  int g  = lane >> 4;        // edge group 0..3
  int cl = lane & 15;        // f4 slot cl and 16+cl
  const float4* f4 = (const float4*)feat;
  float di = dinv[w];
  float4 a0 = make_float4(0.f, 0.f, 0.f, 0.f);
  float4 a1 = make_float4(0.f, 0.f, 0.f, 0.f);
  float rsum = 0.f;
  if (g == 0) {              // self-loop term, scaled by dinv[w]
    float4 v0 = f4[(size_t)w * 32 + cl];
    float4 v1 = f4[(size_t)w * 32 + 16 + cl];
    a0 = make_float4(di * v0.x, di * v0.y, di * v0.z, di * v0.w);
    a1 = make_float4(di * v1.x, di * v1.y, di * v1.z, di * v1.w);
  }
  int s = rowptr[w], e = rowptr[w + 1];
  int j = s;
  for (; j + 16 <= e; j += 16) {   // 4 edges per group
    int c0 = col[j + g];
    int c1 = col[j + 4 + g];
    int c2 = col[j + 8 + g];
    int c3 = col[j + 12 + g];
    float s0 = dinv[c0], s1 = dinv[c1], s2 = dinv[c2], s3 = dinv[c3];
    rsum += (s0 + s1) + (s2 + s3);
    float4 v00 = f4[(size_t)c0 * 32 + cl];
    float4 v01 = f4[(size_t)c0 * 32 + 16 + cl];
    float4 v10 = f4[(size_t)c1 * 32 + cl];
    float4 v11 = f4[(size_t)c1 * 32 + 16 + cl];
    float4 v20 = f4[(size_t)c2 * 32 + cl];
    float4 v21 = f4[(size_t)c2 * 32 + 16 + cl];
    float4 v30 = f4[(size_t)c3 * 32 + cl];
    float4 v31 = f4[(size_t)c3 * 32 + 16 + cl];
    a0.x = fmaf(s0, v00.x, fmaf(s1, v10.x, fmaf(s2, v20.x, fmaf(s3, v30.x, a0.x))));
    a0.y = fmaf(s0, v00.y, fmaf(s1, v10.y, fmaf(s2, v20.y, fmaf(s3, v30.y, a0.y))));
    a0.z = fmaf(s0, v00.z, fmaf(s1, v10.z, fmaf(s2, v20.z, fmaf(s3, v30.z, a0.z))));
    a0.w = fmaf(s0, v00.w, fmaf(s1, v10.w, fmaf(s2, v20.w, fmaf(s3, v30.w, a0.w))));
    a1.x = fmaf(s0, v01.x, fmaf(s1, v11.x, fmaf(s2, v21.x, fmaf(s3, v31.x, a1.x))));
    a1.y = fmaf(s0, v01.y, fmaf(s1, v11.y, fmaf(s2, v21.y, fmaf(s3, v31.y, a1.y))));
    a1.z = fmaf(s0, v01.z, fmaf(s1, v11.z, fmaf(s2, v21.z, fmaf(s3, v31.z, a1.z))));
    a1.w = fmaf(s0, v01.w, fmaf(s1, v11.w, fmaf(s2, v21.w, fmaf(s3, v31.w, a1.w))));
  }
  for (; j + 8 <= e; j += 8) {     // 2 edges per group
    int c0 = col[j + g];
    int c1 = col[j + 4 + g];
    float s0 = dinv[c0], s1 = dinv[c1];
    rsum += s0 + s1;
    float4 v00 = f4[(size_t)c0 * 32 + cl];
    float4 v01 = f4[(size_t)c0 * 32 + 16 + cl];
    float4 v10 = f4[(size_t)c1 * 32 + cl];
    float4 v11 = f4[(size_t)c1 * 32 + 16 + cl];
    a0.x = fmaf(s0, v00.x, fmaf(s1, v10.x, a0.x));
    a0.y = fmaf(s0, v00.y, fmaf(s1, v10.y, a0.y));
    a0.z = fmaf(s0, v00.z, fmaf(s1, v10.z, a0.z));
    a0.w = fmaf(s0, v00.w, fmaf(s1, v10.w, a0.w));
    a1.x = fmaf(s0, v01.x, fmaf(s1, v11.x, a1.x));
    a1.y = fmaf(s0, v01.y, fmaf(s1, v11.y, a1.y));
    a1.z = fmaf(s0, v01.z, fmaf(s1, v11.z, a1.z));
    a1.w = fmaf(s0, v01.w, fmaf(s1, v11.w, a1.w));
  }
  for (; j < e; j += 4) {          // <=1 edge per group, masked
    int jj = j + g;
    if (jj < e) {
      int c = col[jj];
      float s0 = dinv[c];
      rsum += s0;
      float4 v0 = f4[(size_t)c * 32 + cl];
      float4 v1 = f4[(size_t)c * 32 + 16 + cl];
      a0.x = fmaf(s0, v0.x, a0.x); a0.y = fmaf(s0, v0.y, a0.y);
      a0.z = fmaf(s0, v0.z, a0.z); a0.w = fmaf(s0, v0.w, a0.w);
      a1.x = fmaf(s0, v1.x, a1.x); a1.y = fmaf(s0, v1.y, a1.y);
      a1.z = fmaf(s0, v1.z, a1.z); a1.w = fmaf(s0, v1.w, a1.w);
    }
  }
  // reduce across the 4 groups (xor 16, then 32)
  #pragma unroll
  for (int m = 16; m <= 32; m <<= 1) {
    a0.x += __shfl_xor(a0.x, m); a0.y += __shfl_xor(a0.y, m);
    a0.z += __shfl_xor(a0.z, m); a0.w += __shfl_xor(a0.w, m);
    a1.x += __shfl_xor(a1.x, m); a1.y += __shfl_xor(a1.y, m);
    a1.z += __shfl_xor(a1.z, m); a1.w += __shfl_xor(a1.w, m);
    rsum += __shfl_xor(rsum, m);
  }
  if (g == 0) {
    float r0[4] = {a0.x * di, a0.y * di, a0.z * di, a0.w * di};
    float r1[4] = {a1.x * di, a1.y * di, a1.z * di, a1.w * di};
    if (out_f32) {
      ((float4*)out_f32)[(size_t)w * 32 + cl] =
          make_float4(r0[0], r0[1], r0[2], r0[3]);
      ((float4*)out_f32)[(size_t)w * 32 + 16 + cl] =
          make_float4(r1[0], r1[1], r1[2], r1[3]);
    } else {
      ushort h0[4], l0[4], h1[4], l1[4];
      #pragma unroll
      for (int i = 0; i < 4; ++i) {
        h0[i] = f2bf(r0[i]); l0[i] = f2bf(r0[i] - bf2f(h0[i]));
        h1[i] = f2bf(r1[i]); l1[i] = f2bf(r1[i] - bf2f(h1[i]));
      }
      ((ushort4*)out_hi)[(size_t)w * 32 + cl] =
          make_ushort4(h0[0], h0[1], h0[2], h0[3]);
      ((ushort4*)out_hi)[(size_t)w * 32 + 16 + cl] =
          make_ushort4(h1[0], h1[1], h1[2], h1[3]);
      ((ushort4*)out_lo)[(size_t)w * 32 + cl] =
          make_ushort4(l0[0], l0[1], l0[2], l0[3]);
      ((ushort4*)out_lo)[(size_t)w * 32 + 16 + cl] =
          make_ushort4(l1[0], l1[1], l1[2], l1[3]);
    }
    if (r_out && cl == 0) r_out[w] = di * (di + rsum);
  }
}

// MFMA GEMM, col-split: out = relu(A@W + r*p + b). A = bf16 hi/lo [M][128]
// (regs), W = bf16 hi/lo transposed [c][k], 64-col slice in 32KB swizzled LDS.
// Block = 4 waves x 32 rows = 128 rows x 64 cols. blockIdx.y = mat*2+colhalf.
__global__ __launch_bounds__(256) void gemm_mfma_kernel(
    const ushort* __restrict__ Ahi, const ushort* __restrict__ Alo,
    const ushort* __restrict__ W0h, const ushort* __restrict__ W0l,
    const float* __restrict__ p0, const float* __restrict__ b0,
    const ushort* __restrict__ W1h, const ushort* __restrict__ W1l,
    const float* __restrict__ p1, const float* __restrict__ b1,
    const float* __restrict__ rbuf,
    float* __restrict__ out0, float* __restrict__ out1,
    int M) {
  __shared__ ushort Wh[64 * 128];    // 16KB, swizzled 16B slots
  __shared__ ushort Wl[64 * 128];    // 16KB

  const int mat = blockIdx.y >> 1;
  const int c0  = (blockIdx.y & 1) * 64;
  const uint4* GH = (const uint4*)(mat ? W1h : W0h);
  const uint4* GL = (const uint4*)(mat ? W1l : W0l);
  const float* pp = mat ? p1 : p0;
  const float* bb = mat ? b1 : b0;
  float*     outp = mat ? out1 : out0;

  const int tid  = threadIdx.x;
  const int lane = tid & 63;
  const int wv   = tid >> 6;         // wave id 0..3
  const int rA   = lane & 31;        // A row-in-tile / W col-in-tile
  const int kh   = lane >> 5;        // k half
  const int row  = blockIdx.x * 128 + wv * 32 + rA;
  const bool rowok = row < M;

  // stage W cols [c0, c0+64), hi/lo: 1024 16B slots each
  {
    uint4* LH = (uint4*)Wh;
    uint4* LL = (uint4*)Wl;
    #pragma unroll
    for (int t = 0; t < 4; ++t) {
      int q = tid + t * 256;         // 0..1023
      int wr = q >> 4, ls = q & 15;
      int phys = ls ^ (wr & 15);
      LH[wr * 16 + phys] = GH[(c0 + wr) * 16 + ls];
      LL[wr * 16 + phys] = GL[(c0 + wr) * 16 + ls];
    }
  }

  const short8v* AH = (const short8v*)Ahi;
  const short8v* AL = (const short8v*)Alo;
  const short8v zero8 = {0, 0, 0, 0, 0, 0, 0, 0};

  // A fragments for all 8 k-chunks (16B each).
  short8v ah[8], al[8];
  #pragma unroll
  for (int kc = 0; kc < 8; ++kc) {
    int fi = row * 16 + kc * 2 + kh;
    ah[kc] = rowok ? AH[fi] : zero8;
    al[kc] = rowok ? AL[fi] : zero8;
  }

  __syncthreads();

  floatx16 acc[2];
  #pragma unroll
  for (int t = 0; t < 2; ++t)
    #pragma unroll
    for (int j = 0; j < 16; ++j) acc[t][j] = 0.f;

  const short8v* WHv = (const short8v*)Wh;
  const short8v* WLv = (const short8v*)Wl;

  #pragma unroll
  for (int kc = 0; kc < 8; ++kc) {
    int fk = kc * 2 + kh;
    int ph = fk ^ (rA & 15);         // swizzled slot (wrow&15 == rA&15)
    short8v wh[2], wl[2];
    #pragma unroll
    for (int t = 0; t < 2; ++t) {
      wh[t] = WHv[(t * 32 + rA) * 16 + ph];
      wl[t] = WLv[(t * 32 + rA) * 16 + ph];
    }
    #pragma unroll
    for (int t = 0; t < 2; ++t)
      acc[t] = __builtin_amdgcn_mfma_f32_32x32x16_bf16(ah[kc], wh[t], acc[t], 0, 0, 0);
    #pragma unroll
    for (int t = 0; t < 2; ++t)
      acc[t] = __builtin_amdgcn_mfma_f32_32x32x16_bf16(ah[kc], wl[t], acc[t], 0, 0, 0);
    #pragma unroll
    for (int t = 0; t < 2; ++t)
      acc[t] = __builtin_amdgcn_mfma_f32_32x32x16_bf16(al[kc], wh[t], acc[t], 0, 0, 0);
  }

  float bcol[2], pcol[2];
  #pragma unroll
  for (int t = 0; t < 2; ++t) {
    bcol[t] = bb[c0 + t * 32 + rA];
    pcol[t] = pp[c0 + t * 32 + rA];
  }
  #pragma unroll
  for (int r = 0; r < 16; ++r) {
    int r32 = (r & 3) + 8 * (r >> 2) + 4 * kh;
    int orow = blockIdx.x * 128 + wv * 32 + r32;
    if (orow < M) {
      float rb = rbuf[orow];
      #pragma unroll
      for (int t = 0; t < 2; ++t) {
        float v = acc[t][r] + fmaf(rb, pcol[t], bcol[t]);
        v = fmaxf(v, 0.f);
        outp[(size_t)orow * CH + c0 + t * 32 + rA] = v;
      }
    }
  }
}

extern "C" void kernel_launch(void* const* d_in, const int* in_sizes, int n_in,
                              void* d_out, int out_size, void* d_ws, size_t ws_size,
                              hipStream_t stream) {
  const float* x      = (const float*)d_in[0];
  const int*   ei     = (const int*)d_in[1];
  const float* W_base = (const float*)d_in[2];
  const float* b_base = (const float*)d_in[3];
  const float* W_mu   = (const float*)d_in[4];
  const float* b_mu   = (const float*)d_in[5];
  const float* W_ls   = (const float*)d_in[6];
  const float* b_ls   = (const float*)d_in[7];
  float* out = (float*)d_out;

  const int N = in_sizes[0] / CH;
  const int E = in_sizes[1] / 2;

  char* ws = (char*)d_ws;
  size_t off = 0;
  auto carve = [&](size_t bytes) -> void* {
    void* p = ws + off;
    off += (bytes + 511) & ~(size_t)511;
    return p;
  };
  int*    cnt    = (int*)carve((size_t)N * 4);
  int*    rowptr = (int*)carve((size_t)(N + 1) * 4);
  int*    cursor = (int*)carve((size_t)N * 4);
  int*    col    = (int*)carve((size_t)E * 4);
  float*  dinv   = (float*)carve((size_t)N * 4);
  float*  rbuf   = (float*)carve((size_t)N * 4);
  int*    bsum   = (int*)carve((size_t)2048 * 4);
  int*    total  = (int*)carve((size_t)4);
  float*  pm   = (float*)carve((size_t)CH * 4);
  float*  ps   = (float*)carve((size_t)CH * 4);
  ushort* Wcmh = (ushort*)carve((size_t)CH * CH * 2);
  ushort* Wcml = (ushort*)carve((size_t)CH * CH * 2);
  ushort* Wcsh = (ushort*)carve((size_t)CH * CH * 2);
  ushort* Wcsl = (ushort*)carve((size_t)CH * CH * 2);
  float*  t1   = (float*)carve((size_t)N * CH * 4);   // A@x (f32)
  ushort* zhi  = (ushort*)carve((size_t)N * CH * 2);  // z = A^2@x hi
  ushort* zlo  = (ushort*)carve((size_t)N * CH * 2);  // z lo

  hipMemsetAsync(cnt, 0, (size_t)N * 4, stream);

  int eb = (E + 255) / 256;
  int nb = (N + SCAN_CHUNK - 1) / SCAN_CHUNK;
  count_kernel<<<eb, 256, 0, stream>>>(ei, E, cnt);
  scan_sum_kernel<<<nb, 256, 0, stream>>>(cnt, N, bsum);
  scan_bsum_kernel<<<1, 256, 0, stream>>>(bsum, nb, total);
  scan_fin_kernel<<<nb, 256, 0, stream>>>(cnt, N, bsum, total, rowptr, cursor, dinv);
  fill_kernel<<<eb, 256, 0, stream>>>(ei, E, cursor, col);

  wcombsplit_kernel<<<33, 256, 0, stream>>>(W_base, b_base, W_mu, W_ls,
                                            Wcmh, Wcml, Wcsh, Wcsl, pm, ps);

  int ab = (N * 64 + 255) / 256;
  int gb = (N + 127) / 128;

  // t1 = A@x (f32)
  agg_kernel<<<ab, 256, 0, stream>>>(x, rowptr, col, dinv,
                                     t1, nullptr, nullptr, nullptr, N);
  // z = A@t1 (split bf16), r = A@1
  agg_kernel<<<ab, 256, 0, stream>>>(t1, rowptr, col, dinv,
                                     nullptr, zhi, zlo, rbuf, N);
  // m = relu(z@Wcm + r*pm + bmu), s = relu(z@Wcs + r*ps + bls)
  gemm_mfma_kernel<<<dim3(gb, 4), 256, 0, stream>>>(zhi, zlo,
                                           Wcmh, Wcml, pm, b_mu,
                                           Wcsh, Wcsl, ps, b_ls,
                                           rbuf, out, out + (size_t)N * CH, N);
}

// Round 11
// 187.055 us; speedup vs baseline: 1.7108x; 1.1274x over previous
//
#include <hip/hip_runtime.h>
#include <hip/hip_fp16.h>

// GCN edge-predictor encoder, R11: fp16 gather features (half the bytes).
//   m = relu(A^2 x (Wb@Wmu) + (A1)(bb@Wmu) + bmu), s likewise with W_ls.
//   deg/dinv -> CSR -> xh=fp16(x) -> t1h = A@xh (fp16) -> z = A@t1h
//   (split bf16) + r = A@1 -> wcombsplit -> dual MFMA gemm.
// Gather accumulates f32 in registers; only stored features are fp16
// (11 mantissa bits, ~2.4e-4 rel err; adds ~1.5e-3 to output vs 1.18e-2
// threshold). Row = 256B -> one 16B load/lane (8 halfs), volume halved.
// agg: one wave/node, 4 edge-groups x 16 lanes, ladder 16/8/4/tail.
// GEMM: split-bf16 (Ah@Wh+Ah@Wl+Al@Wh) 32x32x16 MFMA, W-slice in 32KB
// swizzled LDS, grid.y = mat*2+colhalf.

#define CH 128
#define SCAN_CHUNK 1024

typedef __attribute__((ext_vector_type(8))) short short8v;
typedef __attribute__((ext_vector_type(16))) float floatx16;

__device__ inline ushort f2bf(float f) {
  uint u = __builtin_bit_cast(uint, f);
  uint r = (u + 0x7FFFu + ((u >> 16) & 1u)) >> 16;
  return (ushort)r;
}
__device__ inline float bf2f(ushort h) {
  uint u = ((uint)h) << 16;
  return __builtin_bit_cast(float, u);
}

__global__ void count_kernel(const int* __restrict__ ei, int E, int* __restrict__ cnt) {
  int e = blockIdx.x * blockDim.x + threadIdx.x;
  if (e < E) atomicAdd(&cnt[ei[E + e]], 1);
}

__global__ __launch_bounds__(256) void scan_sum_kernel(const int* __restrict__ cnt,
    int n, int* __restrict__ bsum) {
  __shared__ int sdata[256];
  int base = blockIdx.x * SCAN_CHUNK;
  int tid = threadIdx.x;
  int s = 0;
  #pragma unroll
  for (int j = 0; j < 4; ++j) {
    int i = base + tid * 4 + j;
    if (i < n) s += cnt[i];
  }
  sdata[tid] = s;
  __syncthreads();
  for (int off = 128; off > 0; off >>= 1) {
    if (tid < off) sdata[tid] += sdata[tid + off];
    __syncthreads();
  }
  if (tid == 0) bsum[blockIdx.x] = sdata[0];
}

__global__ __launch_bounds__(256) void scan_bsum_kernel(int* __restrict__ bsum,
    int nb, int* __restrict__ total_out) {
  __shared__ int sdata[1024];
  int tid = threadIdx.x;
  #pragma unroll
  for (int j = 0; j < 4; ++j) {
    int i = tid * 4 + j;
    sdata[i] = (i < nb) ? bsum[i] : 0;
  }
  __syncthreads();
  if (tid == 0) {
    int run = 0;
    for (int i = 0; i < nb; ++i) { int v = sdata[i]; sdata[i] = run; run += v; }
    *total_out = run;
  }
  __syncthreads();
  #pragma unroll
  for (int j = 0; j < 4; ++j) {
    int i = tid * 4 + j;
    if (i < nb) bsum[i] = sdata[i];
  }
}

__global__ __launch_bounds__(256) void scan_fin_kernel(const int* __restrict__ cnt,
    int n, const int* __restrict__ bsum, const int* __restrict__ total,
    int* __restrict__ rowptr, int* __restrict__ cursor, float* __restrict__ dinv) {
  __shared__ int sthr[256];
  int base = blockIdx.x * SCAN_CHUNK;
  int tid = threadIdx.x;
  int v[4];
  int ts = 0;
  #pragma unroll
  for (int j = 0; j < 4; ++j) {
    int i = base + tid * 4 + j;
    v[j] = (i < n) ? cnt[i] : 0;
    ts += v[j];
  }
  sthr[tid] = ts;
  __syncthreads();
  for (int off = 1; off < 256; off <<= 1) {
    int t = (tid >= off) ? sthr[tid - off] : 0;
    __syncthreads();
    sthr[tid] += t;
    __syncthreads();
  }
  int excl = sthr[tid] - ts + bsum[blockIdx.x];
  #pragma unroll
  for (int j = 0; j < 4; ++j) {
    int i = base + tid * 4 + j;
    if (i < n) {
      rowptr[i] = excl;
      cursor[i] = excl;
      dinv[i]   = rsqrtf((float)(v[j] + 1));
      excl += v[j];
    }
  }
  if (blockIdx.x == 0 && tid == 0) rowptr[n] = *total;
}

__global__ void fill_kernel(const int* __restrict__ ei, int E,
                            int* __restrict__ cursor, int* __restrict__ col) {
  int e = blockIdx.x * blockDim.x + threadIdx.x;
  if (e < E) {
    int d = ei[E + e];
    int pos = atomicAdd(&cursor[d], 1);
    col[pos] = ei[e];
  }
}

// x (f32) -> xh (fp16). Thread handles 8 elements.
__global__ __launch_bounds__(256) void f2h_kernel(const float* __restrict__ in,
    ushort* __restrict__ outh, int n8) {
  int t = blockIdx.x * 256 + threadIdx.x;
  if (t < n8) {
    const float4* f4 = (const float4*)in;
    float4 a = f4[2 * t], b = f4[2 * t + 1];
    __half h[8] = {__float2half_rn(a.x), __float2half_rn(a.y),
                   __float2half_rn(a.z), __float2half_rn(a.w),
                   __float2half_rn(b.x), __float2half_rn(b.y),
                   __float2half_rn(b.z), __float2half_rn(b.w)};
    ((uint4*)outh)[t] = *(const uint4*)h;
  }
}

// Fused: Wc = Wb@W2 computed and written DIRECTLY as transposed split-bf16
// [c][k] hi/lo. Blocks 0-31: 16 per matrix; block 32: pm = bb@Wmu, ps = bb@Wls.
__global__ __launch_bounds__(256) void wcombsplit_kernel(
    const float* __restrict__ Wb, const float* __restrict__ bb,
    const float* __restrict__ Wmu, const float* __restrict__ Wls,
    ushort* __restrict__ Wcmh, ushort* __restrict__ Wcml,
    ushort* __restrict__ Wcsh, ushort* __restrict__ Wcsl,
    float* __restrict__ pm, float* __restrict__ ps) {
  int gid = blockIdx.x;
  if (gid < 32) {
    int sel = gid >> 4;
    const float* W2 = sel ? Wls : Wmu;
    ushort* Wh = sel ? Wcsh : Wcmh;
    ushort* Wl = sel ? Wcsl : Wcml;
    int o = (gid & 15) * 1024 + threadIdx.x * 4;  // [k][c] linear, 4 consecutive c
    int k = o >> 7, c = o & 127;
    float acc[4] = {0.f, 0.f, 0.f, 0.f};
    for (int j = 0; j < 128; ++j) {
      float a = Wb[k * 128 + j];
      const float* wr = &W2[j * 128 + c];
      acc[0] = fmaf(a, wr[0], acc[0]);
      acc[1] = fmaf(a, wr[1], acc[1]);
      acc[2] = fmaf(a, wr[2], acc[2]);
      acc[3] = fmaf(a, wr[3], acc[3]);
    }
    #pragma unroll
    for (int j = 0; j < 4; ++j) {     // write transposed [c][k] split
      ushort h = f2bf(acc[j]);
      Wh[(c + j) * 128 + k] = h;
      Wl[(c + j) * 128 + k] = f2bf(acc[j] - bf2f(h));
    }
  } else {
    int t = threadIdx.x;
    int sel = t >> 7, c = t & 127;
    const float* W2 = sel ? Wls : Wmu;
    float acc = 0.f;
    for (int j = 0; j < 128; ++j) acc = fmaf(bb[j], W2[j * 128 + c], acc);
    (sel ? ps : pm)[c] = acc;
  }
}

__device__ inline void h8_fma(uint4 v, float s, float* a) {
  const __half2* h2 = (const __half2*)&v;
  #pragma unroll
  for (int i = 0; i < 4; ++i) {
    float2 f = __half22float2(h2[i]);
    a[2 * i]     = fmaf(s, f.x, a[2 * i]);
    a[2 * i + 1] = fmaf(s, f.y, a[2 * i + 1]);
  }
}

// One wave per node; 4 edge-groups of 16 lanes; lane cl owns channels
// cl*8..cl*8+7 (one 16B uint4 = 8 halfs per row). Accum f32.
// out[w] = dinv[w] * ( dinv[w]*feat[w] + sum_src dinv[src]*feat[src] ).
// Output: fp16 (out_h) or split bf16 (out_hi/lo).
// r_out (optional): r[w] = dinv[w]*(dinv[w] + sum_src dinv[src]) = (A@1)[w].
__global__ __launch_bounds__(256) void agg_kernel(const ushort* __restrict__ feat,
    const int* __restrict__ rowptr, const int* __restrict__ col,
    const float* __restrict__ dinv,
    ushort* __restrict__ out_h, ushort* __restrict__ out_hi,
    ushort* __restrict__ out_lo, float* __restrict__ r_out, int n) {
  int w = (blockIdx.x * 256 + threadIdx.x) >> 6;
  if (w >= n) return;
  int lane = threadIdx.x & 63;
  int g  = lane >> 4;        // edge group 0..3
  int cl = lane & 15;        // uint4 slot (8 channels)
  const uint4* u4 = (const uint4*)feat;
  float di = dinv[w];
  float a[8] = {0.f, 0.f, 0.f, 0.f, 0.f, 0.f, 0.f, 0.f};
  float rsum = 0.f;
  if (g == 0) {              // self-loop term, scaled by dinv[w]
    h8_fma(u4[(size_t)w * 16 + cl], di, a);
  }
  int s = rowptr[w], e = rowptr[w + 1];
  int j = s;
  for (; j + 16 <= e; j += 16) {   // 4 edges per group
    int c0 = col[j + g];
    int c1 = col[j + 4 + g];
    int c2 = col[j + 8 + g];
    int c3 = col[j + 12 + g];
    float s0 = dinv[c0], s1 = dinv[c1], s2 = dinv[c2], s3 = dinv[c3];
    rsum += (s0 + s1) + (s2 + s3);
    uint4 v0 = u4[(size_t)c0 * 16 + cl];
    uint4 v1 = u4[(size_t)c1 * 16 + cl];
    uint4 v2 = u4[(size_t)c2 * 16 + cl];
    uint4 v3 = u4[(size_t)c3 * 16 + cl];
    h8_fma(v0, s0, a);
    h8_fma(v1, s1, a);
    h8_fma(v2, s2, a);
    h8_fma(v3, s3, a);
  }
  for (; j + 8 <= e; j += 8) {     // 2 edges per group
    int c0 = col[j + g];
    int c1 = col[j + 4 + g];
    float s0 = dinv[c0], s1 = dinv[c1];
    rsum += s0 + s1;
    uint4 v0 = u4[(size_t)c0 * 16 + cl];
    uint4 v1 = u4[(size_t)c1 * 16 + cl];
    h8_fma(v0, s0, a);
    h8_fma(v1, s1, a);
  }
  for (; j < e; j += 4) {          // <=1 edge per group, masked
    int jj = j + g;
    if (jj < e) {
      int c = col[jj];
      float s0 = dinv[c];
      rsum += s0;
      h8_fma(u4[(size_t)c * 16 + cl], s0, a);
    }
  }
  // reduce across the 4 groups (xor 16, then 32)
  #pragma unroll
  for (int m = 16; m <= 32; m <<= 1) {
    #pragma unroll
    for (int i = 0; i < 8; ++i) a[i] += __shfl_xor(a[i], m);
    rsum += __shfl_xor(rsum, m);
  }
  if (g == 0) {
    float r[8];
    #pragma unroll
    for (int i = 0; i < 8; ++i) r[i] = a[i] * di;
    if (out_h) {
      __half h[8];
      #pragma unroll
      for (int i = 0; i < 8; ++i) h[i] = __float2half_rn(r[i]);
      ((uint4*)out_h)[(size_t)w * 16 + cl] = *(const uint4*)h;
    } else {
      ushort h[8], l[8];
      #pragma unroll
      for (int i = 0; i < 8; ++i) {
        h[i] = f2bf(r[i]);
        l[i] = f2bf(r[i] - bf2f(h[i]));
      }
      size_t o = (size_t)w * 32 + cl * 2;
      ((ushort4*)out_hi)[o]     = make_ushort4(h[0], h[1], h[2], h[3]);
      ((ushort4*)out_hi)[o + 1] = make_ushort4(h[4], h[5], h[6], h[7]);
      ((ushort4*)out_lo)[o]     = make_ushort4(l[0], l[1], l[2], l[3]);
      ((ushort4*)out_lo)[o + 1] = make_ushort4(l[4], l[5], l[6], l[7]);
    }
    if (r_out && cl == 0) r_out[w] = di * (di + rsum);
  }
}

// MFMA GEMM, col-split: out = relu(A@W + r*p + b). A = bf16 hi/lo [M][128]
// (regs), W = bf16 hi/lo transposed [c][k], 64-col slice in 32KB swizzled LDS.
// Block = 4 waves x 32 rows = 128 rows x 64 cols. blockIdx.y = mat*2+colhalf.
__global__ __launch_bounds__(256) void gemm_mfma_kernel(
    const ushort* __restrict__ Ahi, const ushort* __restrict__ Alo,
    const ushort* __restrict__ W0h, const ushort* __restrict__ W0l,
    const float* __restrict__ p0, const float* __restrict__ b0,
    const ushort* __restrict__ W1h, const ushort* __restrict__ W1l,
    const float* __restrict__ p1, const float* __restrict__ b1,
    const float* __restrict__ rbuf,
    float* __restrict__ out0, float* __restrict__ out1,
    int M) {
  __shared__ ushort Wh[64 * 128];    // 16KB, swizzled 16B slots
  __shared__ ushort Wl[64 * 128];    // 16KB

  const int mat = blockIdx.y >> 1;
  const int c0  = (blockIdx.y & 1) * 64;
  const uint4* GH = (const uint4*)(mat ? W1h : W0h);
  const uint4* GL = (const uint4*)(mat ? W1l : W0l);
  const float* pp = mat ? p1 : p0;
  const float* bb = mat ? b1 : b0;
  float*     outp = mat ? out1 : out0;

  const int tid  = threadIdx.x;
  const int lane = tid & 63;
  const int wv   = tid >> 6;         // wave id 0..3
  const int rA   = lane & 31;        // A row-in-tile / W col-in-tile
  const int kh   = lane >> 5;        // k half
  const int row  = blockIdx.x * 128 + wv * 32 + rA;
  const bool rowok = row < M;

  // stage W cols [c0, c0+64), hi/lo: 1024 16B slots each
  {
    uint4* LH = (uint4*)Wh;
    uint4* LL = (uint4*)Wl;
    #pragma unroll
    for (int t = 0; t < 4; ++t) {
      int q = tid + t * 256;         // 0..1023
      int wr = q >> 4, ls = q & 15;
      int phys = ls ^ (wr & 15);
      LH[wr * 16 + phys] = GH[(c0 + wr) * 16 + ls];
      LL[wr * 16 + phys] = GL[(c0 + wr) * 16 + ls];
    }
  }

  const short8v* AH = (const short8v*)Ahi;
  const short8v* AL = (const short8v*)Alo;
  const short8v zero8 = {0, 0, 0, 0, 0, 0, 0, 0};

  // A fragments for all 8 k-chunks (16B each).
  short8v ah[8], al[8];
  #pragma unroll
  for (int kc = 0; kc < 8; ++kc) {
    int fi = row * 16 + kc * 2 + kh;
    ah[kc] = rowok ? AH[fi] : zero8;
    al[kc] = rowok ? AL[fi] : zero8;
  }

  __syncthreads();

  floatx16 acc[2];
  #pragma unroll
  for (int t = 0; t < 2; ++t)
    #pragma unroll
    for (int j = 0; j < 16; ++j) acc[t][j] = 0.f;

  const short8v* WHv = (const short8v*)Wh;
  const short8v* WLv = (const short8v*)Wl;

  #pragma unroll
  for (int kc = 0; kc < 8; ++kc) {
    int fk = kc * 2 + kh;
    int ph = fk ^ (rA & 15);         // swizzled slot (wrow&15 == rA&15)
    short8v wh[2], wl[2];
    #pragma unroll
    for (int t = 0; t < 2; ++t) {
      wh[t] = WHv[(t * 32 + rA) * 16 + ph];
      wl[t] = WLv[(t * 32 + rA) * 16 + ph];
    }
    #pragma unroll
    for (int t = 0; t < 2; ++t)
      acc[t] = __builtin_amdgcn_mfma_f32_32x32x16_bf16(ah[kc], wh[t], acc[t], 0, 0, 0);
    #pragma unroll
    for (int t = 0; t < 2; ++t)
      acc[t] = __builtin_amdgcn_mfma_f32_32x32x16_bf16(ah[kc], wl[t], acc[t], 0, 0, 0);
    #pragma unroll
    for (int t = 0; t < 2; ++t)
      acc[t] = __builtin_amdgcn_mfma_f32_32x32x16_bf16(al[kc], wh[t], acc[t], 0, 0, 0);
  }

  float bcol[2], pcol[2];
  #pragma unroll
  for (int t = 0; t < 2; ++t) {
    bcol[t] = bb[c0 + t * 32 + rA];
    pcol[t] = pp[c0 + t * 32 + rA];
  }
  #pragma unroll
  for (int r = 0; r < 16; ++r) {
    int r32 = (r & 3) + 8 * (r >> 2) + 4 * kh;
    int orow = blockIdx.x * 128 + wv * 32 + r32;
    if (orow < M) {
      float rb = rbuf[orow];
      #pragma unroll
      for (int t = 0; t < 2; ++t) {
        float v = acc[t][r] + fmaf(rb, pcol[t], bcol[t]);
        v = fmaxf(v, 0.f);
        outp[(size_t)orow * CH + c0 + t * 32 + rA] = v;
      }
    }
  }
}

extern "C" void kernel_launch(void* const* d_in, const int* in_sizes, int n_in,
                              void* d_out, int out_size, void* d_ws, size_t ws_size,
                              hipStream_t stream) {
  const float* x      = (const float*)d_in[0];
  const int*   ei     = (const int*)d_in[1];
  const float* W_base = (const float*)d_in[2];
  const float* b_base = (const float*)d_in[3];
  const float* W_mu   = (const float*)d_in[4];
  const float* b_mu   = (const float*)d_in[5];
  const float* W_ls   = (const float*)d_in[6];
  const float* b_ls   = (const float*)d_in[7];
  float* out = (float*)d_out;

  const int N = in_sizes[0] / CH;
  const int E = in_sizes[1] / 2;

  char* ws = (char*)d_ws;
  size_t off = 0;
  auto carve = [&](size_t bytes) -> void* {
    void* p = ws + off;
    off += (bytes + 511) & ~(size_t)511;
    return p;
  };
  int*    cnt    = (int*)carve((size_t)N * 4);
  int*    rowptr = (int*)carve((size_t)(N + 1) * 4);
  int*    cursor = (int*)carve((size_t)N * 4);
  int*    col    = (int*)carve((size_t)E * 4);
  float*  dinv   = (float*)carve((size_t)N * 4);
  float*  rbuf   = (float*)carve((size_t)N * 4);
  int*    bsum   = (int*)carve((size_t)2048 * 4);
  int*    total  = (int*)carve((size_t)4);
  float*  pm   = (float*)carve((size_t)CH * 4);
  float*  ps   = (float*)carve((size_t)CH * 4);
  ushort* Wcmh = (ushort*)carve((size_t)CH * CH * 2);
  ushort* Wcml = (ushort*)carve((size_t)CH * CH * 2);
  ushort* Wcsh = (ushort*)carve((size_t)CH * CH * 2);
  ushort* Wcsl = (ushort*)carve((size_t)CH * CH * 2);
  ushort* xh   = (ushort*)carve((size_t)N * CH * 2);  // x as fp16
  ushort* t1h  = (ushort*)carve((size_t)N * CH * 2);  // A@x as fp16
  ushort* zhi  = (ushort*)carve((size_t)N * CH * 2);  // z = A^2@x hi
  ushort* zlo  = (ushort*)carve((size_t)N * CH * 2);  // z lo

  hipMemsetAsync(cnt, 0, (size_t)N * 4, stream);

  int eb = (E + 255) / 256;
  int nb = (N + SCAN_CHUNK - 1) / SCAN_CHUNK;
  count_kernel<<<eb, 256, 0, stream>>>(ei, E, cnt);
  scan_sum_kernel<<<nb, 256, 0, stream>>>(cnt, N, bsum);
  scan_bsum_kernel<<<1, 256, 0, stream>>>(bsum, nb, total);
  scan_fin_kernel<<<nb, 256, 0, stream>>>(cnt, N, bsum, total, rowptr, cursor, dinv);
  fill_kernel<<<eb, 256, 0, stream>>>(ei, E, cursor, col);

  wcombsplit_kernel<<<33, 256, 0, stream>>>(W_base, b_base, W_mu, W_ls,
                                            Wcmh, Wcml, Wcsh, Wcsl, pm, ps);

  int n8 = N * CH / 8;
  f2h_kernel<<<(n8 + 255) / 256, 256, 0, stream>>>(x, xh, n8);

  int ab = (N * 64 + 255) / 256;
  int gb = (N + 127) / 128;

  // t1h = A@xh (fp16)
  agg_kernel<<<ab, 256, 0, stream>>>(xh, rowptr, col, dinv,
                                     t1h, nullptr, nullptr, nullptr, N);
  // z = A@t1h (split bf16), r = A@1
  agg_kernel<<<ab, 256, 0, stream>>>(t1h, rowptr, col, dinv,
                                     nullptr, zhi, zlo, rbuf, N);
  // m = relu(z@Wcm + r*pm + bmu), s = relu(z@Wcs + r*ps + bls)
  gemm_mfma_kernel<<<dim3(gb, 4), 256, 0, stream>>>(zhi, zlo,
                                           Wcmh, Wcml, pm, b_mu,
                                           Wcsh, Wcsl, ps, b_ls,
                                           rbuf, out, out + (size_t)N * CH, N);
}

// Round 12
// 181.889 us; speedup vs baseline: 1.7594x; 1.0284x over previous
//
#include <hip/hip_runtime.h>
#include <hip/hip_fp16.h>

// GCN edge-predictor encoder, R12: R11 + memset deleted (fused into f2h).
//   m = relu(A^2 x (Wb@Wmu) + (A1)(bb@Wmu) + bmu), s likewise with W_ls.
//   f2h(x)+zero(cnt) -> count -> scan -> fill (CSR) -> wcombsplit
//   -> t1h = A@xh (fp16) -> z = A@t1h (split bf16) + r = A@1
//   -> dual MFMA gemm: m,s = relu(z@Wc + r*p + b)
// R11 profile: hipMemsetAsync(cnt, 200KB) ran as a 42us fillBufferAligned
// dispatch (22% of total!) -- replaced by 12.5K int4-writes inside f2h.
// Gather: fp16 features (f32 accum), one wave/node, 4 edge-groups x 16
// lanes x 16B; ladder 16/8/4/tail. GEMM: split-bf16 32x32x16 MFMA,
// W-slice in 32KB swizzled LDS, grid.y = mat*2+colhalf.

#define CH 128
#define SCAN_CHUNK 1024

typedef __attribute__((ext_vector_type(8))) short short8v;
typedef __attribute__((ext_vector_type(16))) float floatx16;

__device__ inline ushort f2bf(float f) {
  uint u = __builtin_bit_cast(uint, f);
  uint r = (u + 0x7FFFu + ((u >> 16) & 1u)) >> 16;
  return (ushort)r;
}
__device__ inline float bf2f(ushort h) {
  uint u = ((uint)h) << 16;
  return __builtin_bit_cast(float, u);
}

__global__ void count_kernel(const int* __restrict__ ei, int E, int* __restrict__ cnt) {
  int e = blockIdx.x * blockDim.x + threadIdx.x;
  if (e < E) atomicAdd(&cnt[ei[E + e]], 1);
}

__global__ __launch_bounds__(256) void scan_sum_kernel(const int* __restrict__ cnt,
    int n, int* __restrict__ bsum) {
  __shared__ int sdata[256];
  int base = blockIdx.x * SCAN_CHUNK;
  int tid = threadIdx.x;
  int s = 0;
  #pragma unroll
  for (int j = 0; j < 4; ++j) {
    int i = base + tid * 4 + j;
    if (i < n) s += cnt[i];
  }
  sdata[tid] = s;
  __syncthreads();
  for (int off = 128; off > 0; off >>= 1) {
    if (tid < off) sdata[tid] += sdata[tid + off];
    __syncthreads();
  }
  if (tid == 0) bsum[blockIdx.x] = sdata[0];
}

__global__ __launch_bounds__(256) void scan_bsum_kernel(int* __restrict__ bsum,
    int nb, int* __restrict__ total_out) {
  __shared__ int sdata[1024];
  int tid = threadIdx.x;
  #pragma unroll
  for (int j = 0; j < 4; ++j) {
    int i = tid * 4 + j;
    sdata[i] = (i < nb) ? bsum[i] : 0;
  }
  __syncthreads();
  if (tid == 0) {
    int run = 0;
    for (int i = 0; i < nb; ++i) { int v = sdata[i]; sdata[i] = run; run += v; }
    *total_out = run;
  }
  __syncthreads();
  #pragma unroll
  for (int j = 0; j < 4; ++j) {
    int i = tid * 4 + j;
    if (i < nb) bsum[i] = sdata[i];
  }
}

__global__ __launch_bounds__(256) void scan_fin_kernel(const int* __restrict__ cnt,
    int n, const int* __restrict__ bsum, const int* __restrict__ total,
    int* __restrict__ rowptr, int* __restrict__ cursor, float* __restrict__ dinv) {
  __shared__ int sthr[256];
  int base = blockIdx.x * SCAN_CHUNK;
  int tid = threadIdx.x;
  int v[4];
  int ts = 0;
  #pragma unroll
  for (int j = 0; j < 4; ++j) {
    int i = base + tid * 4 + j;
    v[j] = (i < n) ? cnt[i] : 0;
    ts += v[j];
  }
  sthr[tid] = ts;
  __syncthreads();
  for (int off = 1; off < 256; off <<= 1) {
    int t = (tid >= off) ? sthr[tid - off] : 0;
    __syncthreads();
    sthr[tid] += t;
    __syncthreads();
  }
  int excl = sthr[tid] - ts + bsum[blockIdx.x];
  #pragma unroll
  for (int j = 0; j < 4; ++j) {
    int i = base + tid * 4 + j;
    if (i < n) {
      rowptr[i] = excl;
      cursor[i] = excl;
      dinv[i]   = rsqrtf((float)(v[j] + 1));
      excl += v[j];
    }
  }
  if (blockIdx.x == 0 && tid == 0) rowptr[n] = *total;
}

__global__ void fill_kernel(const int* __restrict__ ei, int E,
                            int* __restrict__ cursor, int* __restrict__ col) {
  int e = blockIdx.x * blockDim.x + threadIdx.x;
  if (e < E) {
    int d = ei[E + e];
    int pos = atomicAdd(&cursor[d], 1);
    col[pos] = ei[e];
  }
}

// x (f32) -> xh (fp16), 8 elements/thread; first ncnt4 threads also zero cnt
// (replaces the 42us hipMemsetAsync fill dispatch).
__global__ __launch_bounds__(256) void f2h_kernel(const float* __restrict__ in,
    ushort* __restrict__ outh, int n8, int* __restrict__ cnt, int ncnt4) {
  int t = blockIdx.x * 256 + threadIdx.x;
  if (t < ncnt4) ((int4*)cnt)[t] = make_int4(0, 0, 0, 0);
  if (t < n8) {
    const float4* f4 = (const float4*)in;
    float4 a = f4[2 * t], b = f4[2 * t + 1];
    __half h[8] = {__float2half_rn(a.x), __float2half_rn(a.y),
                   __float2half_rn(a.z), __float2half_rn(a.w),
                   __float2half_rn(b.x), __float2half_rn(b.y),
                   __float2half_rn(b.z), __float2half_rn(b.w)};
    ((uint4*)outh)[t] = *(const uint4*)h;
  }
}

// Fused: Wc = Wb@W2 computed and written DIRECTLY as transposed split-bf16
// [c][k] hi/lo. Blocks 0-31: 16 per matrix; block 32: pm = bb@Wmu, ps = bb@Wls.
__global__ __launch_bounds__(256) void wcombsplit_kernel(
    const float* __restrict__ Wb, const float* __restrict__ bb,
    const float* __restrict__ Wmu, const float* __restrict__ Wls,
    ushort* __restrict__ Wcmh, ushort* __restrict__ Wcml,
    ushort* __restrict__ Wcsh, ushort* __restrict__ Wcsl,
    float* __restrict__ pm, float* __restrict__ ps) {
  int gid = blockIdx.x;
  if (gid < 32) {
    int sel = gid >> 4;
    const float* W2 = sel ? Wls : Wmu;
    ushort* Wh = sel ? Wcsh : Wcmh;
    ushort* Wl = sel ? Wcsl : Wcml;
    int o = (gid & 15) * 1024 + threadIdx.x * 4;  // [k][c] linear, 4 consecutive c
    int k = o >> 7, c = o & 127;
    float acc[4] = {0.f, 0.f, 0.f, 0.f};
    for (int j = 0; j < 128; ++j) {
      float a = Wb[k * 128 + j];
      const float* wr = &W2[j * 128 + c];
      acc[0] = fmaf(a, wr[0], acc[0]);
      acc[1] = fmaf(a, wr[1], acc[1]);
      acc[2] = fmaf(a, wr[2], acc[2]);
      acc[3] = fmaf(a, wr[3], acc[3]);
    }
    #pragma unroll
    for (int j = 0; j < 4; ++j) {     // write transposed [c][k] split
      ushort h = f2bf(acc[j]);
      Wh[(c + j) * 128 + k] = h;
      Wl[(c + j) * 128 + k] = f2bf(acc[j] - bf2f(h));
    }
  } else {
    int t = threadIdx.x;
    int sel = t >> 7, c = t & 127;
    const float* W2 = sel ? Wls : Wmu;
    float acc = 0.f;
    for (int j = 0; j < 128; ++j) acc = fmaf(bb[j], W2[j * 128 + c], acc);
    (sel ? ps : pm)[c] = acc;
  }
}

__device__ inline void h8_fma(uint4 v, float s, float* a) {
  const __half2* h2 = (const __half2*)&v;
  #pragma unroll
  for (int i = 0; i < 4; ++i) {
    float2 f = __half22float2(h2[i]);
    a[2 * i]     = fmaf(s, f.x, a[2 * i]);
    a[2 * i + 1] = fmaf(s, f.y, a[2 * i + 1]);
  }
}

// One wave per node; 4 edge-groups of 16 lanes; lane cl owns channels
// cl*8..cl*8+7 (one 16B uint4 = 8 halfs per row). Accum f32.
// out[w] = dinv[w] * ( dinv[w]*feat[w] + sum_src dinv[src]*feat[src] ).
// Output: fp16 (out_h) or split bf16 (out_hi/lo).
// r_out (optional): r[w] = dinv[w]*(dinv[w] + sum_src dinv[src]) = (A@1)[w].
__global__ __launch_bounds__(256) void agg_kernel(const ushort* __restrict__ feat,
    const int* __restrict__ rowptr, const int* __restrict__ col,
    const float* __restrict__ dinv,
    ushort* __restrict__ out_h, ushort* __restrict__ out_hi,
    ushort* __restrict__ out_lo, float* __restrict__ r_out, int n) {
  int w = (blockIdx.x * 256 + threadIdx.x) >> 6;
  if (w >= n) return;
  int lane = threadIdx.x & 63;
  int g  = lane >> 4;        // edge group 0..3
  int cl = lane & 15;        // uint4 slot (8 channels)
  const uint4* u4 = (const uint4*)feat;
  float di = dinv[w];
  float a[8] = {0.f, 0.f, 0.f, 0.f, 0.f, 0.f, 0.f, 0.f};
  float rsum = 0.f;
  if (g == 0) {              // self-loop term, scaled by dinv[w]
    h8_fma(u4[(size_t)w * 16 + cl], di, a);
  }
  int s = rowptr[w], e = rowptr[w + 1];
  int j = s;
  for (; j + 16 <= e; j += 16) {   // 4 edges per group
    int c0 = col[j + g];
    int c1 = col[j + 4 + g];
    int c2 = col[j + 8 + g];
    int c3 = col[j + 12 + g];
    float s0 = dinv[c0], s1 = dinv[c1], s2 = dinv[c2], s3 = dinv[c3];
    rsum += (s0 + s1) + (s2 + s3);
    uint4 v0 = u4[(size_t)c0 * 16 + cl];
    uint4 v1 = u4[(size_t)c1 * 16 + cl];
    uint4 v2 = u4[(size_t)c2 * 16 + cl];
    uint4 v3 = u4[(size_t)c3 * 16 + cl];
    h8_fma(v0, s0, a);
    h8_fma(v1, s1, a);
    h8_fma(v2, s2, a);
    h8_fma(v3, s3, a);
  }
  for (; j + 8 <= e; j += 8) {     // 2 edges per group
    int c0 = col[j + g];
    int c1 = col[j + 4 + g];
    float s0 = dinv[c0], s1 = dinv[c1];
    rsum += s0 + s1;
    uint4 v0 = u4[(size_t)c0 * 16 + cl];
    uint4 v1 = u4[(size_t)c1 * 16 + cl];
    h8_fma(v0, s0, a);
    h8_fma(v1, s1, a);
  }
  for (; j < e; j += 4) {          // <=1 edge per group, masked
    int jj = j + g;
    if (jj < e) {
      int c = col[jj];
      float s0 = dinv[c];
      rsum += s0;
      h8_fma(u4[(size_t)c * 16 + cl], s0, a);
    }
  }
  // reduce across the 4 groups (xor 16, then 32)
  #pragma unroll
  for (int m = 16; m <= 32; m <<= 1) {
    #pragma unroll
    for (int i = 0; i < 8; ++i) a[i] += __shfl_xor(a[i], m);
    rsum += __shfl_xor(rsum, m);
  }
  if (g == 0) {
    float r[8];
    #pragma unroll
    for (int i = 0; i < 8; ++i) r[i] = a[i] * di;
    if (out_h) {
      __half h[8];
      #pragma unroll
      for (int i = 0; i < 8; ++i) h[i] = __float2half_rn(r[i]);
      ((uint4*)out_h)[(size_t)w * 16 + cl] = *(const uint4*)h;
    } else {
      ushort h[8], l[8];
      #pragma unroll
      for (int i = 0; i < 8; ++i) {
        h[i] = f2bf(r[i]);
        l[i] = f2bf(r[i] - bf2f(h[i]));
      }
      size_t o = (size_t)w * 32 + cl * 2;
      ((ushort4*)out_hi)[o]     = make_ushort4(h[0], h[1], h[2], h[3]);
      ((ushort4*)out_hi)[o + 1] = make_ushort4(h[4], h[5], h[6], h[7]);
      ((ushort4*)out_lo)[o]     = make_ushort4(l[0], l[1], l[2], l[3]);
      ((ushort4*)out_lo)[o + 1] = make_ushort4(l[4], l[5], l[6], l[7]);
    }
    if (r_out && cl == 0) r_out[w] = di * (di + rsum);
  }
}

// MFMA GEMM, col-split: out = relu(A@W + r*p + b). A = bf16 hi/lo [M][128]
// (regs), W = bf16 hi/lo transposed [c][k], 64-col slice in 32KB swizzled LDS.
// Block = 4 waves x 32 rows = 128 rows x 64 cols. blockIdx.y = mat*2+colhalf.
__global__ __launch_bounds__(256) void gemm_mfma_kernel(
    const ushort* __restrict__ Ahi, const ushort* __restrict__ Alo,
    const ushort* __restrict__ W0h, const ushort* __restrict__ W0l,
    const float* __restrict__ p0, const float* __restrict__ b0,
    const ushort* __restrict__ W1h, const ushort* __restrict__ W1l,
    const float* __restrict__ p1, const float* __restrict__ b1,
    const float* __restrict__ rbuf,
    float* __restrict__ out0, float* __restrict__ out1,
    int M) {
  __shared__ ushort Wh[64 * 128];    // 16KB, swizzled 16B slots
  __shared__ ushort Wl[64 * 128];    // 16KB

  const int mat = blockIdx.y >> 1;
  const int c0  = (blockIdx.y & 1) * 64;
  const uint4* GH = (const uint4*)(mat ? W1h : W0h);
  const uint4* GL = (const uint4*)(mat ? W1l : W0l);
  const float* pp = mat ? p1 : p0;
  const float* bb = mat ? b1 : b0;
  float*     outp = mat ? out1 : out0;

  const int tid  = threadIdx.x;
  const int lane = tid & 63;
  const int wv   = tid >> 6;         // wave id 0..3
  const int rA   = lane & 31;        // A row-in-tile / W col-in-tile
  const int kh   = lane >> 5;        // k half
  const int row  = blockIdx.x * 128 + wv * 32 + rA;
  const bool rowok = row < M;

  // stage W cols [c0, c0+64), hi/lo: 1024 16B slots each
  {
    uint4* LH = (uint4*)Wh;
    uint4* LL = (uint4*)Wl;
    #pragma unroll
    for (int t = 0; t < 4; ++t) {
      int q = tid + t * 256;         // 0..1023
      int wr = q >> 4, ls = q & 15;
      int phys = ls ^ (wr & 15);
      LH[wr * 16 + phys] = GH[(c0 + wr) * 16 + ls];
      LL[wr * 16 + phys] = GL[(c0 + wr) * 16 + ls];
    }
  }

  const short8v* AH = (const short8v*)Ahi;
  const short8v* AL = (const short8v*)Alo;
  const short8v zero8 = {0, 0, 0, 0, 0, 0, 0, 0};

  // A fragments for all 8 k-chunks (16B each).
  short8v ah[8], al[8];
  #pragma unroll
  for (int kc = 0; kc < 8; ++kc) {
    int fi = row * 16 + kc * 2 + kh;
    ah[kc] = rowok ? AH[fi] : zero8;
    al[kc] = rowok ? AL[fi] : zero8;
  }

  __syncthreads();

  floatx16 acc[2];
  #pragma unroll
  for (int t = 0; t < 2; ++t)
    #pragma unroll
    for (int j = 0; j < 16; ++j) acc[t][j] = 0.f;

  const short8v* WHv = (const short8v*)Wh;
  const short8v* WLv = (const short8v*)Wl;

  #pragma unroll
  for (int kc = 0; kc < 8; ++kc) {
    int fk = kc * 2 + kh;
    int ph = fk ^ (rA & 15);         // swizzled slot (wrow&15 == rA&15)
    short8v wh[2], wl[2];
    #pragma unroll
    for (int t = 0; t < 2; ++t) {
      wh[t] = WHv[(t * 32 + rA) * 16 + ph];
      wl[t] = WLv[(t * 32 + rA) * 16 + ph];
    }
    #pragma unroll
    for (int t = 0; t < 2; ++t)
      acc[t] = __builtin_amdgcn_mfma_f32_32x32x16_bf16(ah[kc], wh[t], acc[t], 0, 0, 0);
    #pragma unroll
    for (int t = 0; t < 2; ++t)
      acc[t] = __builtin_amdgcn_mfma_f32_32x32x16_bf16(ah[kc], wl[t], acc[t], 0, 0, 0);
    #pragma unroll
    for (int t = 0; t < 2; ++t)
      acc[t] = __builtin_amdgcn_mfma_f32_32x32x16_bf16(al[kc], wh[t], acc[t], 0, 0, 0);
  }

  float bcol[2], pcol[2];
  #pragma unroll
  for (int t = 0; t < 2; ++t) {
    bcol[t] = bb[c0 + t * 32 + rA];
    pcol[t] = pp[c0 + t * 32 + rA];
  }
  #pragma unroll
  for (int r = 0; r < 16; ++r) {
    int r32 = (r & 3) + 8 * (r >> 2) + 4 * kh;
    int orow = blockIdx.x * 128 + wv * 32 + r32;
    if (orow < M) {
      float rb = rbuf[orow];
      #pragma unroll
      for (int t = 0; t < 2; ++t) {
        float v = acc[t][r] + fmaf(rb, pcol[t], bcol[t]);
        v = fmaxf(v, 0.f);
        outp[(size_t)orow * CH + c0 + t * 32 + rA] = v;
      }
    }
  }
}

extern "C" void kernel_launch(void* const* d_in, const int* in_sizes, int n_in,
                              void* d_out, int out_size, void* d_ws, size_t ws_size,
                              hipStream_t stream) {
  const float* x      = (const float*)d_in[0];
  const int*   ei     = (const int*)d_in[1];
  const float* W_base = (const float*)d_in[2];
  const float* b_base = (const float*)d_in[3];
  const float* W_mu   = (const float*)d_in[4];
  const float* b_mu   = (const float*)d_in[5];
  const float* W_ls   = (const float*)d_in[6];
  const float* b_ls   = (const float*)d_in[7];
  float* out = (float*)d_out;

  const int N = in_sizes[0] / CH;
  const int E = in_sizes[1] / 2;

  char* ws = (char*)d_ws;
  size_t off = 0;
  auto carve = [&](size_t bytes) -> void* {
    void* p = ws + off;
    off += (bytes + 511) & ~(size_t)511;
    return p;
  };
  int*    cnt    = (int*)carve((size_t)N * 4);
  int*    rowptr = (int*)carve((size_t)(N + 1) * 4);
  int*    cursor = (int*)carve((size_t)N * 4);
  int*    col    = (int*)carve((size_t)E * 4);
  float*  dinv   = (float*)carve((size_t)N * 4);
  float*  rbuf   = (float*)carve((size_t)N * 4);
  int*    bsum   = (int*)carve((size_t)2048 * 4);
  int*    total  = (int*)carve((size_t)4);
  float*  pm   = (float*)carve((size_t)CH * 4);
  float*  ps   = (float*)carve((size_t)CH * 4);
  ushort* Wcmh = (ushort*)carve((size_t)CH * CH * 2);
  ushort* Wcml = (ushort*)carve((size_t)CH * CH * 2);
  ushort* Wcsh = (ushort*)carve((size_t)CH * CH * 2);
  ushort* Wcsl = (ushort*)carve((size_t)CH * CH * 2);
  ushort* xh   = (ushort*)carve((size_t)N * CH * 2);  // x as fp16
  ushort* t1h  = (ushort*)carve((size_t)N * CH * 2);  // A@x as fp16
  ushort* zhi  = (ushort*)carve((size_t)N * CH * 2);  // z = A^2@x hi
  ushort* zlo  = (ushort*)carve((size_t)N * CH * 2);  // z lo

  int eb = (E + 255) / 256;
  int nb = (N + SCAN_CHUNK - 1) / SCAN_CHUNK;
  int n8 = N * CH / 8;
  int ncnt4 = (N + 3) / 4;

  // f2h + cnt zeroing (replaces hipMemsetAsync)
  f2h_kernel<<<(n8 + 255) / 256, 256, 0, stream>>>(x, xh, n8, cnt, ncnt4);

  count_kernel<<<eb, 256, 0, stream>>>(ei, E, cnt);
  scan_sum_kernel<<<nb, 256, 0, stream>>>(cnt, N, bsum);
  scan_bsum_kernel<<<1, 256, 0, stream>>>(bsum, nb, total);
  scan_fin_kernel<<<nb, 256, 0, stream>>>(cnt, N, bsum, total, rowptr, cursor, dinv);
  fill_kernel<<<eb, 256, 0, stream>>>(ei, E, cursor, col);

  wcombsplit_kernel<<<33, 256, 0, stream>>>(W_base, b_base, W_mu, W_ls,
                                            Wcmh, Wcml, Wcsh, Wcsl, pm, ps);

  int ab = (N * 64 + 255) / 256;
  int gb = (N + 127) / 128;

  // t1h = A@xh (fp16)
  agg_kernel<<<ab, 256, 0, stream>>>(xh, rowptr, col, dinv,
                                     t1h, nullptr, nullptr, nullptr, N);
  // z = A@t1h (split bf16), r = A@1
  agg_kernel<<<ab, 256, 0, stream>>>(t1h, rowptr, col, dinv,
                                     nullptr, zhi, zlo, rbuf, N);
  // m = relu(z@Wcm + r*pm + bmu), s = relu(z@Wcs + r*ps + bls)
  gemm_mfma_kernel<<<dim3(gb, 4), 256, 0, stream>>>(zhi, zlo,
                                           Wcmh, Wcml, pm, b_mu,
                                           Wcsh, Wcsl, ps, b_ls,
                                           rbuf, out, out + (size_t)N * CH, N);
}

// Round 13
// 163.800 us; speedup vs baseline: 1.9537x; 1.1104x over previous
//
#include <hip/hip_runtime.h>
#include <hip/hip_fp16.h>

// GCN edge-predictor encoder, R13: fused dispatches + fp16 tail.
//   m = relu(A^2 x (Wb@Wmu) + (A1)(bb@Wmu) + bmu), s likewise with W_ls.
// Chain (7 dispatches, was 10):
//   mega1 [f2h(x)->xh + zero cnt/flags + Wc=Wb@W2 split-fp16 + pm/ps]
//   -> count -> scan1p (single-pass: publish aggregate+flag, spin-wait
//   predecessors; 49 co-resident blocks) -> fill
//   -> agg1: t1h = A@xh (fp16) -> agg2: zh = A@t1h (fp16) + r = A@1
//   -> gemm: m,s = relu(zh@Wc + r*p + b), f16 MFMA, 2 passes (Wh+Wl).
// Gather: one wave/node, 4 edge-groups x 16 lanes x 16B, f32 accum.
// Precision: fp16 features (2.4e-4 rel) + split-fp16 W; adds ~1e-3 to
// absmax vs 1.18e-2 threshold.

#define CH 128
#define SCAN_CHUNK 1024

typedef __attribute__((ext_vector_type(8))) _Float16 half8v;
typedef __attribute__((ext_vector_type(16))) float floatx16;

__global__ void count_kernel(const int* __restrict__ ei, int E, int* __restrict__ cnt) {
  int e = blockIdx.x * blockDim.x + threadIdx.x;
  if (e < E) atomicAdd(&cnt[ei[E + e]], 1);
}

// Single-pass device-wide scan over cnt (nb blocks of SCAN_CHUNK):
// per-block sum -> publish gsum+flag -> wait all predecessors -> offset ->
// local scan -> write rowptr/cursor/dinv; last block writes rowptr[n].
__global__ __launch_bounds__(256) void scan1p_kernel(const int* __restrict__ cnt,
    int n, int nb, int* __restrict__ gsum, int* __restrict__ flags,
    int* __restrict__ rowptr, int* __restrict__ cursor, float* __restrict__ dinv) {
  __shared__ int sthr[256];
  __shared__ int soff;
  int bid = blockIdx.x;
  int base = bid * SCAN_CHUNK;
  int tid = threadIdx.x;
  int v[4];
  int ts = 0;
  #pragma unroll
  for (int j = 0; j < 4; ++j) {
    int i = base + tid * 4 + j;
    v[j] = (i < n) ? cnt[i] : 0;
    ts += v[j];
  }
  sthr[tid] = ts;
  if (tid == 0) soff = 0;
  __syncthreads();
  for (int off = 1; off < 256; off <<= 1) {   // inclusive scan of thread sums
    int t = (tid >= off) ? sthr[tid - off] : 0;
    __syncthreads();
    sthr[tid] += t;
    __syncthreads();
  }
  int blocksum = sthr[255];
  if (tid == 0) {                             // publish aggregate
    gsum[bid] = blocksum;
    __threadfence();
    atomicExch(&flags[bid], 1);
  }
  // accumulate predecessor aggregates (parallel spin over j<bid)
  for (int j = tid; j < bid; j += 256) {
    while (atomicAdd(&flags[j], 0) == 0) {}
    atomicAdd(&soff, atomicAdd(&gsum[j], 0));
  }
  __syncthreads();
  int offset = soff;
  int excl = sthr[tid] - ts + offset;
  #pragma unroll
  for (int j = 0; j < 4; ++j) {
    int i = base + tid * 4 + j;
    if (i < n) {
      rowptr[i] = excl;
      cursor[i] = excl;
      dinv[i]   = rsqrtf((float)(v[j] + 1));
      excl += v[j];
    }
  }
  if (bid == nb - 1 && tid == 0) rowptr[n] = offset + blocksum;
}

__global__ void fill_kernel(const int* __restrict__ ei, int E,
                            int* __restrict__ cursor, int* __restrict__ col) {
  int e = blockIdx.x * blockDim.x + threadIdx.x;
  if (e < E) {
    int d = ei[E + e];
    int pos = atomicAdd(&cursor[d], 1);
    col[pos] = ei[e];
  }
}

// mega1: blocks 0-31: Wc = Wb@W2 -> transposed split-fp16 [c][k] hi/lo.
// block 32: pm = bb@Wmu, ps = bb@Wls (256 thr = 2x128 cols) + zero flags.
// blocks 33+: f2h(x) -> xh (8 elem/thread) + zero cnt.
__global__ __launch_bounds__(256) void mega1_kernel(
    const float* __restrict__ x, ushort* __restrict__ xh, int n8,
    int* __restrict__ cnt, int ncnt4, int* __restrict__ flags,
    const float* __restrict__ Wb, const float* __restrict__ bb,
    const float* __restrict__ Wmu, const float* __restrict__ Wls,
    ushort* __restrict__ Wcmh, ushort* __restrict__ Wcml,
    ushort* __restrict__ Wcsh, ushort* __restrict__ Wcsl,
    float* __restrict__ pm, float* __restrict__ ps) {
  int gid = blockIdx.x;
  int tid = threadIdx.x;
  if (gid < 32) {
    int sel = gid >> 4;
    const float* W2 = sel ? Wls : Wmu;
    ushort* Wh = sel ? Wcsh : Wcmh;
    ushort* Wl = sel ? Wcsl : Wcml;
    int o = (gid & 15) * 1024 + tid * 4;      // [k][c] linear, 4 consecutive c
    int k = o >> 7, c = o & 127;
    float acc[4] = {0.f, 0.f, 0.f, 0.f};
    for (int j = 0; j < 128; ++j) {
      float a = Wb[k * 128 + j];
      const float* wr = &W2[j * 128 + c];
      acc[0] = fmaf(a, wr[0], acc[0]);
      acc[1] = fmaf(a, wr[1], acc[1]);
      acc[2] = fmaf(a, wr[2], acc[2]);
      acc[3] = fmaf(a, wr[3], acc[3]);
    }
    #pragma unroll
    for (int j = 0; j < 4; ++j) {             // write transposed [c][k] split fp16
      _Float16 h = (_Float16)acc[j];
      float resid = acc[j] - (float)h;
      _Float16 l = (_Float16)resid;
      Wh[(c + j) * 128 + k] = __builtin_bit_cast(ushort, h);
      Wl[(c + j) * 128 + k] = __builtin_bit_cast(ushort, l);
    }
  } else if (gid == 32) {
    if (tid < 16) ((int4*)flags)[tid] = make_int4(0, 0, 0, 0);
    int sel = tid >> 7, c = tid & 127;
    const float* W2 = sel ? Wls : Wmu;
    float acc = 0.f;
    for (int j = 0; j < 128; ++j) acc = fmaf(bb[j], W2[j * 128 + c], acc);
    (sel ? ps : pm)[c] = acc;
  } else {
    int t = (gid - 33) * 256 + tid;
    if (t < ncnt4) ((int4*)cnt)[t] = make_int4(0, 0, 0, 0);
    if (t < n8) {
      const float4* f4 = (const float4*)x;
      float4 a = f4[2 * t], b = f4[2 * t + 1];
      __half h[8] = {__float2half_rn(a.x), __float2half_rn(a.y),
                     __float2half_rn(a.z), __float2half_rn(a.w),
                     __float2half_rn(b.x), __float2half_rn(b.y),
                     __float2half_rn(b.z), __float2half_rn(b.w)};
      ((uint4*)xh)[t] = *(const uint4*)h;
    }
  }
}

__device__ inline void h8_fma(uint4 v, float s, float* a) {
  const __half2* h2 = (const __half2*)&v;
  #pragma unroll
  for (int i = 0; i < 4; ++i) {
    float2 f = __half22float2(h2[i]);
    a[2 * i]     = fmaf(s, f.x, a[2 * i]);
    a[2 * i + 1] = fmaf(s, f.y, a[2 * i + 1]);
  }
}

// One wave per node; 4 edge-groups of 16 lanes; lane cl owns channels
// cl*8..cl*8+7 (one 16B uint4 = 8 halfs per row). Accum f32, output fp16.
// out[w] = dinv[w] * ( dinv[w]*feat[w] + sum_src dinv[src]*feat[src] ).
// r_out (optional): r[w] = dinv[w]*(dinv[w] + sum_src dinv[src]) = (A@1)[w].
__global__ __launch_bounds__(256) void agg_kernel(const ushort* __restrict__ feat,
    const int* __restrict__ rowptr, const int* __restrict__ col,
    const float* __restrict__ dinv,
    ushort* __restrict__ out_h, float* __restrict__ r_out, int n) {
  int w = (blockIdx.x * 256 + threadIdx.x) >> 6;
  if (w >= n) return;
  int lane = threadIdx.x & 63;
  int g  = lane >> 4;        // edge group 0..3
  int cl = lane & 15;        // uint4 slot (8 channels)
  const uint4* u4 = (const uint4*)feat;
  float di = dinv[w];
  float a[8] = {0.f, 0.f, 0.f, 0.f, 0.f, 0.f, 0.f, 0.f};
  float rsum = 0.f;
  if (g == 0) {              // self-loop term, scaled by dinv[w]
    h8_fma(u4[(size_t)w * 16 + cl], di, a);
  }
  int s = rowptr[w], e = rowptr[w + 1];
  int j = s;
  for (; j + 16 <= e; j += 16) {   // 4 edges per group
    int c0 = col[j + g];
    int c1 = col[j + 4 + g];
    int c2 = col[j + 8 + g];
    int c3 = col[j + 12 + g];
    float s0 = dinv[c0], s1 = dinv[c1], s2 = dinv[c2], s3 = dinv[c3];
    rsum += (s0 + s1) + (s2 + s3);
    uint4 v0 = u4[(size_t)c0 * 16 + cl];
    uint4 v1 = u4[(size_t)c1 * 16 + cl];
    uint4 v2 = u4[(size_t)c2 * 16 + cl];
    uint4 v3 = u4[(size_t)c3 * 16 + cl];
    h8_fma(v0, s0, a);
    h8_fma(v1, s1, a);
    h8_fma(v2, s2, a);
    h8_fma(v3, s3, a);
  }
  for (; j + 8 <= e; j += 8) {     // 2 edges per group
    int c0 = col[j + g];
    int c1 = col[j + 4 + g];
    float s0 = dinv[c0], s1 = dinv[c1];
    rsum += s0 + s1;
    uint4 v0 = u4[(size_t)c0 * 16 + cl];
    uint4 v1 = u4[(size_t)c1 * 16 + cl];
    h8_fma(v0, s0, a);
    h8_fma(v1, s1, a);
  }
  for (; j < e; j += 4) {          // <=1 edge per group, masked
    int jj = j + g;
    if (jj < e) {
      int c = col[jj];
      float s0 = dinv[c];
      rsum += s0;
      h8_fma(u4[(size_t)c * 16 + cl], s0, a);
    }
  }
  // reduce across the 4 groups (xor 16, then 32)
  #pragma unroll
  for (int m = 16; m <= 32; m <<= 1) {
    #pragma unroll
    for (int i = 0; i < 8; ++i) a[i] += __shfl_xor(a[i], m);
    rsum += __shfl_xor(rsum, m);
  }
  if (g == 0) {
    __half h[8];
    #pragma unroll
    for (int i = 0; i < 8; ++i) h[i] = __float2half_rn(a[i] * di);
    ((uint4*)out_h)[(size_t)w * 16 + cl] = *(const uint4*)h;
    if (r_out && cl == 0) r_out[w] = di * (di + rsum);
  }
}

// MFMA GEMM, col-split: out = relu(A@W + r*p + b). A = fp16 [M][128] (regs),
// W = split-fp16 transposed [c][k], 64-col slice in 32KB swizzled LDS.
// f16 MFMA, 2 passes (A@Wh + A@Wl). Block = 4 waves x 32 rows = 128 rows x
// 64 cols. blockIdx.y = mat*2 + colhalf.
__global__ __launch_bounds__(256) void gemm_mfma_kernel(
    const ushort* __restrict__ Ah16,
    const ushort* __restrict__ W0h, const ushort* __restrict__ W0l,
    const float* __restrict__ p0, const float* __restrict__ b0,
    const ushort* __restrict__ W1h, const ushort* __restrict__ W1l,
    const float* __restrict__ p1, const float* __restrict__ b1,
    const float* __restrict__ rbuf,
    float* __restrict__ out0, float* __restrict__ out1,
    int M) {
  __shared__ ushort Wh[64 * 128];    // 16KB, swizzled 16B slots
  __shared__ ushort Wl[64 * 128];    // 16KB

  const int mat = blockIdx.y >> 1;
  const int c0  = (blockIdx.y & 1) * 64;
  const uint4* GH = (const uint4*)(mat ? W1h : W0h);
  const uint4* GL = (const uint4*)(mat ? W1l : W0l);
  const float* pp = mat ? p1 : p0;
  const float* bb = mat ? b1 : b0;
  float*     outp = mat ? out1 : out0;

  const int tid  = threadIdx.x;
  const int lane = tid & 63;
  const int wv   = tid >> 6;         // wave id 0..3
  const int rA   = lane & 31;        // A row-in-tile / W col-in-tile
  const int kh   = lane >> 5;        // k half
  const int row  = blockIdx.x * 128 + wv * 32 + rA;
  const bool rowok = row < M;

  // stage W cols [c0, c0+64), hi/lo: 1024 16B slots each
  {
    uint4* LH = (uint4*)Wh;
    uint4* LL = (uint4*)Wl;
    #pragma unroll
    for (int t = 0; t < 4; ++t) {
      int q = tid + t * 256;         // 0..1023
      int wr = q >> 4, ls = q & 15;
      int phys = ls ^ (wr & 15);
      LH[wr * 16 + phys] = GH[(c0 + wr) * 16 + ls];
      LL[wr * 16 + phys] = GL[(c0 + wr) * 16 + ls];
    }
  }

  const uint4* AH = (const uint4*)Ah16;
  const uint4 zero4 = make_uint4(0, 0, 0, 0);

  // A fragments for all 8 k-chunks (16B = 8 halfs each).
  half8v ah[8];
  #pragma unroll
  for (int kc = 0; kc < 8; ++kc) {
    uint4 v = rowok ? AH[row * 16 + kc * 2 + kh] : zero4;
    ah[kc] = __builtin_bit_cast(half8v, v);
  }

  __syncthreads();

  floatx16 acc[2];
  #pragma unroll
  for (int t = 0; t < 2; ++t)
    #pragma unroll
    for (int j = 0; j < 16; ++j) acc[t][j] = 0.f;

  const uint4* WHv = (const uint4*)Wh;
  const uint4* WLv = (const uint4*)Wl;

  #pragma unroll
  for (int kc = 0; kc < 8; ++kc) {
    int fk = kc * 2 + kh;
    int ph = fk ^ (rA & 15);         // swizzled slot (wrow&15 == rA&15)
    half8v wh[2], wl[2];
    #pragma unroll
    for (int t = 0; t < 2; ++t) {
      wh[t] = __builtin_bit_cast(half8v, WHv[(t * 32 + rA) * 16 + ph]);
      wl[t] = __builtin_bit_cast(half8v, WLv[(t * 32 + rA) * 16 + ph]);
    }
    #pragma unroll
    for (int t = 0; t < 2; ++t)
      acc[t] = __builtin_amdgcn_mfma_f32_32x32x16_f16(ah[kc], wh[t], acc[t], 0, 0, 0);
    #pragma unroll
    for (int t = 0; t < 2; ++t)
      acc[t] = __builtin_amdgcn_mfma_f32_32x32x16_f16(ah[kc], wl[t], acc[t], 0, 0, 0);
  }

  float bcol[2], pcol[2];
  #pragma unroll
  for (int t = 0; t < 2; ++t) {
    bcol[t] = bb[c0 + t * 32 + rA];
    pcol[t] = pp[c0 + t * 32 + rA];
  }
  #pragma unroll
  for (int r = 0; r < 16; ++r) {
    int r32 = (r & 3) + 8 * (r >> 2) + 4 * kh;
    int orow = blockIdx.x * 128 + wv * 32 + r32;
    if (orow < M) {
      float rb = rbuf[orow];
      #pragma unroll
      for (int t = 0; t < 2; ++t) {
        float v = acc[t][r] + fmaf(rb, pcol[t], bcol[t]);
        v = fmaxf(v, 0.f);
        outp[(size_t)orow * CH + c0 + t * 32 + rA] = v;
      }
    }
  }
}

extern "C" void kernel_launch(void* const* d_in, const int* in_sizes, int n_in,
                              void* d_out, int out_size, void* d_ws, size_t ws_size,
                              hipStream_t stream) {
  const float* x      = (const float*)d_in[0];
  const int*   ei     = (const int*)d_in[1];
  const float* W_base = (const float*)d_in[2];
  const float* b_base = (const float*)d_in[3];
  const float* W_mu   = (const float*)d_in[4];
  const float* b_mu   = (const float*)d_in[5];
  const float* W_ls   = (const float*)d_in[6];
  const float* b_ls   = (const float*)d_in[7];
  float* out = (float*)d_out;

  const int N = in_sizes[0] / CH;
  const int E = in_sizes[1] / 2;

  char* ws = (char*)d_ws;
  size_t off = 0;
  auto carve = [&](size_t bytes) -> void* {
    void* p = ws + off;
    off += (bytes + 511) & ~(size_t)511;
    return p;
  };
  int*    cnt    = (int*)carve((size_t)N * 4);
  int*    rowptr = (int*)carve((size_t)(N + 1) * 4);
  int*    cursor = (int*)carve((size_t)N * 4);
  int*    col    = (int*)carve((size_t)E * 4);
  float*  dinv   = (float*)carve((size_t)N * 4);
  float*  rbuf   = (float*)carve((size_t)N * 4);
  int*    gsum   = (int*)carve((size_t)64 * 4);
  int*    flags  = (int*)carve((size_t)64 * 4);
  float*  pm   = (float*)carve((size_t)CH * 4);
  float*  ps   = (float*)carve((size_t)CH * 4);
  ushort* Wcmh = (ushort*)carve((size_t)CH * CH * 2);
  ushort* Wcml = (ushort*)carve((size_t)CH * CH * 2);
  ushort* Wcsh = (ushort*)carve((size_t)CH * CH * 2);
  ushort* Wcsl = (ushort*)carve((size_t)CH * CH * 2);
  ushort* xh   = (ushort*)carve((size_t)N * CH * 2);  // x as fp16
  ushort* t1h  = (ushort*)carve((size_t)N * CH * 2);  // A@x as fp16
  ushort* zh   = (ushort*)carve((size_t)N * CH * 2);  // z = A^2@x as fp16

  int eb = (E + 255) / 256;
  int nb = (N + SCAN_CHUNK - 1) / SCAN_CHUNK;
  int n8 = N * CH / 8;
  int ncnt4 = (N + 3) / 4;

  // 1: f2h + zero(cnt, flags) + Wc split-fp16 + pm/ps
  mega1_kernel<<<33 + (n8 + 255) / 256, 256, 0, stream>>>(
      x, xh, n8, cnt, ncnt4, flags,
      W_base, b_base, W_mu, W_ls, Wcmh, Wcml, Wcsh, Wcsl, pm, ps);
  // 2-4: CSR build
  count_kernel<<<eb, 256, 0, stream>>>(ei, E, cnt);
  scan1p_kernel<<<nb, 256, 0, stream>>>(cnt, N, nb, gsum, flags,
                                        rowptr, cursor, dinv);
  fill_kernel<<<eb, 256, 0, stream>>>(ei, E, cursor, col);

  int ab = (N * 64 + 255) / 256;
  int gb = (N + 127) / 128;

  // 5: t1h = A@xh
  agg_kernel<<<ab, 256, 0, stream>>>(xh, rowptr, col, dinv, t1h, nullptr, N);
  // 6: zh = A@t1h, r = A@1
  agg_kernel<<<ab, 256, 0, stream>>>(t1h, rowptr, col, dinv, zh, rbuf, N);
  // 7: m = relu(zh@Wcm + r*pm + bmu), s = relu(zh@Wcs + r*ps + bls)
  gemm_mfma_kernel<<<dim3(gb, 4), 256, 0, stream>>>(zh,
                                           Wcmh, Wcml, pm, b_mu,
                                           Wcsh, Wcsl, ps, b_ls,
                                           rbuf, out, out + (size_t)N * CH, N);
}